// Round 10
// baseline (356.088 us; speedup 1.0000x reference)
//
#include <hip/hip_runtime.h>
#include <math.h>

constexpr int FEAT = 128;   // DIN == DH == 128

typedef __attribute__((ext_vector_type(8))) short short8v;   // 8 bf16 raw / 16 B
typedef __attribute__((ext_vector_type(4))) float f32x4;

// ---- fp32 -> bf16 (RNE) helpers ----
__device__ inline unsigned short f2bf(float f) {
    unsigned int u = __float_as_uint(f);
    u += 0x7fffu + ((u >> 16) & 1u);
    return (unsigned short)(u >> 16);
}
__device__ inline float bf2f(unsigned short h) {
    return __uint_as_float(((unsigned int)h) << 16);
}
__device__ inline void split8(const float4 v0, const float4 v1, short8v& h, short8v& lo) {
    const float* f = (const float*)&v0;
    unsigned short hh[8], ll[8];
    #pragma unroll
    for (int i = 0; i < 4; ++i) {
        hh[i] = f2bf(f[i]); ll[i] = f2bf(f[i] - bf2f(hh[i]));
    }
    const float* g = (const float*)&v1;
    #pragma unroll
    for (int i = 0; i < 4; ++i) {
        hh[4 + i] = f2bf(g[i]); ll[4 + i] = f2bf(g[i] - bf2f(hh[4 + i]));
    }
    h  = *(short8v*)hh;
    lo = *(short8v*)ll;
}

// ---------------- degree histogram (int) ----------------
__global__ void deg_kernel(const int* __restrict__ dst, int* __restrict__ degi, int E) {
    int e = blockIdx.x * 256 + threadIdx.x;
    if (e < E) atomicAdd(&degi[dst[e]], 1);
}

// ---------------- hierarchical exclusive scan (1024 elems / block) ----------------
__global__ __launch_bounds__(256) void blockred_kernel(const int* __restrict__ deg,
                                                       int* __restrict__ bsum, int n) {
    __shared__ int red[256];
    int base = blockIdx.x * 1024 + threadIdx.x * 4;
    int s = 0;
    if (base + 3 < n) {
        int4 v = *(const int4*)(deg + base);
        s = v.x + v.y + v.z + v.w;
    } else {
        for (int i = 0; i < 4; ++i) if (base + i < n) s += deg[base + i];
    }
    red[threadIdx.x] = s;
    __syncthreads();
    for (int st = 128; st > 0; st >>= 1) {
        if (threadIdx.x < st) red[threadIdx.x] += red[threadIdx.x + st];
        __syncthreads();
    }
    if (threadIdx.x == 0) bsum[blockIdx.x] = red[0];
}

// 1 block, 256 threads; nb <= 256 (N <= 262144)
__global__ __launch_bounds__(256) void scanb_kernel(const int* __restrict__ bsum,
                                                    int* __restrict__ bpre, int nb) {
    __shared__ int part[256];
    int t = threadIdx.x;
    int v = (t < nb) ? bsum[t] : 0;
    part[t] = v;
    __syncthreads();
    for (int s = 1; s < 256; s <<= 1) {
        int u = (t >= s) ? part[t - s] : 0;
        __syncthreads();
        part[t] += u;
        __syncthreads();
    }
    if (t < nb) bpre[t] = part[t] - v;
}

__global__ __launch_bounds__(256) void scanfill_kernel(const int* __restrict__ deg,
                                                       const int* __restrict__ bpre,
                                                       int* __restrict__ offs,
                                                       float* __restrict__ invd,
                                                       int n, int E) {
    __shared__ int part[256];
    int t = threadIdx.x;
    int base = blockIdx.x * 1024 + t * 4;
    int d[4];
    int s = 0;
    #pragma unroll
    for (int i = 0; i < 4; ++i) {
        d[i] = (base + i < n) ? deg[base + i] : 0;
        s += d[i];
    }
    part[t] = s;
    __syncthreads();
    for (int st = 1; st < 256; st <<= 1) {
        int u = (t >= st) ? part[t - st] : 0;
        __syncthreads();
        part[t] += u;
        __syncthreads();
    }
    int pre = bpre[blockIdx.x] + part[t] - s;
    #pragma unroll
    for (int i = 0; i < 4; ++i) {
        int idx = base + i;
        if (idx < n) {
            offs[idx] = pre;
            invd[idx] = 1.0f / fmaxf((float)d[i], 1.0f);
            pre += d[i];
        }
    }
    if (blockIdx.x == 0 && t == 0) offs[n] = E;
}

// ---------------- CSR fill via LDS counting-sort, one block per 2048-dst range ----
// Writes to eidx are contiguous streaming flushes from a single CU -> no
// cross-XCD line bouncing, no partial-line write amplification.
constexpr int FRANGE = 2048;
constexpr int FCAP   = 36864;   // slots; range edge count ~ 32768 +- 181 (22 sigma margin)
__global__ __launch_bounds__(1024) void fill_lds_kernel(const int* __restrict__ src,
                                                        const int* __restrict__ dst,
                                                        const int* __restrict__ offs,
                                                        int* __restrict__ eidx,
                                                        int n, int E) {
    __shared__ int lcur[FRANGE];        // 8 KB
    __shared__ int lbuf[FCAP];          // 144 KB
    const int lo  = blockIdx.x * FRANGE;
    const int hi  = min(lo + FRANGE, n);
    const int base = offs[lo];
    const int cnt  = offs[hi] - base;

    for (int i = threadIdx.x; i < hi - lo; i += 1024) lcur[i] = offs[lo + i];
    __syncthreads();

    const int e4 = E >> 2;
    for (int i = threadIdx.x; i < e4; i += 1024) {
        int4 d4 = ((const int4*)dst)[i];
        int4 s4 = ((const int4*)src)[i];
        int dd[4] = {d4.x, d4.y, d4.z, d4.w};
        int ss[4] = {s4.x, s4.y, s4.z, s4.w};
        #pragma unroll
        for (int q = 0; q < 4; ++q) {
            int d = dd[q];
            if (d >= lo && d < hi) {
                int pos = atomicAdd(&lcur[d - lo], 1);
                int idx = pos - base;
                if (idx < FCAP) lbuf[idx] = ss[q];
                else            eidx[pos] = ss[q];   // overflow fallback (never taken here)
            }
        }
    }
    for (int e = e4 * 4 + threadIdx.x; e < E; e += 1024) {
        int d = dst[e];
        if (d >= lo && d < hi) {
            int pos = atomicAdd(&lcur[d - lo], 1);
            int idx = pos - base;
            if (idx < FCAP) lbuf[idx] = src[e];
            else            eidx[pos] = src[e];
        }
    }
    __syncthreads();

    const int m = min(cnt, FCAP);
    for (int i = threadIdx.x; i < m; i += 1024) eidx[base + i] = lbuf[i];
}

// ---------------- W prep: split bf16 transpose WTh/WTl[c][k] of concat(Wl;Wr) ----------------
__global__ void prep_wt(const float* __restrict__ Wl, const float* __restrict__ Wr,
                        unsigned short* __restrict__ WTh, unsigned short* __restrict__ WTl,
                        int dout) {
    int idx = blockIdx.x * 256 + threadIdx.x;
    if (idx >= dout * 256) return;
    int c = idx >> 8;
    int k = idx & 255;
    float v = (k < 128) ? Wl[(size_t)k * dout + c] : Wr[(size_t)(k - 128) * dout + c];
    unsigned short h = f2bf(v);
    WTh[(size_t)c * 256 + k] = h;
    WTl[(size_t)c * 256 + k] = f2bf(v - bf2f(h));
}

// ---------------- fp32 -> bf16 convert (x -> xbf) ----------------
__global__ void f2bf_kernel(const float* __restrict__ in, unsigned short* __restrict__ out,
                            int total4) {
    int i = blockIdx.x * 256 + threadIdx.x;
    if (i >= total4) return;
    float4 v = *(const float4*)(in + (size_t)i * 4);
    ushort4 h;
    h.x = f2bf(v.x); h.y = f2bf(v.y); h.z = f2bf(v.z); h.w = f2bf(v.w);
    *(ushort4*)(out + (size_t)i * 4) = h;
}

// ---------------- gather mean: one wave per node, 4 edges in flight ----------------
// 16 lanes per edge, short8v (16 B) per lane; cross-group reduce via shfl_xor.
__global__ __launch_bounds__(256) void gather_bf_kernel(const unsigned short* __restrict__ featbf,
                                                        const int* __restrict__ offs,
                                                        const int* __restrict__ eidx,
                                                        const float* __restrict__ invd,
                                                        float* __restrict__ agg, int n) {
    int node = blockIdx.x * 4 + (threadIdx.x >> 6);
    if (node >= n) return;
    const int l   = threadIdx.x & 63;
    const int grp = l >> 4;
    const int li  = l & 15;
    const int c8  = li * 8;
    int beg = offs[node], end = offs[node + 1];
    float acc[8];
    #pragma unroll
    for (int q = 0; q < 8; ++q) acc[q] = 0.f;

    int j = beg + grp;
    for (; j + 4 < end; j += 8) {
        int s0 = eidx[j], s1 = eidx[j + 4];
        short8v v0 = *(const short8v*)(featbf + (size_t)s0 * FEAT + c8);
        short8v v1 = *(const short8v*)(featbf + (size_t)s1 * FEAT + c8);
        #pragma unroll
        for (int q = 0; q < 8; ++q) {
            acc[q] += __uint_as_float(((unsigned)(unsigned short)v0[q]) << 16);
            acc[q] += __uint_as_float(((unsigned)(unsigned short)v1[q]) << 16);
        }
    }
    if (j < end) {
        int s0 = eidx[j];
        short8v v0 = *(const short8v*)(featbf + (size_t)s0 * FEAT + c8);
        #pragma unroll
        for (int q = 0; q < 8; ++q)
            acc[q] += __uint_as_float(((unsigned)(unsigned short)v0[q]) << 16);
    }

    #pragma unroll
    for (int off = 16; off < 64; off <<= 1)
        #pragma unroll
        for (int q = 0; q < 8; ++q)
            acc[q] += __shfl_xor(acc[q], off, 64);

    if (grp == 0) {
        float sc = invd[node];
        float4 r0, r1;
        r0.x = acc[0] * sc; r0.y = acc[1] * sc; r0.z = acc[2] * sc; r0.w = acc[3] * sc;
        r1.x = acc[4] * sc; r1.y = acc[5] * sc; r1.z = acc[6] * sc; r1.w = acc[7] * sc;
        float* p = agg + (size_t)node * FEAT + c8;
        *(float4*)p = r0;
        *(float4*)(p + 4) = r1;
    }
}

// ---------------- MFMA dense, LDS-resident B, 64 cols/block ----------------
// out = elu([mean|x] @ W + b); K=256. mean (fp32): hi/lo split, 3 MFMAs;
// x (bf16): 2 MFMAs. Block = 1024 thr = 16 waves x 16 rows = 256 rows;
// blockIdx.y = 64-col half (DOUT=128) or 0 (DOUT=64). B staged once into LDS
// (64 KB hi+lo) with XOR swizzle byte^=((c&7)<<4); one barrier total.
template <int DOUT, bool WBF, bool LSM>
__global__ __launch_bounds__(1024, 4) void dense_mfma(
    const float* __restrict__ mean, const unsigned short* __restrict__ xinbf,
    const unsigned short* __restrict__ WTh, const unsigned short* __restrict__ WTl,
    const float* __restrict__ bias,
    float* outf, unsigned short* outbf, int n)
{
    __shared__ unsigned short Bh[64 * 256];   // 32 KB
    __shared__ unsigned short Bl[64 * 256];   // 32 KB
    const int tid = threadIdx.x;
    const int colbase = blockIdx.y * 64;

    #pragma unroll
    for (int it = 0; it < 2; ++it) {
        int o  = (tid + it * 1024) * 8;       // ushort index, 16B granules
        int cl = o >> 8;                      // local col 0..63
        int k  = o & 255;
        size_t gsrc = (size_t)(colbase + cl) * 256 + k;
        int db = (o * 2) ^ ((cl & 7) << 4);   // swizzled byte offset
        *(short8v*)((char*)Bh + db) = *(const short8v*)(WTh + gsrc);
        *(short8v*)((char*)Bl + db) = *(const short8v*)(WTl + gsrc);
    }
    __syncthreads();

    const int l    = tid & 63;
    const int w    = tid >> 6;
    const int l15  = l & 15;
    const int lg   = l >> 4;
    const int row0 = blockIdx.x * 256 + w * 16;
    if (row0 >= n) return;                    // no barriers after this point
    const int g = row0 + l15;                 // this lane's A row

    f32x4 acc[4];
    #pragma unroll
    for (int ct = 0; ct < 4; ++ct) acc[ct] = (f32x4){0.f, 0.f, 0.f, 0.f};

    // ---- chunks 0..3: mean (fp32, hi/lo split, 3 MFMAs per ct) ----
    #pragma unroll
    for (int ch = 0; ch < 4; ++ch) {
        float4 v0 = make_float4(0.f, 0.f, 0.f, 0.f), v1 = v0;
        if (g < n) {
            const float* p = mean + (size_t)g * FEAT + ch * 32 + lg * 8;
            v0 = *(const float4*)p;
            v1 = *(const float4*)(p + 4);
        }
        short8v ah, al;
        split8(v0, v1, ah, al);
        #pragma unroll
        for (int ct = 0; ct < 4; ++ct) {
            int cl = ct * 16 + l15;
            int db = (cl * 512 + ch * 64 + lg * 16) ^ ((cl & 7) << 4);
            short8v bh = *(const short8v*)((const char*)Bh + db);
            short8v bl = *(const short8v*)((const char*)Bl + db);
            acc[ct] = __builtin_amdgcn_mfma_f32_16x16x32_bf16(ah, bh, acc[ct], 0, 0, 0);
            acc[ct] = __builtin_amdgcn_mfma_f32_16x16x32_bf16(ah, bl, acc[ct], 0, 0, 0);
            acc[ct] = __builtin_amdgcn_mfma_f32_16x16x32_bf16(al, bh, acc[ct], 0, 0, 0);
        }
    }
    // ---- chunks 4..7: x as bf16 (2 MFMAs per ct) ----
    #pragma unroll
    for (int ch = 4; ch < 8; ++ch) {
        short8v ah = (short8v){0,0,0,0,0,0,0,0};
        if (g < n) ah = *(const short8v*)(xinbf + (size_t)g * FEAT + (ch - 4) * 32 + lg * 8);
        #pragma unroll
        for (int ct = 0; ct < 4; ++ct) {
            int cl = ct * 16 + l15;
            int db = (cl * 512 + ch * 64 + lg * 16) ^ ((cl & 7) << 4);
            short8v bh = *(const short8v*)((const char*)Bh + db);
            short8v bl = *(const short8v*)((const char*)Bl + db);
            acc[ct] = __builtin_amdgcn_mfma_f32_16x16x32_bf16(ah, bh, acc[ct], 0, 0, 0);
            acc[ct] = __builtin_amdgcn_mfma_f32_16x16x32_bf16(ah, bl, acc[ct], 0, 0, 0);
        }
    }

    // ---- epilogue: bias + ELU (+ optional fused log_softmax) ----
    float t[4][4];
    #pragma unroll
    for (int ct = 0; ct < 4; ++ct) {
        float b = bias[colbase + ct * 16 + l15];
        #pragma unroll
        for (int q = 0; q < 4; ++q) {
            float v = acc[ct][q] + b;
            t[ct][q] = (v > 0.f) ? v : expm1f(v);
        }
    }
    if (LSM) {
        #pragma unroll
        for (int q = 0; q < 4; ++q) {
            float m = t[0][q];
            #pragma unroll
            for (int ct = 1; ct < 4; ++ct) m = fmaxf(m, t[ct][q]);
            #pragma unroll
            for (int s = 1; s < 16; s <<= 1) m = fmaxf(m, __shfl_xor(m, s, 64));
            float sum = 0.f;
            #pragma unroll
            for (int ct = 0; ct < 4; ++ct) sum += expf(t[ct][q] - m);
            #pragma unroll
            for (int s = 1; s < 16; s <<= 1) sum += __shfl_xor(sum, s, 64);
            float ls = m + logf(sum);
            #pragma unroll
            for (int ct = 0; ct < 4; ++ct) t[ct][q] -= ls;
        }
    }
    #pragma unroll
    for (int ct = 0; ct < 4; ++ct) {
        int col = colbase + ct * 16 + l15;
        #pragma unroll
        for (int q = 0; q < 4; ++q) {
            int grow = row0 + lg * 4 + q;
            if (grow < n) {
                if (WBF) outbf[(size_t)grow * DOUT + col] = f2bf(t[ct][q]);
                else     outf[(size_t)grow * DOUT + col] = t[ct][q];
            }
        }
    }
}

extern "C" void kernel_launch(void* const* d_in, const int* in_sizes, int n_in,
                              void* d_out, int out_size, void* d_ws, size_t ws_size,
                              hipStream_t stream) {
    const float* x   = (const float*)d_in[0];
    const float* W1l = (const float*)d_in[1];
    const float* W1r = (const float*)d_in[2];
    const float* b1  = (const float*)d_in[3];
    const float* W2l = (const float*)d_in[4];
    const float* W2r = (const float*)d_in[5];
    const float* b2  = (const float*)d_in[6];
    const float* W3l = (const float*)d_in[7];
    const float* W3r = (const float*)d_in[8];
    const float* b3  = (const float*)d_in[9];
    const int*   src = (const int*)d_in[10];
    const int*   dst = (const int*)d_in[11];

    const int N = in_sizes[0] / FEAT;
    const int E = in_sizes[10];

    const size_t NA = ((size_t)N + 63) & ~(size_t)63;
    const size_t EA = ((size_t)E + 63) & ~(size_t)63;
    const int nb = (N + 1023) / 1024;       // scan blocks (<=256)

    float* ws   = (float*)d_ws;
    float* invd = ws;                             // NA floats
    int*   deg  = (int*)(ws + NA);                // NA ints
    int*   offs = deg + NA;                       // NA+64 ints
    int*   bsum = offs + NA + 64;                 // 256 ints
    int*   bpre = bsum + 256;                     // 256 ints
    int*   eidx = bpre + 256;                     // EA ints
    unsigned short* wtb = (unsigned short*)(eidx + EA);
    unsigned short* WTh1 = wtb;                   // 128*256
    unsigned short* WTl1 = WTh1 + 128 * 256;
    unsigned short* WTh2 = WTl1 + 128 * 256;
    unsigned short* WTl2 = WTh2 + 128 * 256;
    unsigned short* WTh3 = WTl2 + 128 * 256;      // 64*256
    unsigned short* WTl3 = WTh3 + 64 * 256;
    float* bufM = (float*)(WTl3 + 64 * 256);      // NA*128 fp32 mean scratch
    unsigned short* bfA = (unsigned short*)(bufM + NA * FEAT);  // NA*128 bf16
    unsigned short* bfB = bfA + NA * FEAT;                      // NA*128 bf16
    float* outp = (float*)d_out;

    const int gblocks = (N + 3) / 4;
    const int dblocks = (N + 255) / 256;
    const int fblocks = (N + FRANGE - 1) / FRANGE;

    // ---- CSR build + weight prep (once per launch) ----
    hipMemsetAsync(deg, 0, (size_t)N * 4, stream);
    deg_kernel<<<(E + 255) / 256, 256, 0, stream>>>(dst, deg, E);
    blockred_kernel<<<nb, 256, 0, stream>>>(deg, bsum, N);
    scanb_kernel<<<1, 256, 0, stream>>>(bsum, bpre, nb);
    scanfill_kernel<<<nb, 256, 0, stream>>>(deg, bpre, offs, invd, N, E);
    fill_lds_kernel<<<fblocks, 1024, 0, stream>>>(src, dst, offs, eidx, N, E);
    prep_wt<<<(128 * 256 + 255) / 256, 256, 0, stream>>>(W1l, W1r, WTh1, WTl1, 128);
    prep_wt<<<(128 * 256 + 255) / 256, 256, 0, stream>>>(W2l, W2r, WTh2, WTl2, 128);
    prep_wt<<<(64 * 256 + 255) / 256, 256, 0, stream>>>(W3l, W3r, WTh3, WTl3, 64);
    f2bf_kernel<<<(N * FEAT / 4 + 255) / 256, 256, 0, stream>>>(x, bfA, N * FEAT / 4);

    // layer 1: gather(xbf=bfA) -> M ; h1bf = dense(M, bfA) -> bfB
    gather_bf_kernel<<<gblocks, 256, 0, stream>>>(bfA, offs, eidx, invd, bufM, N);
    dense_mfma<128, true, false><<<dim3(dblocks, 2), 1024, 0, stream>>>(bufM, bfA, WTh1, WTl1, b1, nullptr, bfB, N);

    // layer 2: gather(h1bf=bfB) -> M ; h2bf = dense(M, bfB) -> bfA
    gather_bf_kernel<<<gblocks, 256, 0, stream>>>(bfB, offs, eidx, invd, bufM, N);
    dense_mfma<128, true, false><<<dim3(dblocks, 2), 1024, 0, stream>>>(bufM, bfB, WTh2, WTl2, b2, nullptr, bfA, N);

    // layer 3: gather(h2bf=bfA) -> M ; out = log_softmax(elu(dense(M, bfA))) -> d_out
    gather_bf_kernel<<<gblocks, 256, 0, stream>>>(bfA, offs, eidx, invd, bufM, N);
    dense_mfma<64, false, true><<<dim3(dblocks, 1), 1024, 0, stream>>>(bufM, bfA, WTh3, WTl3, b3, outp, nullptr, N);
}

// Round 11
// 258.721 us; speedup vs baseline: 1.3763x; 1.3763x over previous
//
#include <hip/hip_runtime.h>
#include <math.h>

constexpr int FEAT = 128;   // DIN == DH == 128

typedef __attribute__((ext_vector_type(8))) short short8v;   // 8 bf16 raw / 16 B
typedef __attribute__((ext_vector_type(4))) float f32x4;

// ---- fp32 -> bf16 (RNE) helpers ----
__device__ inline unsigned short f2bf(float f) {
    unsigned int u = __float_as_uint(f);
    u += 0x7fffu + ((u >> 16) & 1u);
    return (unsigned short)(u >> 16);
}
__device__ inline float bf2f(unsigned short h) {
    return __uint_as_float(((unsigned int)h) << 16);
}
__device__ inline void split8(const float4 v0, const float4 v1, short8v& h, short8v& lo) {
    const float* f = (const float*)&v0;
    unsigned short hh[8], ll[8];
    #pragma unroll
    for (int i = 0; i < 4; ++i) {
        hh[i] = f2bf(f[i]); ll[i] = f2bf(f[i] - bf2f(hh[i]));
    }
    const float* g = (const float*)&v1;
    #pragma unroll
    for (int i = 0; i < 4; ++i) {
        hh[4 + i] = f2bf(g[i]); ll[4 + i] = f2bf(g[i] - bf2f(hh[4 + i]));
    }
    h  = *(short8v*)hh;
    lo = *(short8v*)ll;
}

// ---------------- degree histogram (int) ----------------
__global__ void deg_kernel(const int* __restrict__ dst, int* __restrict__ degi, int E) {
    int e = blockIdx.x * 256 + threadIdx.x;
    if (e < E) atomicAdd(&degi[dst[e]], 1);
}

// ---------------- hierarchical exclusive scan (1024 elems / block) ----------------
__global__ __launch_bounds__(256) void blockred_kernel(const int* __restrict__ deg,
                                                       int* __restrict__ bsum, int n) {
    __shared__ int red[256];
    int base = blockIdx.x * 1024 + threadIdx.x * 4;
    int s = 0;
    if (base + 3 < n) {
        int4 v = *(const int4*)(deg + base);
        s = v.x + v.y + v.z + v.w;
    } else {
        for (int i = 0; i < 4; ++i) if (base + i < n) s += deg[base + i];
    }
    red[threadIdx.x] = s;
    __syncthreads();
    for (int st = 128; st > 0; st >>= 1) {
        if (threadIdx.x < st) red[threadIdx.x] += red[threadIdx.x + st];
        __syncthreads();
    }
    if (threadIdx.x == 0) bsum[blockIdx.x] = red[0];
}

// 1 block, 256 threads; nb <= 256 (N <= 262144)
__global__ __launch_bounds__(256) void scanb_kernel(const int* __restrict__ bsum,
                                                    int* __restrict__ bpre, int nb) {
    __shared__ int part[256];
    int t = threadIdx.x;
    int v = (t < nb) ? bsum[t] : 0;
    part[t] = v;
    __syncthreads();
    for (int s = 1; s < 256; s <<= 1) {
        int u = (t >= s) ? part[t - s] : 0;
        __syncthreads();
        part[t] += u;
        __syncthreads();
    }
    if (t < nb) bpre[t] = part[t] - v;
}

__global__ __launch_bounds__(256) void scanfill_kernel(const int* __restrict__ deg,
                                                       const int* __restrict__ bpre,
                                                       int* __restrict__ offs,
                                                       int* __restrict__ cur,
                                                       float* __restrict__ invd,
                                                       int n, int E) {
    __shared__ int part[256];
    int t = threadIdx.x;
    int base = blockIdx.x * 1024 + t * 4;
    int d[4];
    int s = 0;
    #pragma unroll
    for (int i = 0; i < 4; ++i) {
        d[i] = (base + i < n) ? deg[base + i] : 0;
        s += d[i];
    }
    part[t] = s;
    __syncthreads();
    for (int st = 1; st < 256; st <<= 1) {
        int u = (t >= st) ? part[t - st] : 0;
        __syncthreads();
        part[t] += u;
        __syncthreads();
    }
    int pre = bpre[blockIdx.x] + part[t] - s;
    #pragma unroll
    for (int i = 0; i < 4; ++i) {
        int idx = base + i;
        if (idx < n) {
            offs[idx] = pre;
            cur[idx]  = pre;
            invd[idx] = 1.0f / fmaxf((float)d[i], 1.0f);
            pre += d[i];
        }
    }
    if (blockIdx.x == 0 && t == 0) offs[n] = E;
}

// ---------------- CSR fill, XCD-pinned dst ranges ----------------
// 8 dst-ranges; range p is processed ONLY by blocks with blockIdx&7==p, which
// round-robin dispatch puts on one XCD -> all scattered eidx writes for that
// ~400KB region stay in that XCD's L2 until lines are full (write amp ~1x).
// Parallelism: (E/FCH) chunks per range, full grid. Correct regardless of the
// actual block->XCD mapping (mapping affects locality only).
constexpr int FCH = 4096;    // edges per chunk (1024 int4 per block)
__global__ __launch_bounds__(256) void fill_xcd_kernel(const int* __restrict__ src,
                                                       const int* __restrict__ dst,
                                                       int* __restrict__ cur,
                                                       int* __restrict__ eidx,
                                                       int E, int rsize) {
    const int p     = blockIdx.x & 7;
    const int chunk = blockIdx.x >> 3;
    const int lo = p * rsize;
    const int hi = lo + rsize;
    #pragma unroll
    for (int it = 0; it < 4; ++it) {
        int e = chunk * FCH + (it * 256 + threadIdx.x) * 4;
        if (e + 3 < E) {
            int4 d4 = *(const int4*)(dst + e);
            int dd[4] = {d4.x, d4.y, d4.z, d4.w};
            #pragma unroll
            for (int q = 0; q < 4; ++q) {
                int d = dd[q];
                if (d >= lo && d < hi) {
                    int pos = atomicAdd(&cur[d], 1);
                    eidx[pos] = src[e + q];
                }
            }
        } else {
            for (int q = 0; e + q < E && q < 4; ++q) {
                int d = dst[e + q];
                if (d >= lo && d < hi) {
                    int pos = atomicAdd(&cur[d], 1);
                    eidx[pos] = src[e + q];
                }
            }
        }
    }
}

// ---------------- W prep: split bf16 transpose WTh/WTl[c][k] of concat(Wl;Wr) ----------------
__global__ void prep_wt(const float* __restrict__ Wl, const float* __restrict__ Wr,
                        unsigned short* __restrict__ WTh, unsigned short* __restrict__ WTl,
                        int dout) {
    int idx = blockIdx.x * 256 + threadIdx.x;
    if (idx >= dout * 256) return;
    int c = idx >> 8;
    int k = idx & 255;
    float v = (k < 128) ? Wl[(size_t)k * dout + c] : Wr[(size_t)(k - 128) * dout + c];
    unsigned short h = f2bf(v);
    WTh[(size_t)c * 256 + k] = h;
    WTl[(size_t)c * 256 + k] = f2bf(v - bf2f(h));
}

// ---------------- fp32 -> bf16 convert (x -> xbf) ----------------
__global__ void f2bf_kernel(const float* __restrict__ in, unsigned short* __restrict__ out,
                            int total4) {
    int i = blockIdx.x * 256 + threadIdx.x;
    if (i >= total4) return;
    float4 v = *(const float4*)(in + (size_t)i * 4);
    ushort4 h;
    h.x = f2bf(v.x); h.y = f2bf(v.y); h.z = f2bf(v.z); h.w = f2bf(v.w);
    *(ushort4*)(out + (size_t)i * 4) = h;
}

// ---------------- gather mean: one wave per node, 4 edges in flight ----------------
// 16 lanes per edge, short8v (16 B) per lane; cross-group reduce via shfl_xor.
__global__ __launch_bounds__(256) void gather_bf_kernel(const unsigned short* __restrict__ featbf,
                                                        const int* __restrict__ offs,
                                                        const int* __restrict__ eidx,
                                                        const float* __restrict__ invd,
                                                        float* __restrict__ agg, int n) {
    int node = blockIdx.x * 4 + (threadIdx.x >> 6);
    if (node >= n) return;
    const int l   = threadIdx.x & 63;
    const int grp = l >> 4;
    const int li  = l & 15;
    const int c8  = li * 8;
    int beg = offs[node], end = offs[node + 1];
    float acc[8];
    #pragma unroll
    for (int q = 0; q < 8; ++q) acc[q] = 0.f;

    int j = beg + grp;
    for (; j + 4 < end; j += 8) {
        int s0 = eidx[j], s1 = eidx[j + 4];
        short8v v0 = *(const short8v*)(featbf + (size_t)s0 * FEAT + c8);
        short8v v1 = *(const short8v*)(featbf + (size_t)s1 * FEAT + c8);
        #pragma unroll
        for (int q = 0; q < 8; ++q) {
            acc[q] += __uint_as_float(((unsigned)(unsigned short)v0[q]) << 16);
            acc[q] += __uint_as_float(((unsigned)(unsigned short)v1[q]) << 16);
        }
    }
    if (j < end) {
        int s0 = eidx[j];
        short8v v0 = *(const short8v*)(featbf + (size_t)s0 * FEAT + c8);
        #pragma unroll
        for (int q = 0; q < 8; ++q)
            acc[q] += __uint_as_float(((unsigned)(unsigned short)v0[q]) << 16);
    }

    #pragma unroll
    for (int off = 16; off < 64; off <<= 1)
        #pragma unroll
        for (int q = 0; q < 8; ++q)
            acc[q] += __shfl_xor(acc[q], off, 64);

    if (grp == 0) {
        float sc = invd[node];
        float4 r0, r1;
        r0.x = acc[0] * sc; r0.y = acc[1] * sc; r0.z = acc[2] * sc; r0.w = acc[3] * sc;
        r1.x = acc[4] * sc; r1.y = acc[5] * sc; r1.z = acc[6] * sc; r1.w = acc[7] * sc;
        float* p = agg + (size_t)node * FEAT + c8;
        *(float4*)p = r0;
        *(float4*)(p + 4) = r1;
    }
}

// ---------------- MFMA dense, LDS-resident B, 64 cols/block ----------------
// out = elu([mean|x] @ W + b); K=256. mean (fp32): hi/lo split, 3 MFMAs;
// x (bf16): 2 MFMAs. Block = 1024 thr = 16 waves x 16 rows = 256 rows;
// blockIdx.y = 64-col half (DOUT=128) or 0 (DOUT=64). B staged once into LDS
// (64 KB hi+lo) with XOR swizzle byte^=((c&7)<<4); one barrier total.
template <int DOUT, bool WBF, bool LSM>
__global__ __launch_bounds__(1024, 4) void dense_mfma(
    const float* __restrict__ mean, const unsigned short* __restrict__ xinbf,
    const unsigned short* __restrict__ WTh, const unsigned short* __restrict__ WTl,
    const float* __restrict__ bias,
    float* outf, unsigned short* outbf, int n)
{
    __shared__ unsigned short Bh[64 * 256];   // 32 KB
    __shared__ unsigned short Bl[64 * 256];   // 32 KB
    const int tid = threadIdx.x;
    const int colbase = blockIdx.y * 64;

    #pragma unroll
    for (int it = 0; it < 2; ++it) {
        int o  = (tid + it * 1024) * 8;       // ushort index, 16B granules
        int cl = o >> 8;                      // local col 0..63
        int k  = o & 255;
        size_t gsrc = (size_t)(colbase + cl) * 256 + k;
        int db = (o * 2) ^ ((cl & 7) << 4);   // swizzled byte offset
        *(short8v*)((char*)Bh + db) = *(const short8v*)(WTh + gsrc);
        *(short8v*)((char*)Bl + db) = *(const short8v*)(WTl + gsrc);
    }
    __syncthreads();

    const int l    = tid & 63;
    const int w    = tid >> 6;
    const int l15  = l & 15;
    const int lg   = l >> 4;
    const int row0 = blockIdx.x * 256 + w * 16;
    if (row0 >= n) return;                    // no barriers after this point
    const int g = row0 + l15;                 // this lane's A row

    f32x4 acc[4];
    #pragma unroll
    for (int ct = 0; ct < 4; ++ct) acc[ct] = (f32x4){0.f, 0.f, 0.f, 0.f};

    // ---- chunks 0..3: mean (fp32, hi/lo split, 3 MFMAs per ct) ----
    #pragma unroll
    for (int ch = 0; ch < 4; ++ch) {
        float4 v0 = make_float4(0.f, 0.f, 0.f, 0.f), v1 = v0;
        if (g < n) {
            const float* p = mean + (size_t)g * FEAT + ch * 32 + lg * 8;
            v0 = *(const float4*)p;
            v1 = *(const float4*)(p + 4);
        }
        short8v ah, al;
        split8(v0, v1, ah, al);
        #pragma unroll
        for (int ct = 0; ct < 4; ++ct) {
            int cl = ct * 16 + l15;
            int db = (cl * 512 + ch * 64 + lg * 16) ^ ((cl & 7) << 4);
            short8v bh = *(const short8v*)((const char*)Bh + db);
            short8v bl = *(const short8v*)((const char*)Bl + db);
            acc[ct] = __builtin_amdgcn_mfma_f32_16x16x32_bf16(ah, bh, acc[ct], 0, 0, 0);
            acc[ct] = __builtin_amdgcn_mfma_f32_16x16x32_bf16(ah, bl, acc[ct], 0, 0, 0);
            acc[ct] = __builtin_amdgcn_mfma_f32_16x16x32_bf16(al, bh, acc[ct], 0, 0, 0);
        }
    }
    // ---- chunks 4..7: x as bf16 (2 MFMAs per ct) ----
    #pragma unroll
    for (int ch = 4; ch < 8; ++ch) {
        short8v ah = (short8v){0,0,0,0,0,0,0,0};
        if (g < n) ah = *(const short8v*)(xinbf + (size_t)g * FEAT + (ch - 4) * 32 + lg * 8);
        #pragma unroll
        for (int ct = 0; ct < 4; ++ct) {
            int cl = ct * 16 + l15;
            int db = (cl * 512 + ch * 64 + lg * 16) ^ ((cl & 7) << 4);
            short8v bh = *(const short8v*)((const char*)Bh + db);
            short8v bl = *(const short8v*)((const char*)Bl + db);
            acc[ct] = __builtin_amdgcn_mfma_f32_16x16x32_bf16(ah, bh, acc[ct], 0, 0, 0);
            acc[ct] = __builtin_amdgcn_mfma_f32_16x16x32_bf16(ah, bl, acc[ct], 0, 0, 0);
        }
    }

    // ---- epilogue: bias + ELU (+ optional fused log_softmax) ----
    float t[4][4];
    #pragma unroll
    for (int ct = 0; ct < 4; ++ct) {
        float b = bias[colbase + ct * 16 + l15];
        #pragma unroll
        for (int q = 0; q < 4; ++q) {
            float v = acc[ct][q] + b;
            t[ct][q] = (v > 0.f) ? v : expm1f(v);
        }
    }
    if (LSM) {
        #pragma unroll
        for (int q = 0; q < 4; ++q) {
            float m = t[0][q];
            #pragma unroll
            for (int ct = 1; ct < 4; ++ct) m = fmaxf(m, t[ct][q]);
            #pragma unroll
            for (int s = 1; s < 16; s <<= 1) m = fmaxf(m, __shfl_xor(m, s, 64));
            float sum = 0.f;
            #pragma unroll
            for (int ct = 0; ct < 4; ++ct) sum += expf(t[ct][q] - m);
            #pragma unroll
            for (int s = 1; s < 16; s <<= 1) sum += __shfl_xor(sum, s, 64);
            float ls = m + logf(sum);
            #pragma unroll
            for (int ct = 0; ct < 4; ++ct) t[ct][q] -= ls;
        }
    }
    #pragma unroll
    for (int ct = 0; ct < 4; ++ct) {
        int col = colbase + ct * 16 + l15;
        #pragma unroll
        for (int q = 0; q < 4; ++q) {
            int grow = row0 + lg * 4 + q;
            if (grow < n) {
                if (WBF) outbf[(size_t)grow * DOUT + col] = f2bf(t[ct][q]);
                else     outf[(size_t)grow * DOUT + col] = t[ct][q];
            }
        }
    }
}

extern "C" void kernel_launch(void* const* d_in, const int* in_sizes, int n_in,
                              void* d_out, int out_size, void* d_ws, size_t ws_size,
                              hipStream_t stream) {
    const float* x   = (const float*)d_in[0];
    const float* W1l = (const float*)d_in[1];
    const float* W1r = (const float*)d_in[2];
    const float* b1  = (const float*)d_in[3];
    const float* W2l = (const float*)d_in[4];
    const float* W2r = (const float*)d_in[5];
    const float* b2  = (const float*)d_in[6];
    const float* W3l = (const float*)d_in[7];
    const float* W3r = (const float*)d_in[8];
    const float* b3  = (const float*)d_in[9];
    const int*   src = (const int*)d_in[10];
    const int*   dst = (const int*)d_in[11];

    const int N = in_sizes[0] / FEAT;
    const int E = in_sizes[10];

    const size_t NA = ((size_t)N + 63) & ~(size_t)63;
    const size_t EA = ((size_t)E + 63) & ~(size_t)63;
    const int nb = (N + 1023) / 1024;       // scan blocks (<=256)

    float* ws   = (float*)d_ws;
    float* invd = ws;                             // NA floats
    int*   deg  = (int*)(ws + NA);                // NA ints
    int*   offs = deg + NA;                       // NA+64 ints
    int*   cur  = offs + NA + 64;                 // NA ints
    int*   bsum = cur + NA;                       // 256 ints
    int*   bpre = bsum + 256;                     // 256 ints
    int*   eidx = bpre + 256;                     // EA ints
    unsigned short* wtb = (unsigned short*)(eidx + EA);
    unsigned short* WTh1 = wtb;                   // 128*256
    unsigned short* WTl1 = WTh1 + 128 * 256;
    unsigned short* WTh2 = WTl1 + 128 * 256;
    unsigned short* WTl2 = WTh2 + 128 * 256;
    unsigned short* WTh3 = WTl2 + 128 * 256;      // 64*256
    unsigned short* WTl3 = WTh3 + 64 * 256;
    float* bufM = (float*)(WTl3 + 64 * 256);      // NA*128 fp32 mean scratch
    unsigned short* bfA = (unsigned short*)(bufM + NA * FEAT);  // NA*128 bf16
    unsigned short* bfB = bfA + NA * FEAT;                      // NA*128 bf16
    float* outp = (float*)d_out;

    const int gblocks = (N + 3) / 4;
    const int dblocks = (N + 255) / 256;
    const int rsize   = (N + 7) / 8;              // dst-range size per XCD
    const int fblocks = ((E + FCH - 1) / FCH) * 8;

    // ---- CSR build + weight prep (once per launch) ----
    hipMemsetAsync(deg, 0, (size_t)N * 4, stream);
    deg_kernel<<<(E + 255) / 256, 256, 0, stream>>>(dst, deg, E);
    blockred_kernel<<<nb, 256, 0, stream>>>(deg, bsum, N);
    scanb_kernel<<<1, 256, 0, stream>>>(bsum, bpre, nb);
    scanfill_kernel<<<nb, 256, 0, stream>>>(deg, bpre, offs, cur, invd, N, E);
    fill_xcd_kernel<<<fblocks, 256, 0, stream>>>(src, dst, cur, eidx, E, rsize);
    prep_wt<<<(128 * 256 + 255) / 256, 256, 0, stream>>>(W1l, W1r, WTh1, WTl1, 128);
    prep_wt<<<(128 * 256 + 255) / 256, 256, 0, stream>>>(W2l, W2r, WTh2, WTl2, 128);
    prep_wt<<<(64 * 256 + 255) / 256, 256, 0, stream>>>(W3l, W3r, WTh3, WTl3, 64);
    f2bf_kernel<<<(N * FEAT / 4 + 255) / 256, 256, 0, stream>>>(x, bfA, N * FEAT / 4);

    // layer 1: gather(xbf=bfA) -> M ; h1bf = dense(M, bfA) -> bfB
    gather_bf_kernel<<<gblocks, 256, 0, stream>>>(bfA, offs, eidx, invd, bufM, N);
    dense_mfma<128, true, false><<<dim3(dblocks, 2), 1024, 0, stream>>>(bufM, bfA, WTh1, WTl1, b1, nullptr, bfB, N);

    // layer 2: gather(h1bf=bfB) -> M ; h2bf = dense(M, bfB) -> bfA
    gather_bf_kernel<<<gblocks, 256, 0, stream>>>(bfB, offs, eidx, invd, bufM, N);
    dense_mfma<128, true, false><<<dim3(dblocks, 2), 1024, 0, stream>>>(bufM, bfB, WTh2, WTl2, b2, nullptr, bfA, N);

    // layer 3: gather(h2bf=bfA) -> M ; out = log_softmax(elu(dense(M, bfA))) -> d_out
    gather_bf_kernel<<<gblocks, 256, 0, stream>>>(bfA, offs, eidx, invd, bufM, N);
    dense_mfma<64, false, true><<<dim3(dblocks, 1), 1024, 0, stream>>>(bufM, bfA, WTh3, WTl3, b3, outp, nullptr, N);
}

// Round 12
// 252.243 us; speedup vs baseline: 1.4117x; 1.0257x over previous
//
#include <hip/hip_runtime.h>
#include <math.h>

constexpr int FEAT = 128;   // DIN == DH == 128

typedef __attribute__((ext_vector_type(8))) short short8v;   // 8 bf16 raw / 16 B
typedef __attribute__((ext_vector_type(4))) float f32x4;
typedef __attribute__((ext_vector_type(2))) float f32x2;
typedef __attribute__((ext_vector_type(4))) int   int4v;

// ---- fp32 -> bf16 (RNE) helpers ----
__device__ inline unsigned short f2bf(float f) {
    unsigned int u = __float_as_uint(f);
    u += 0x7fffu + ((u >> 16) & 1u);
    return (unsigned short)(u >> 16);
}
__device__ inline float bf2f(unsigned short h) {
    return __uint_as_float(((unsigned int)h) << 16);
}
__device__ inline unsigned char f2fp8(float f) {
    int r = __builtin_amdgcn_cvt_pk_fp8_f32(f, 0.f, 0, false);
    return (unsigned char)(r & 0xff);
}
__device__ inline void split8(const float4 v0, const float4 v1, short8v& h, short8v& lo) {
    const float* f = (const float*)&v0;
    unsigned short hh[8], ll[8];
    #pragma unroll
    for (int i = 0; i < 4; ++i) {
        hh[i] = f2bf(f[i]); ll[i] = f2bf(f[i] - bf2f(hh[i]));
    }
    const float* g = (const float*)&v1;
    #pragma unroll
    for (int i = 0; i < 4; ++i) {
        hh[4 + i] = f2bf(g[i]); ll[4 + i] = f2bf(g[i] - bf2f(hh[4 + i]));
    }
    h  = *(short8v*)hh;
    lo = *(short8v*)ll;
}

// ---------------- degree histogram (int) ----------------
__global__ void deg_kernel(const int* __restrict__ dst, int* __restrict__ degi, int E) {
    int e = blockIdx.x * 256 + threadIdx.x;
    if (e < E) atomicAdd(&degi[__builtin_nontemporal_load(dst + e)], 1);
}

// ---------------- hierarchical exclusive scan (1024 elems / block) ----------------
__global__ __launch_bounds__(256) void blockred_kernel(const int* __restrict__ deg,
                                                       int* __restrict__ bsum, int n) {
    __shared__ int red[256];
    int base = blockIdx.x * 1024 + threadIdx.x * 4;
    int s = 0;
    if (base + 3 < n) {
        int4 v = *(const int4*)(deg + base);
        s = v.x + v.y + v.z + v.w;
    } else {
        for (int i = 0; i < 4; ++i) if (base + i < n) s += deg[base + i];
    }
    red[threadIdx.x] = s;
    __syncthreads();
    for (int st = 128; st > 0; st >>= 1) {
        if (threadIdx.x < st) red[threadIdx.x] += red[threadIdx.x + st];
        __syncthreads();
    }
    if (threadIdx.x == 0) bsum[blockIdx.x] = red[0];
}

// 1 block, 256 threads; nb <= 256 (N <= 262144)
__global__ __launch_bounds__(256) void scanb_kernel(const int* __restrict__ bsum,
                                                    int* __restrict__ bpre, int nb) {
    __shared__ int part[256];
    int t = threadIdx.x;
    int v = (t < nb) ? bsum[t] : 0;
    part[t] = v;
    __syncthreads();
    for (int s = 1; s < 256; s <<= 1) {
        int u = (t >= s) ? part[t - s] : 0;
        __syncthreads();
        part[t] += u;
        __syncthreads();
    }
    if (t < nb) bpre[t] = part[t] - v;
}

__global__ __launch_bounds__(256) void scanfill_kernel(const int* __restrict__ deg,
                                                       const int* __restrict__ bpre,
                                                       int* __restrict__ offs,
                                                       int* __restrict__ cur,
                                                       float* __restrict__ invd,
                                                       int n, int E) {
    __shared__ int part[256];
    int t = threadIdx.x;
    int base = blockIdx.x * 1024 + t * 4;
    int d[4];
    int s = 0;
    #pragma unroll
    for (int i = 0; i < 4; ++i) {
        d[i] = (base + i < n) ? deg[base + i] : 0;
        s += d[i];
    }
    part[t] = s;
    __syncthreads();
    for (int st = 1; st < 256; st <<= 1) {
        int u = (t >= st) ? part[t - st] : 0;
        __syncthreads();
        part[t] += u;
        __syncthreads();
    }
    int pre = bpre[blockIdx.x] + part[t] - s;
    #pragma unroll
    for (int i = 0; i < 4; ++i) {
        int idx = base + i;
        if (idx < n) {
            offs[idx] = pre;
            cur[idx]  = pre;
            invd[idx] = 1.0f / fmaxf((float)d[i], 1.0f);
            pre += d[i];
        }
    }
    if (blockIdx.x == 0 && t == 0) offs[n] = E;
}

// ---------------- CSR fill, XCD-pinned dst ranges, NT streaming reads ----------------
// Range p handled only by blocks with blockIdx&7==p (round-robin -> one XCD);
// NT loads keep the streamed dst/src out of L2 so the scattered eidx write
// lines can accumulate to full lines before writeback.
constexpr int FCH = 4096;    // edges per chunk (1024 int4 per block)
__global__ __launch_bounds__(256) void fill_xcd_kernel(const int* __restrict__ src,
                                                       const int* __restrict__ dst,
                                                       int* __restrict__ cur,
                                                       int* __restrict__ eidx,
                                                       int E, int rsize) {
    const int p     = blockIdx.x & 7;
    const int chunk = blockIdx.x >> 3;
    const int lo = p * rsize;
    const int hi = lo + rsize;
    #pragma unroll
    for (int it = 0; it < 4; ++it) {
        int e = chunk * FCH + (it * 256 + threadIdx.x) * 4;
        if (e + 3 < E) {
            int4v d4 = __builtin_nontemporal_load((const int4v*)(dst + e));
            #pragma unroll
            for (int q = 0; q < 4; ++q) {
                int d = d4[q];
                if (d >= lo && d < hi) {
                    int pos = atomicAdd(&cur[d], 1);
                    eidx[pos] = __builtin_nontemporal_load(src + e + q);
                }
            }
        } else {
            for (int q = 0; e + q < E && q < 4; ++q) {
                int d = dst[e + q];
                if (d >= lo && d < hi) {
                    int pos = atomicAdd(&cur[d], 1);
                    eidx[pos] = src[e + q];
                }
            }
        }
    }
}

// ---------------- W prep: split bf16 transpose WTh/WTl[c][k] of concat(Wl;Wr) ----------------
__global__ void prep_wt(const float* __restrict__ Wl, const float* __restrict__ Wr,
                        unsigned short* __restrict__ WTh, unsigned short* __restrict__ WTl,
                        int dout) {
    int idx = blockIdx.x * 256 + threadIdx.x;
    if (idx >= dout * 256) return;
    int c = idx >> 8;
    int k = idx & 255;
    float v = (k < 128) ? Wl[(size_t)k * dout + c] : Wr[(size_t)(k - 128) * dout + c];
    unsigned short h = f2bf(v);
    WTh[(size_t)c * 256 + k] = h;
    WTl[(size_t)c * 256 + k] = f2bf(v - bf2f(h));
}

// ---------------- fp32 -> bf16 + fp8 convert (x -> xbf, xf8) ----------------
__global__ void f2bf8_kernel(const float* __restrict__ in, unsigned short* __restrict__ outbf,
                             unsigned char* __restrict__ outf8, int total4) {
    int i = blockIdx.x * 256 + threadIdx.x;
    if (i >= total4) return;
    float4 v = *(const float4*)(in + (size_t)i * 4);
    ushort4 h;
    h.x = f2bf(v.x); h.y = f2bf(v.y); h.z = f2bf(v.z); h.w = f2bf(v.w);
    *(ushort4*)(outbf + (size_t)i * 4) = h;
    uchar4 c;
    c.x = f2fp8(v.x); c.y = f2fp8(v.y); c.z = f2fp8(v.z); c.w = f2fp8(v.w);
    *(uchar4*)(outf8 + (size_t)i * 4) = c;
}

// ---------------- gather mean from bf16 feats (layer 3) ----------------
__global__ __launch_bounds__(256) void gather_bf_kernel(const unsigned short* __restrict__ featbf,
                                                        const int* __restrict__ offs,
                                                        const int* __restrict__ eidx,
                                                        const float* __restrict__ invd,
                                                        float* __restrict__ agg, int n) {
    int node = blockIdx.x * 4 + (threadIdx.x >> 6);
    if (node >= n) return;
    const int l   = threadIdx.x & 63;
    const int grp = l >> 4;
    const int li  = l & 15;
    const int c8  = li * 8;
    int beg = offs[node], end = offs[node + 1];
    float acc[8];
    #pragma unroll
    for (int q = 0; q < 8; ++q) acc[q] = 0.f;

    int j = beg + grp;
    for (; j + 4 < end; j += 8) {
        int s0 = eidx[j], s1 = eidx[j + 4];
        short8v v0 = *(const short8v*)(featbf + (size_t)s0 * FEAT + c8);
        short8v v1 = *(const short8v*)(featbf + (size_t)s1 * FEAT + c8);
        #pragma unroll
        for (int q = 0; q < 8; ++q) {
            acc[q] += __uint_as_float(((unsigned)(unsigned short)v0[q]) << 16);
            acc[q] += __uint_as_float(((unsigned)(unsigned short)v1[q]) << 16);
        }
    }
    if (j < end) {
        int s0 = eidx[j];
        short8v v0 = *(const short8v*)(featbf + (size_t)s0 * FEAT + c8);
        #pragma unroll
        for (int q = 0; q < 8; ++q)
            acc[q] += __uint_as_float(((unsigned)(unsigned short)v0[q]) << 16);
    }

    #pragma unroll
    for (int off = 16; off < 64; off <<= 1)
        #pragma unroll
        for (int q = 0; q < 8; ++q)
            acc[q] += __shfl_xor(acc[q], off, 64);

    if (grp == 0) {
        float sc = invd[node];
        float4 r0, r1;
        r0.x = acc[0] * sc; r0.y = acc[1] * sc; r0.z = acc[2] * sc; r0.w = acc[3] * sc;
        r1.x = acc[4] * sc; r1.y = acc[5] * sc; r1.z = acc[6] * sc; r1.w = acc[7] * sc;
        float* p = agg + (size_t)node * FEAT + c8;
        *(float4*)p = r0;
        *(float4*)(p + 4) = r1;
    }
}

// ---------------- gather mean from fp8 feats (layers 1,2): 8 B/lane ----------------
__global__ __launch_bounds__(256) void gather_f8_kernel(const unsigned char* __restrict__ featf8,
                                                        const int* __restrict__ offs,
                                                        const int* __restrict__ eidx,
                                                        const float* __restrict__ invd,
                                                        float* __restrict__ agg, int n) {
    int node = blockIdx.x * 4 + (threadIdx.x >> 6);
    if (node >= n) return;
    const int l   = threadIdx.x & 63;
    const int grp = l >> 4;
    const int li  = l & 15;
    const int c8  = li * 8;
    int beg = offs[node], end = offs[node + 1];
    float acc[8];
    #pragma unroll
    for (int q = 0; q < 8; ++q) acc[q] = 0.f;

    int j = beg + grp;
    for (; j + 4 < end; j += 8) {
        int s0 = eidx[j], s1 = eidx[j + 4];
        uint2 v0 = *(const uint2*)(featf8 + (size_t)s0 * FEAT + c8);
        uint2 v1 = *(const uint2*)(featf8 + (size_t)s1 * FEAT + c8);
        f32x2 p;
        p = __builtin_amdgcn_cvt_pk_f32_fp8(v0.x, false); acc[0] += p.x; acc[1] += p.y;
        p = __builtin_amdgcn_cvt_pk_f32_fp8(v0.x, true);  acc[2] += p.x; acc[3] += p.y;
        p = __builtin_amdgcn_cvt_pk_f32_fp8(v0.y, false); acc[4] += p.x; acc[5] += p.y;
        p = __builtin_amdgcn_cvt_pk_f32_fp8(v0.y, true);  acc[6] += p.x; acc[7] += p.y;
        p = __builtin_amdgcn_cvt_pk_f32_fp8(v1.x, false); acc[0] += p.x; acc[1] += p.y;
        p = __builtin_amdgcn_cvt_pk_f32_fp8(v1.x, true);  acc[2] += p.x; acc[3] += p.y;
        p = __builtin_amdgcn_cvt_pk_f32_fp8(v1.y, false); acc[4] += p.x; acc[5] += p.y;
        p = __builtin_amdgcn_cvt_pk_f32_fp8(v1.y, true);  acc[6] += p.x; acc[7] += p.y;
    }
    if (j < end) {
        int s0 = eidx[j];
        uint2 v0 = *(const uint2*)(featf8 + (size_t)s0 * FEAT + c8);
        f32x2 p;
        p = __builtin_amdgcn_cvt_pk_f32_fp8(v0.x, false); acc[0] += p.x; acc[1] += p.y;
        p = __builtin_amdgcn_cvt_pk_f32_fp8(v0.x, true);  acc[2] += p.x; acc[3] += p.y;
        p = __builtin_amdgcn_cvt_pk_f32_fp8(v0.y, false); acc[4] += p.x; acc[5] += p.y;
        p = __builtin_amdgcn_cvt_pk_f32_fp8(v0.y, true);  acc[6] += p.x; acc[7] += p.y;
    }

    #pragma unroll
    for (int off = 16; off < 64; off <<= 1)
        #pragma unroll
        for (int q = 0; q < 8; ++q)
            acc[q] += __shfl_xor(acc[q], off, 64);

    if (grp == 0) {
        float sc = invd[node];
        float4 r0, r1;
        r0.x = acc[0] * sc; r0.y = acc[1] * sc; r0.z = acc[2] * sc; r0.w = acc[3] * sc;
        r1.x = acc[4] * sc; r1.y = acc[5] * sc; r1.z = acc[6] * sc; r1.w = acc[7] * sc;
        float* p = agg + (size_t)node * FEAT + c8;
        *(float4*)p = r0;
        *(float4*)(p + 4) = r1;
    }
}

// ---------------- MFMA dense, LDS-resident B, 64 cols/block ----------------
// out = elu([mean|x] @ W + b); K=256. mean (fp32): hi/lo split, 3 MFMAs;
// x (bf16): 2 MFMAs. Block = 1024 thr = 16 waves x 16 rows = 256 rows;
// blockIdx.y = 64-col half. B staged once into LDS (64 KB) XOR-swizzled.
// WBF: write bf16 activation copy; WF8: also write fp8 copy; LSM: fused
// log_softmax (requires DOUT=64, writes fp32 outf).
template <int DOUT, bool WBF, bool WF8, bool LSM>
__global__ __launch_bounds__(1024, 4) void dense_mfma(
    const float* __restrict__ mean, const unsigned short* __restrict__ xinbf,
    const unsigned short* __restrict__ WTh, const unsigned short* __restrict__ WTl,
    const float* __restrict__ bias,
    float* outf, unsigned short* outbf, unsigned char* outf8, int n)
{
    __shared__ unsigned short Bh[64 * 256];   // 32 KB
    __shared__ unsigned short Bl[64 * 256];   // 32 KB
    const int tid = threadIdx.x;
    const int colbase = blockIdx.y * 64;

    #pragma unroll
    for (int it = 0; it < 2; ++it) {
        int o  = (tid + it * 1024) * 8;       // ushort index, 16B granules
        int cl = o >> 8;                      // local col 0..63
        int k  = o & 255;
        size_t gsrc = (size_t)(colbase + cl) * 256 + k;
        int db = (o * 2) ^ ((cl & 7) << 4);   // swizzled byte offset
        *(short8v*)((char*)Bh + db) = *(const short8v*)(WTh + gsrc);
        *(short8v*)((char*)Bl + db) = *(const short8v*)(WTl + gsrc);
    }
    __syncthreads();

    const int l    = tid & 63;
    const int w    = tid >> 6;
    const int l15  = l & 15;
    const int lg   = l >> 4;
    const int row0 = blockIdx.x * 256 + w * 16;
    if (row0 >= n) return;                    // no barriers after this point
    const int g = row0 + l15;                 // this lane's A row

    f32x4 acc[4];
    #pragma unroll
    for (int ct = 0; ct < 4; ++ct) acc[ct] = (f32x4){0.f, 0.f, 0.f, 0.f};

    // ---- chunks 0..3: mean (fp32, hi/lo split, 3 MFMAs per ct) ----
    #pragma unroll
    for (int ch = 0; ch < 4; ++ch) {
        float4 v0 = make_float4(0.f, 0.f, 0.f, 0.f), v1 = v0;
        if (g < n) {
            const float* p = mean + (size_t)g * FEAT + ch * 32 + lg * 8;
            v0 = *(const float4*)p;
            v1 = *(const float4*)(p + 4);
        }
        short8v ah, al;
        split8(v0, v1, ah, al);
        #pragma unroll
        for (int ct = 0; ct < 4; ++ct) {
            int cl = ct * 16 + l15;
            int db = (cl * 512 + ch * 64 + lg * 16) ^ ((cl & 7) << 4);
            short8v bh = *(const short8v*)((const char*)Bh + db);
            short8v bl = *(const short8v*)((const char*)Bl + db);
            acc[ct] = __builtin_amdgcn_mfma_f32_16x16x32_bf16(ah, bh, acc[ct], 0, 0, 0);
            acc[ct] = __builtin_amdgcn_mfma_f32_16x16x32_bf16(ah, bl, acc[ct], 0, 0, 0);
            acc[ct] = __builtin_amdgcn_mfma_f32_16x16x32_bf16(al, bh, acc[ct], 0, 0, 0);
        }
    }
    // ---- chunks 4..7: x as bf16 (2 MFMAs per ct) ----
    #pragma unroll
    for (int ch = 4; ch < 8; ++ch) {
        short8v ah = (short8v){0,0,0,0,0,0,0,0};
        if (g < n) ah = *(const short8v*)(xinbf + (size_t)g * FEAT + (ch - 4) * 32 + lg * 8);
        #pragma unroll
        for (int ct = 0; ct < 4; ++ct) {
            int cl = ct * 16 + l15;
            int db = (cl * 512 + ch * 64 + lg * 16) ^ ((cl & 7) << 4);
            short8v bh = *(const short8v*)((const char*)Bh + db);
            short8v bl = *(const short8v*)((const char*)Bl + db);
            acc[ct] = __builtin_amdgcn_mfma_f32_16x16x32_bf16(ah, bh, acc[ct], 0, 0, 0);
            acc[ct] = __builtin_amdgcn_mfma_f32_16x16x32_bf16(ah, bl, acc[ct], 0, 0, 0);
        }
    }

    // ---- epilogue: bias + ELU (+ optional fused log_softmax) ----
    float t[4][4];
    #pragma unroll
    for (int ct = 0; ct < 4; ++ct) {
        float b = bias[colbase + ct * 16 + l15];
        #pragma unroll
        for (int q = 0; q < 4; ++q) {
            float v = acc[ct][q] + b;
            t[ct][q] = (v > 0.f) ? v : expm1f(v);
        }
    }
    if (LSM) {
        #pragma unroll
        for (int q = 0; q < 4; ++q) {
            float m = t[0][q];
            #pragma unroll
            for (int ct = 1; ct < 4; ++ct) m = fmaxf(m, t[ct][q]);
            #pragma unroll
            for (int s = 1; s < 16; s <<= 1) m = fmaxf(m, __shfl_xor(m, s, 64));
            float sum = 0.f;
            #pragma unroll
            for (int ct = 0; ct < 4; ++ct) sum += expf(t[ct][q] - m);
            #pragma unroll
            for (int s = 1; s < 16; s <<= 1) sum += __shfl_xor(sum, s, 64);
            float ls = m + logf(sum);
            #pragma unroll
            for (int ct = 0; ct < 4; ++ct) t[ct][q] -= ls;
        }
    }
    #pragma unroll
    for (int ct = 0; ct < 4; ++ct) {
        int col = colbase + ct * 16 + l15;
        #pragma unroll
        for (int q = 0; q < 4; ++q) {
            int grow = row0 + lg * 4 + q;
            if (grow < n) {
                if (WBF) outbf[(size_t)grow * DOUT + col] = f2bf(t[ct][q]);
                if (WF8) outf8[(size_t)grow * DOUT + col] = f2fp8(t[ct][q]);
                if (!WBF && !WF8) outf[(size_t)grow * DOUT + col] = t[ct][q];
            }
        }
    }
}

extern "C" void kernel_launch(void* const* d_in, const int* in_sizes, int n_in,
                              void* d_out, int out_size, void* d_ws, size_t ws_size,
                              hipStream_t stream) {
    const float* x   = (const float*)d_in[0];
    const float* W1l = (const float*)d_in[1];
    const float* W1r = (const float*)d_in[2];
    const float* b1  = (const float*)d_in[3];
    const float* W2l = (const float*)d_in[4];
    const float* W2r = (const float*)d_in[5];
    const float* b2  = (const float*)d_in[6];
    const float* W3l = (const float*)d_in[7];
    const float* W3r = (const float*)d_in[8];
    const float* b3  = (const float*)d_in[9];
    const int*   src = (const int*)d_in[10];
    const int*   dst = (const int*)d_in[11];

    const int N = in_sizes[0] / FEAT;
    const int E = in_sizes[10];

    const size_t NA = ((size_t)N + 63) & ~(size_t)63;
    const size_t EA = ((size_t)E + 63) & ~(size_t)63;
    const int nb = (N + 1023) / 1024;       // scan blocks (<=256)

    float* ws   = (float*)d_ws;
    float* invd = ws;                             // NA floats
    int*   deg  = (int*)(ws + NA);                // NA ints
    int*   offs = deg + NA;                       // NA+64 ints
    int*   cur  = offs + NA + 64;                 // NA ints
    int*   bsum = cur + NA;                       // 256 ints
    int*   bpre = bsum + 256;                     // 256 ints
    int*   eidx = bpre + 256;                     // EA ints
    unsigned short* wtb = (unsigned short*)(eidx + EA);
    unsigned short* WTh1 = wtb;                   // 128*256
    unsigned short* WTl1 = WTh1 + 128 * 256;
    unsigned short* WTh2 = WTl1 + 128 * 256;
    unsigned short* WTl2 = WTh2 + 128 * 256;
    unsigned short* WTh3 = WTl2 + 128 * 256;      // 64*256
    unsigned short* WTl3 = WTh3 + 64 * 256;
    float* bufM = (float*)(WTl3 + 64 * 256);      // NA*128 fp32 mean scratch
    unsigned short* bfA = (unsigned short*)(bufM + NA * FEAT);  // NA*128 bf16
    unsigned short* bfB = bfA + NA * FEAT;                      // NA*128 bf16
    unsigned char*  f8X = (unsigned char*)(bfB + NA * FEAT);    // NA*128 fp8
    float* outp = (float*)d_out;

    const int gblocks = (N + 3) / 4;
    const int dblocks = (N + 255) / 256;
    const int rsize   = (N + 7) / 8;              // dst-range size per XCD
    const int fblocks = ((E + FCH - 1) / FCH) * 8;

    // ---- CSR build + weight prep (once per launch) ----
    hipMemsetAsync(deg, 0, (size_t)N * 4, stream);
    deg_kernel<<<(E + 255) / 256, 256, 0, stream>>>(dst, deg, E);
    blockred_kernel<<<nb, 256, 0, stream>>>(deg, bsum, N);
    scanb_kernel<<<1, 256, 0, stream>>>(bsum, bpre, nb);
    scanfill_kernel<<<nb, 256, 0, stream>>>(deg, bpre, offs, cur, invd, N, E);
    fill_xcd_kernel<<<fblocks, 256, 0, stream>>>(src, dst, cur, eidx, E, rsize);
    prep_wt<<<(128 * 256 + 255) / 256, 256, 0, stream>>>(W1l, W1r, WTh1, WTl1, 128);
    prep_wt<<<(128 * 256 + 255) / 256, 256, 0, stream>>>(W2l, W2r, WTh2, WTl2, 128);
    prep_wt<<<(64 * 256 + 255) / 256, 256, 0, stream>>>(W3l, W3r, WTh3, WTl3, 64);
    f2bf8_kernel<<<(N * FEAT / 4 + 255) / 256, 256, 0, stream>>>(x, bfA, f8X, N * FEAT / 4);

    // layer 1: gather_f8(x_f8) -> M ; h1 = dense(M, x_bf) -> bfB (bf16) + f8X (fp8, overwrites x_f8)
    gather_f8_kernel<<<gblocks, 256, 0, stream>>>(f8X, offs, eidx, invd, bufM, N);
    dense_mfma<128, true, true, false><<<dim3(dblocks, 2), 1024, 0, stream>>>(bufM, bfA, WTh1, WTl1, b1, nullptr, bfB, f8X, N);

    // layer 2: gather_f8(h1_f8) -> M ; h2 = dense(M, h1_bf) -> bfA (bf16)
    gather_f8_kernel<<<gblocks, 256, 0, stream>>>(f8X, offs, eidx, invd, bufM, N);
    dense_mfma<128, true, false, false><<<dim3(dblocks, 2), 1024, 0, stream>>>(bufM, bfB, WTh2, WTl2, b2, nullptr, bfA, nullptr, N);

    // layer 3: gather_bf(h2_bf) -> M ; out = log_softmax(elu(dense(M, h2_bf))) -> d_out
    gather_bf_kernel<<<gblocks, 256, 0, stream>>>(bfA, offs, eidx, invd, bufM, N);
    dense_mfma<64, false, false, true><<<dim3(dblocks, 1), 1024, 0, stream>>>(bufM, bfA, WTh3, WTl3, b3, outp, nullptr, nullptr, N);
}

// Round 13
// 244.675 us; speedup vs baseline: 1.4553x; 1.0309x over previous
//
#include <hip/hip_runtime.h>
#include <math.h>

constexpr int FEAT = 128;   // DIN == DH == 128

typedef __attribute__((ext_vector_type(8))) short short8v;   // 8 bf16 raw / 16 B
typedef __attribute__((ext_vector_type(4))) float f32x4;
typedef __attribute__((ext_vector_type(2))) float f32x2;
typedef __attribute__((ext_vector_type(4))) int   int4v;

// ---- fp32 -> bf16 (RNE) helpers ----
__device__ inline unsigned short f2bf(float f) {
    unsigned int u = __float_as_uint(f);
    u += 0x7fffu + ((u >> 16) & 1u);
    return (unsigned short)(u >> 16);
}
__device__ inline float bf2f(unsigned short h) {
    return __uint_as_float(((unsigned int)h) << 16);
}
__device__ inline unsigned char f2fp8(float f) {
    int r = __builtin_amdgcn_cvt_pk_fp8_f32(f, 0.f, 0, false);
    return (unsigned char)(r & 0xff);
}
__device__ inline void split8(const float4 v0, const float4 v1, short8v& h, short8v& lo) {
    const float* f = (const float*)&v0;
    unsigned short hh[8], ll[8];
    #pragma unroll
    for (int i = 0; i < 4; ++i) {
        hh[i] = f2bf(f[i]); ll[i] = f2bf(f[i] - bf2f(hh[i]));
    }
    const float* g = (const float*)&v1;
    #pragma unroll
    for (int i = 0; i < 4; ++i) {
        hh[4 + i] = f2bf(g[i]); ll[4 + i] = f2bf(g[i] - bf2f(hh[4 + i]));
    }
    h  = *(short8v*)hh;
    lo = *(short8v*)ll;
}

// ---------------- degree histogram (int) ----------------
__global__ void deg_kernel(const int* __restrict__ dst, int* __restrict__ degi, int E) {
    int e = blockIdx.x * 256 + threadIdx.x;
    if (e < E) atomicAdd(&degi[__builtin_nontemporal_load(dst + e)], 1);
}

// ---------------- hierarchical exclusive scan (1024 elems / block) ----------------
__global__ __launch_bounds__(256) void blockred_kernel(const int* __restrict__ deg,
                                                       int* __restrict__ bsum, int n) {
    __shared__ int red[256];
    int base = blockIdx.x * 1024 + threadIdx.x * 4;
    int s = 0;
    if (base + 3 < n) {
        int4 v = *(const int4*)(deg + base);
        s = v.x + v.y + v.z + v.w;
    } else {
        for (int i = 0; i < 4; ++i) if (base + i < n) s += deg[base + i];
    }
    red[threadIdx.x] = s;
    __syncthreads();
    for (int st = 128; st > 0; st >>= 1) {
        if (threadIdx.x < st) red[threadIdx.x] += red[threadIdx.x + st];
        __syncthreads();
    }
    if (threadIdx.x == 0) bsum[blockIdx.x] = red[0];
}

// 1 block, 256 threads; nb <= 256 (N <= 262144)
__global__ __launch_bounds__(256) void scanb_kernel(const int* __restrict__ bsum,
                                                    int* __restrict__ bpre, int nb) {
    __shared__ int part[256];
    int t = threadIdx.x;
    int v = (t < nb) ? bsum[t] : 0;
    part[t] = v;
    __syncthreads();
    for (int s = 1; s < 256; s <<= 1) {
        int u = (t >= s) ? part[t - s] : 0;
        __syncthreads();
        part[t] += u;
        __syncthreads();
    }
    if (t < nb) bpre[t] = part[t] - v;
}

__global__ __launch_bounds__(256) void scanfill_kernel(const int* __restrict__ deg,
                                                       const int* __restrict__ bpre,
                                                       int* __restrict__ offs,
                                                       int* __restrict__ cur,
                                                       float* __restrict__ invd,
                                                       int n, int E) {
    __shared__ int part[256];
    int t = threadIdx.x;
    int base = blockIdx.x * 1024 + t * 4;
    int d[4];
    int s = 0;
    #pragma unroll
    for (int i = 0; i < 4; ++i) {
        d[i] = (base + i < n) ? deg[base + i] : 0;
        s += d[i];
    }
    part[t] = s;
    __syncthreads();
    for (int st = 1; st < 256; st <<= 1) {
        int u = (t >= st) ? part[t - st] : 0;
        __syncthreads();
        part[t] += u;
        __syncthreads();
    }
    int pre = bpre[blockIdx.x] + part[t] - s;
    #pragma unroll
    for (int i = 0; i < 4; ++i) {
        int idx = base + i;
        if (idx < n) {
            offs[idx] = pre;
            cur[idx]  = pre;
            invd[idx] = 1.0f / fmaxf((float)d[i], 1.0f);
            pre += d[i];
        }
    }
    if (blockIdx.x == 0 && t == 0) offs[n] = E;
}

// ---------------- CSR fill phase 1: per-chunk LDS bucket sort ----------------
// Chunk = 8192 edges/block. Buckets = dst>>9 (512 dsts each). Packed word:
// src (16b) | (dst&511)<<16 — requires N <= 65536. Output: chunkdata (sorted
// by bucket within chunk, written LINEARLY -> coalesced) + per-chunk bucket
// offset table. All global writes are full-line streaming.
__global__ __launch_bounds__(1024) void bucket_kernel(const int* __restrict__ src,
                                                      const int* __restrict__ dst,
                                                      unsigned int* __restrict__ chunkdata,
                                                      int* __restrict__ table,
                                                      int E, int nb) {
    __shared__ int cnt[128];
    __shared__ int part[128];
    __shared__ int sbase[128];
    __shared__ unsigned int sbuf[8192];
    const int t = threadIdx.x;
    const int c = blockIdx.x;
    const int e0 = c * 8192;

    if (t < 128) cnt[t] = 0;
    __syncthreads();

    unsigned int word[8];
    int bkt[8], rnk[8];
    #pragma unroll
    for (int it = 0; it < 2; ++it) {
        int e = e0 + it * 4096 + t * 4;
        int4 d4 = make_int4(0, 0, 0, 0), s4 = d4;
        if (e + 3 < E) {
            d4 = *(const int4*)(dst + e);
            s4 = *(const int4*)(src + e);
        } else {
            if (e + 0 < E) { d4.x = dst[e + 0]; s4.x = src[e + 0]; } else d4.x = -1;
            if (e + 1 < E) { d4.y = dst[e + 1]; s4.y = src[e + 1]; } else d4.y = -1;
            if (e + 2 < E) { d4.z = dst[e + 2]; s4.z = src[e + 2]; } else d4.z = -1;
            if (e + 3 < E) { d4.w = dst[e + 3]; s4.w = src[e + 3]; } else d4.w = -1;
        }
        int dd[4] = {d4.x, d4.y, d4.z, d4.w};
        int ss[4] = {s4.x, s4.y, s4.z, s4.w};
        #pragma unroll
        for (int q = 0; q < 4; ++q) {
            int i = it * 4 + q;
            int d = dd[q];
            if (d >= 0) {
                bkt[i]  = d >> 9;
                rnk[i]  = atomicAdd(&cnt[bkt[i]], 1);
                word[i] = (unsigned int)ss[q] | ((unsigned int)(d & 511) << 16);
            } else bkt[i] = -1;
        }
    }
    __syncthreads();

    // scan cnt[0..127] -> part (inclusive); sbase = exclusive
    if (t < 128) part[t] = cnt[t];
    __syncthreads();
    for (int s = 1; s < 128; s <<= 1) {
        int v = (t >= s && t < 128) ? part[t - s] : 0;
        __syncthreads();
        if (t < 128) part[t] += v;
        __syncthreads();
    }
    if (t < 128) sbase[t] = part[t] - cnt[t];
    __syncthreads();

    // table[c][b] = sbase[b] for b in 0..nb (sbase[nb] == total)
    if (t <= nb) table[(size_t)c * (nb + 1) + t] = sbase[t];

    // scatter into LDS, sorted by bucket
    #pragma unroll
    for (int i = 0; i < 8; ++i)
        if (bkt[i] >= 0) sbuf[sbase[bkt[i]] + rnk[i]] = word[i];
    __syncthreads();

    // linear dump (coalesced)
    const int total = part[127];
    for (int i = t; i < total; i += 1024)
        chunkdata[(size_t)c * 8192 + i] = sbuf[i];
}

// ---------------- CSR fill phase 2: per-bucket LDS counting-sort + flush ----------------
constexpr int P2CAP = 10240;   // bucket edges ~8192 +- 90; +22 sigma, w/ fallback
__global__ __launch_bounds__(1024) void fillsort_kernel(const unsigned int* __restrict__ chunkdata,
                                                        const int* __restrict__ table,
                                                        const int* __restrict__ offs,
                                                        int* __restrict__ eidx,
                                                        int n, int nch, int nb) {
    __shared__ int lcur[512];
    __shared__ int lbuf[P2CAP];
    const int b  = blockIdx.x;
    const int t  = threadIdx.x;
    const int lo = b << 9;
    const int hi = min(lo + 512, n);
    const int gbase = offs[lo];
    const int cnt_total = offs[hi] - gbase;

    for (int i = t; i < hi - lo; i += 1024) lcur[i] = offs[lo + i] - gbase;
    __syncthreads();

    const int w    = t >> 6;
    const int lane = t & 63;
    for (int c = w; c < nch; c += 16) {
        int o0 = table[(size_t)c * (nb + 1) + b];
        int o1 = table[(size_t)c * (nb + 1) + b + 1];
        for (int i = o0 + lane; i < o1; i += 64) {
            unsigned int wd = chunkdata[(size_t)c * 8192 + i];
            int s  = wd & 0xffff;
            int ld = (wd >> 16) & 511;
            int p  = atomicAdd(&lcur[ld], 1);
            if (p < P2CAP) lbuf[p] = s;
            else           eidx[gbase + p] = s;   // overflow fallback
        }
    }
    __syncthreads();

    const int m = min(cnt_total, P2CAP);
    for (int i = t; i < m; i += 1024) eidx[gbase + i] = lbuf[i];
}

// ---------------- fallback fill (N > 65536): XCD-pinned atomic scatter ----------------
constexpr int FCH = 4096;
__global__ __launch_bounds__(256) void fill_xcd_kernel(const int* __restrict__ src,
                                                       const int* __restrict__ dst,
                                                       int* __restrict__ cur,
                                                       int* __restrict__ eidx,
                                                       int E, int rsize) {
    const int p     = blockIdx.x & 7;
    const int chunk = blockIdx.x >> 3;
    const int lo = p * rsize;
    const int hi = lo + rsize;
    #pragma unroll
    for (int it = 0; it < 4; ++it) {
        int e = chunk * FCH + (it * 256 + threadIdx.x) * 4;
        if (e + 3 < E) {
            int4v d4 = __builtin_nontemporal_load((const int4v*)(dst + e));
            #pragma unroll
            for (int q = 0; q < 4; ++q) {
                int d = d4[q];
                if (d >= lo && d < hi) {
                    int pos = atomicAdd(&cur[d], 1);
                    eidx[pos] = __builtin_nontemporal_load(src + e + q);
                }
            }
        } else {
            for (int q = 0; e + q < E && q < 4; ++q) {
                int d = dst[e + q];
                if (d >= lo && d < hi) {
                    int pos = atomicAdd(&cur[d], 1);
                    eidx[pos] = src[e + q];
                }
            }
        }
    }
}

// ---------------- W prep: split bf16 transpose WTh/WTl[c][k] of concat(Wl;Wr) ----------------
__global__ void prep_wt(const float* __restrict__ Wl, const float* __restrict__ Wr,
                        unsigned short* __restrict__ WTh, unsigned short* __restrict__ WTl,
                        int dout) {
    int idx = blockIdx.x * 256 + threadIdx.x;
    if (idx >= dout * 256) return;
    int c = idx >> 8;
    int k = idx & 255;
    float v = (k < 128) ? Wl[(size_t)k * dout + c] : Wr[(size_t)(k - 128) * dout + c];
    unsigned short h = f2bf(v);
    WTh[(size_t)c * 256 + k] = h;
    WTl[(size_t)c * 256 + k] = f2bf(v - bf2f(h));
}

// ---------------- fp32 -> bf16 + fp8 convert (x -> xbf, xf8) ----------------
__global__ void f2bf8_kernel(const float* __restrict__ in, unsigned short* __restrict__ outbf,
                             unsigned char* __restrict__ outf8, int total4) {
    int i = blockIdx.x * 256 + threadIdx.x;
    if (i >= total4) return;
    float4 v = *(const float4*)(in + (size_t)i * 4);
    ushort4 h;
    h.x = f2bf(v.x); h.y = f2bf(v.y); h.z = f2bf(v.z); h.w = f2bf(v.w);
    *(ushort4*)(outbf + (size_t)i * 4) = h;
    uchar4 c;
    c.x = f2fp8(v.x); c.y = f2fp8(v.y); c.z = f2fp8(v.z); c.w = f2fp8(v.w);
    *(uchar4*)(outf8 + (size_t)i * 4) = c;
}

// ---------------- gather mean from bf16 feats (layer 3) ----------------
__global__ __launch_bounds__(256) void gather_bf_kernel(const unsigned short* __restrict__ featbf,
                                                        const int* __restrict__ offs,
                                                        const int* __restrict__ eidx,
                                                        const float* __restrict__ invd,
                                                        float* __restrict__ agg, int n) {
    int node = blockIdx.x * 4 + (threadIdx.x >> 6);
    if (node >= n) return;
    const int l   = threadIdx.x & 63;
    const int grp = l >> 4;
    const int li  = l & 15;
    const int c8  = li * 8;
    int beg = offs[node], end = offs[node + 1];
    float acc[8];
    #pragma unroll
    for (int q = 0; q < 8; ++q) acc[q] = 0.f;

    int j = beg + grp;
    for (; j + 4 < end; j += 8) {
        int s0 = eidx[j], s1 = eidx[j + 4];
        short8v v0 = *(const short8v*)(featbf + (size_t)s0 * FEAT + c8);
        short8v v1 = *(const short8v*)(featbf + (size_t)s1 * FEAT + c8);
        #pragma unroll
        for (int q = 0; q < 8; ++q) {
            acc[q] += __uint_as_float(((unsigned)(unsigned short)v0[q]) << 16);
            acc[q] += __uint_as_float(((unsigned)(unsigned short)v1[q]) << 16);
        }
    }
    if (j < end) {
        int s0 = eidx[j];
        short8v v0 = *(const short8v*)(featbf + (size_t)s0 * FEAT + c8);
        #pragma unroll
        for (int q = 0; q < 8; ++q)
            acc[q] += __uint_as_float(((unsigned)(unsigned short)v0[q]) << 16);
    }

    #pragma unroll
    for (int off = 16; off < 64; off <<= 1)
        #pragma unroll
        for (int q = 0; q < 8; ++q)
            acc[q] += __shfl_xor(acc[q], off, 64);

    if (grp == 0) {
        float sc = invd[node];
        float4 r0, r1;
        r0.x = acc[0] * sc; r0.y = acc[1] * sc; r0.z = acc[2] * sc; r0.w = acc[3] * sc;
        r1.x = acc[4] * sc; r1.y = acc[5] * sc; r1.z = acc[6] * sc; r1.w = acc[7] * sc;
        float* p = agg + (size_t)node * FEAT + c8;
        *(float4*)p = r0;
        *(float4*)(p + 4) = r1;
    }
}

// ---------------- gather mean from fp8 feats (layers 1,2): 8 B/lane ----------------
__global__ __launch_bounds__(256) void gather_f8_kernel(const unsigned char* __restrict__ featf8,
                                                        const int* __restrict__ offs,
                                                        const int* __restrict__ eidx,
                                                        const float* __restrict__ invd,
                                                        float* __restrict__ agg, int n) {
    int node = blockIdx.x * 4 + (threadIdx.x >> 6);
    if (node >= n) return;
    const int l   = threadIdx.x & 63;
    const int grp = l >> 4;
    const int li  = l & 15;
    const int c8  = li * 8;
    int beg = offs[node], end = offs[node + 1];
    float acc[8];
    #pragma unroll
    for (int q = 0; q < 8; ++q) acc[q] = 0.f;

    int j = beg + grp;
    for (; j + 4 < end; j += 8) {
        int s0 = eidx[j], s1 = eidx[j + 4];
        uint2 v0 = *(const uint2*)(featf8 + (size_t)s0 * FEAT + c8);
        uint2 v1 = *(const uint2*)(featf8 + (size_t)s1 * FEAT + c8);
        f32x2 p;
        p = __builtin_amdgcn_cvt_pk_f32_fp8(v0.x, false); acc[0] += p.x; acc[1] += p.y;
        p = __builtin_amdgcn_cvt_pk_f32_fp8(v0.x, true);  acc[2] += p.x; acc[3] += p.y;
        p = __builtin_amdgcn_cvt_pk_f32_fp8(v0.y, false); acc[4] += p.x; acc[5] += p.y;
        p = __builtin_amdgcn_cvt_pk_f32_fp8(v0.y, true);  acc[6] += p.x; acc[7] += p.y;
        p = __builtin_amdgcn_cvt_pk_f32_fp8(v1.x, false); acc[0] += p.x; acc[1] += p.y;
        p = __builtin_amdgcn_cvt_pk_f32_fp8(v1.x, true);  acc[2] += p.x; acc[3] += p.y;
        p = __builtin_amdgcn_cvt_pk_f32_fp8(v1.y, false); acc[4] += p.x; acc[5] += p.y;
        p = __builtin_amdgcn_cvt_pk_f32_fp8(v1.y, true);  acc[6] += p.x; acc[7] += p.y;
    }
    if (j < end) {
        int s0 = eidx[j];
        uint2 v0 = *(const uint2*)(featf8 + (size_t)s0 * FEAT + c8);
        f32x2 p;
        p = __builtin_amdgcn_cvt_pk_f32_fp8(v0.x, false); acc[0] += p.x; acc[1] += p.y;
        p = __builtin_amdgcn_cvt_pk_f32_fp8(v0.x, true);  acc[2] += p.x; acc[3] += p.y;
        p = __builtin_amdgcn_cvt_pk_f32_fp8(v0.y, false); acc[4] += p.x; acc[5] += p.y;
        p = __builtin_amdgcn_cvt_pk_f32_fp8(v0.y, true);  acc[6] += p.x; acc[7] += p.y;
    }

    #pragma unroll
    for (int off = 16; off < 64; off <<= 1)
        #pragma unroll
        for (int q = 0; q < 8; ++q)
            acc[q] += __shfl_xor(acc[q], off, 64);

    if (grp == 0) {
        float sc = invd[node];
        float4 r0, r1;
        r0.x = acc[0] * sc; r0.y = acc[1] * sc; r0.z = acc[2] * sc; r0.w = acc[3] * sc;
        r1.x = acc[4] * sc; r1.y = acc[5] * sc; r1.z = acc[6] * sc; r1.w = acc[7] * sc;
        float* p = agg + (size_t)node * FEAT + c8;
        *(float4*)p = r0;
        *(float4*)(p + 4) = r1;
    }
}

// ---------------- MFMA dense, LDS-resident B, 64 cols/block ----------------
template <int DOUT, bool WBF, bool WF8, bool LSM>
__global__ __launch_bounds__(1024, 4) void dense_mfma(
    const float* __restrict__ mean, const unsigned short* __restrict__ xinbf,
    const unsigned short* __restrict__ WTh, const unsigned short* __restrict__ WTl,
    const float* __restrict__ bias,
    float* outf, unsigned short* outbf, unsigned char* outf8, int n)
{
    __shared__ unsigned short Bh[64 * 256];   // 32 KB
    __shared__ unsigned short Bl[64 * 256];   // 32 KB
    const int tid = threadIdx.x;
    const int colbase = blockIdx.y * 64;

    #pragma unroll
    for (int it = 0; it < 2; ++it) {
        int o  = (tid + it * 1024) * 8;       // ushort index, 16B granules
        int cl = o >> 8;                      // local col 0..63
        int k  = o & 255;
        size_t gsrc = (size_t)(colbase + cl) * 256 + k;
        int db = (o * 2) ^ ((cl & 7) << 4);   // swizzled byte offset
        *(short8v*)((char*)Bh + db) = *(const short8v*)(WTh + gsrc);
        *(short8v*)((char*)Bl + db) = *(const short8v*)(WTl + gsrc);
    }
    __syncthreads();

    const int l    = tid & 63;
    const int w    = tid >> 6;
    const int l15  = l & 15;
    const int lg   = l >> 4;
    const int row0 = blockIdx.x * 256 + w * 16;
    if (row0 >= n) return;                    // no barriers after this point
    const int g = row0 + l15;                 // this lane's A row

    f32x4 acc[4];
    #pragma unroll
    for (int ct = 0; ct < 4; ++ct) acc[ct] = (f32x4){0.f, 0.f, 0.f, 0.f};

    // ---- chunks 0..3: mean (fp32, hi/lo split, 3 MFMAs per ct) ----
    #pragma unroll
    for (int ch = 0; ch < 4; ++ch) {
        float4 v0 = make_float4(0.f, 0.f, 0.f, 0.f), v1 = v0;
        if (g < n) {
            const float* p = mean + (size_t)g * FEAT + ch * 32 + lg * 8;
            v0 = *(const float4*)p;
            v1 = *(const float4*)(p + 4);
        }
        short8v ah, al;
        split8(v0, v1, ah, al);
        #pragma unroll
        for (int ct = 0; ct < 4; ++ct) {
            int cl = ct * 16 + l15;
            int db = (cl * 512 + ch * 64 + lg * 16) ^ ((cl & 7) << 4);
            short8v bh = *(const short8v*)((const char*)Bh + db);
            short8v bl = *(const short8v*)((const char*)Bl + db);
            acc[ct] = __builtin_amdgcn_mfma_f32_16x16x32_bf16(ah, bh, acc[ct], 0, 0, 0);
            acc[ct] = __builtin_amdgcn_mfma_f32_16x16x32_bf16(ah, bl, acc[ct], 0, 0, 0);
            acc[ct] = __builtin_amdgcn_mfma_f32_16x16x32_bf16(al, bh, acc[ct], 0, 0, 0);
        }
    }
    // ---- chunks 4..7: x as bf16 (2 MFMAs per ct) ----
    #pragma unroll
    for (int ch = 4; ch < 8; ++ch) {
        short8v ah = (short8v){0,0,0,0,0,0,0,0};
        if (g < n) ah = *(const short8v*)(xinbf + (size_t)g * FEAT + (ch - 4) * 32 + lg * 8);
        #pragma unroll
        for (int ct = 0; ct < 4; ++ct) {
            int cl = ct * 16 + l15;
            int db = (cl * 512 + ch * 64 + lg * 16) ^ ((cl & 7) << 4);
            short8v bh = *(const short8v*)((const char*)Bh + db);
            short8v bl = *(const short8v*)((const char*)Bl + db);
            acc[ct] = __builtin_amdgcn_mfma_f32_16x16x32_bf16(ah, bh, acc[ct], 0, 0, 0);
            acc[ct] = __builtin_amdgcn_mfma_f32_16x16x32_bf16(ah, bl, acc[ct], 0, 0, 0);
        }
    }

    // ---- epilogue: bias + ELU (+ optional fused log_softmax) ----
    float t[4][4];
    #pragma unroll
    for (int ct = 0; ct < 4; ++ct) {
        float b = bias[colbase + ct * 16 + l15];
        #pragma unroll
        for (int q = 0; q < 4; ++q) {
            float v = acc[ct][q] + b;
            t[ct][q] = (v > 0.f) ? v : expm1f(v);
        }
    }
    if (LSM) {
        #pragma unroll
        for (int q = 0; q < 4; ++q) {
            float m = t[0][q];
            #pragma unroll
            for (int ct = 1; ct < 4; ++ct) m = fmaxf(m, t[ct][q]);
            #pragma unroll
            for (int s = 1; s < 16; s <<= 1) m = fmaxf(m, __shfl_xor(m, s, 64));
            float sum = 0.f;
            #pragma unroll
            for (int ct = 0; ct < 4; ++ct) sum += expf(t[ct][q] - m);
            #pragma unroll
            for (int s = 1; s < 16; s <<= 1) sum += __shfl_xor(sum, s, 64);
            float ls = m + logf(sum);
            #pragma unroll
            for (int ct = 0; ct < 4; ++ct) t[ct][q] -= ls;
        }
    }
    #pragma unroll
    for (int ct = 0; ct < 4; ++ct) {
        int col = colbase + ct * 16 + l15;
        #pragma unroll
        for (int q = 0; q < 4; ++q) {
            int grow = row0 + lg * 4 + q;
            if (grow < n) {
                if (WBF) outbf[(size_t)grow * DOUT + col] = f2bf(t[ct][q]);
                if (WF8) outf8[(size_t)grow * DOUT + col] = f2fp8(t[ct][q]);
                if (!WBF && !WF8) outf[(size_t)grow * DOUT + col] = t[ct][q];
            }
        }
    }
}

extern "C" void kernel_launch(void* const* d_in, const int* in_sizes, int n_in,
                              void* d_out, int out_size, void* d_ws, size_t ws_size,
                              hipStream_t stream) {
    const float* x   = (const float*)d_in[0];
    const float* W1l = (const float*)d_in[1];
    const float* W1r = (const float*)d_in[2];
    const float* b1  = (const float*)d_in[3];
    const float* W2l = (const float*)d_in[4];
    const float* W2r = (const float*)d_in[5];
    const float* b2  = (const float*)d_in[6];
    const float* W3l = (const float*)d_in[7];
    const float* W3r = (const float*)d_in[8];
    const float* b3  = (const float*)d_in[9];
    const int*   src = (const int*)d_in[10];
    const int*   dst = (const int*)d_in[11];

    const int N = in_sizes[0] / FEAT;
    const int E = in_sizes[10];

    const size_t NA = ((size_t)N + 63) & ~(size_t)63;
    const size_t EA = ((size_t)E + 63) & ~(size_t)63;
    const int nb = (N + 1023) / 1024;       // scan blocks (<=256)
    const int nbk = (N + 511) >> 9;         // fill buckets (512 dsts each)
    const int nch = (E + 8191) / 8192;      // fill chunks

    float* ws   = (float*)d_ws;
    float* invd = ws;                             // NA floats
    int*   deg  = (int*)(ws + NA);                // NA ints
    int*   offs = deg + NA;                       // NA+64 ints
    int*   cur  = offs + NA + 64;                 // NA ints
    int*   bsum = cur + NA;                       // 256 ints
    int*   bpre = bsum + 256;                     // 256 ints
    int*   eidx = bpre + 256;                     // EA ints
    unsigned int* chunkd = (unsigned int*)(eidx + EA);          // nch*8192 uints
    int*   table = (int*)(chunkd + (size_t)nch * 8192 + 64);    // nch*(nbk+1) ints
    unsigned short* wtb = (unsigned short*)(table + (size_t)nch * (nbk + 1) + 64);
    unsigned short* WTh1 = wtb;                   // 128*256
    unsigned short* WTl1 = WTh1 + 128 * 256;
    unsigned short* WTh2 = WTl1 + 128 * 256;
    unsigned short* WTl2 = WTh2 + 128 * 256;
    unsigned short* WTh3 = WTl2 + 128 * 256;      // 64*256
    unsigned short* WTl3 = WTh3 + 64 * 256;
    float* bufM = (float*)(WTl3 + 64 * 256 + 64); // NA*128 fp32 mean scratch
    unsigned short* bfA = (unsigned short*)(bufM + NA * FEAT);  // NA*128 bf16
    unsigned short* bfB = bfA + NA * FEAT;                      // NA*128 bf16
    unsigned char*  f8X = (unsigned char*)(bfB + NA * FEAT);    // NA*128 fp8
    float* outp = (float*)d_out;

    const int gblocks = (N + 3) / 4;
    const int dblocks = (N + 255) / 256;

    // ---- CSR build + weight prep (once per launch) ----
    hipMemsetAsync(deg, 0, (size_t)N * 4, stream);
    deg_kernel<<<(E + 255) / 256, 256, 0, stream>>>(dst, deg, E);
    blockred_kernel<<<nb, 256, 0, stream>>>(deg, bsum, N);
    scanb_kernel<<<1, 256, 0, stream>>>(bsum, bpre, nb);
    scanfill_kernel<<<nb, 256, 0, stream>>>(deg, bpre, offs, cur, invd, N, E);
    if (N <= 65536) {
        bucket_kernel<<<nch, 1024, 0, stream>>>(src, dst, chunkd, table, E, nbk);
        fillsort_kernel<<<nbk, 1024, 0, stream>>>(chunkd, table, offs, eidx, N, nch, nbk);
    } else {
        const int rsize   = (N + 7) / 8;
        const int fblocks = ((E + FCH - 1) / FCH) * 8;
        fill_xcd_kernel<<<fblocks, 256, 0, stream>>>(src, dst, cur, eidx, E, rsize);
    }
    prep_wt<<<(128 * 256 + 255) / 256, 256, 0, stream>>>(W1l, W1r, WTh1, WTl1, 128);
    prep_wt<<<(128 * 256 + 255) / 256, 256, 0, stream>>>(W2l, W2r, WTh2, WTl2, 128);
    prep_wt<<<(64 * 256 + 255) / 256, 256, 0, stream>>>(W3l, W3r, WTh3, WTl3, 64);
    f2bf8_kernel<<<(N * FEAT / 4 + 255) / 256, 256, 0, stream>>>(x, bfA, f8X, N * FEAT / 4);

    // layer 1: gather_f8(x_f8) -> M ; h1 = dense(M, x_bf) -> bfB (bf16) + f8X (fp8)
    gather_f8_kernel<<<gblocks, 256, 0, stream>>>(f8X, offs, eidx, invd, bufM, N);
    dense_mfma<128, true, true, false><<<dim3(dblocks, 2), 1024, 0, stream>>>(bufM, bfA, WTh1, WTl1, b1, nullptr, bfB, f8X, N);

    // layer 2: gather_f8(h1_f8) -> M ; h2 = dense(M, h1_bf) -> bfA (bf16)
    gather_f8_kernel<<<gblocks, 256, 0, stream>>>(f8X, offs, eidx, invd, bufM, N);
    dense_mfma<128, true, false, false><<<dim3(dblocks, 2), 1024, 0, stream>>>(bufM, bfB, WTh2, WTl2, b2, nullptr, bfA, nullptr, N);

    // layer 3: gather_bf(h2_bf) -> M ; out = log_softmax(elu(dense(M, h2_bf))) -> d_out
    gather_bf_kernel<<<gblocks, 256, 0, stream>>>(bfA, offs, eidx, invd, bufM, N);
    dense_mfma<64, false, false, true><<<dim3(dblocks, 1), 1024, 0, stream>>>(bufM, bfA, WTh3, WTl3, b3, outp, nullptr, nullptr, N);
}

// Round 14
// 207.098 us; speedup vs baseline: 1.7194x; 1.1814x over previous
//
#include <hip/hip_runtime.h>
#include <math.h>

constexpr int FEAT = 128;   // DIN == DH == 128

typedef __attribute__((ext_vector_type(8))) short short8v;   // 8 bf16 raw / 16 B
typedef __attribute__((ext_vector_type(4))) float f32x4;
typedef __attribute__((ext_vector_type(2))) float f32x2;
typedef __attribute__((ext_vector_type(4))) int   int4v;

// ---- fp32 -> bf16 (RNE) / fp8 helpers ----
__device__ inline unsigned short f2bf(float f) {
    unsigned int u = __float_as_uint(f);
    u += 0x7fffu + ((u >> 16) & 1u);
    return (unsigned short)(u >> 16);
}
__device__ inline float bf2f(unsigned short h) {
    return __uint_as_float(((unsigned int)h) << 16);
}
__device__ inline unsigned char f2fp8(float f) {
    int r = __builtin_amdgcn_cvt_pk_fp8_f32(f, 0.f, 0, false);
    return (unsigned char)(r & 0xff);
}
__device__ inline void split8(const float4 v0, const float4 v1, short8v& h, short8v& lo) {
    const float* f = (const float*)&v0;
    unsigned short hh[8], ll[8];
    #pragma unroll
    for (int i = 0; i < 4; ++i) {
        hh[i] = f2bf(f[i]); ll[i] = f2bf(f[i] - bf2f(hh[i]));
    }
    const float* g = (const float*)&v1;
    #pragma unroll
    for (int i = 0; i < 4; ++i) {
        hh[4 + i] = f2bf(g[i]); ll[4 + i] = f2bf(g[i] - bf2f(hh[4 + i]));
    }
    h  = *(short8v*)hh;
    lo = *(short8v*)ll;
}

// ================= CSR build (N <= 65536 fast path) =================
// Phase 1: per-chunk LDS bucket sort. Chunk = 8192 edges/block; bucket = dst>>9.
// Packed word: src(16b) | (dst&511)<<16. Output written LINEARLY (coalesced).
__global__ __launch_bounds__(1024) void bucket_kernel(const int* __restrict__ src,
                                                      const int* __restrict__ dst,
                                                      unsigned int* __restrict__ chunkdata,
                                                      int* __restrict__ table,
                                                      int E, int nb) {
    __shared__ int cnt[128];
    __shared__ int part[128];
    __shared__ int sbase[128];
    __shared__ unsigned int sbuf[8192];
    const int t = threadIdx.x;
    const int c = blockIdx.x;
    const int e0 = c * 8192;

    if (t < 128) cnt[t] = 0;
    __syncthreads();

    unsigned int word[8];
    int bkt[8], rnk[8];
    #pragma unroll
    for (int it = 0; it < 2; ++it) {
        int e = e0 + it * 4096 + t * 4;
        int4 d4 = make_int4(0, 0, 0, 0), s4 = d4;
        if (e + 3 < E) {
            d4 = *(const int4*)(dst + e);
            s4 = *(const int4*)(src + e);
        } else {
            if (e + 0 < E) { d4.x = dst[e + 0]; s4.x = src[e + 0]; } else d4.x = -1;
            if (e + 1 < E) { d4.y = dst[e + 1]; s4.y = src[e + 1]; } else d4.y = -1;
            if (e + 2 < E) { d4.z = dst[e + 2]; s4.z = src[e + 2]; } else d4.z = -1;
            if (e + 3 < E) { d4.w = dst[e + 3]; s4.w = src[e + 3]; } else d4.w = -1;
        }
        int dd[4] = {d4.x, d4.y, d4.z, d4.w};
        int ss[4] = {s4.x, s4.y, s4.z, s4.w};
        #pragma unroll
        for (int q = 0; q < 4; ++q) {
            int i = it * 4 + q;
            int d = dd[q];
            if (d >= 0) {
                bkt[i]  = d >> 9;
                rnk[i]  = atomicAdd(&cnt[bkt[i]], 1);
                word[i] = (unsigned int)ss[q] | ((unsigned int)(d & 511) << 16);
            } else bkt[i] = -1;
        }
    }
    __syncthreads();

    if (t < 128) part[t] = cnt[t];
    __syncthreads();
    for (int s = 1; s < 128; s <<= 1) {
        int v = (t >= s && t < 128) ? part[t - s] : 0;
        __syncthreads();
        if (t < 128) part[t] += v;
        __syncthreads();
    }
    if (t < 128) sbase[t] = part[t] - cnt[t];
    __syncthreads();

    if (t <= nb) table[(size_t)c * (nb + 1) + t] = sbase[t];

    #pragma unroll
    for (int i = 0; i < 8; ++i)
        if (bkt[i] >= 0) sbuf[sbase[bkt[i]] + rnk[i]] = word[i];
    __syncthreads();

    const int total = part[127];
    for (int i = t; i < total; i += 1024)
        chunkdata[(size_t)c * 8192 + i] = sbuf[i];
}

// Bucket totals -> exclusive bases (1 block). Also writes offs[n] = E.
__global__ __launch_bounds__(256) void btot_kernel(const int* __restrict__ table,
                                                   int* __restrict__ bbase,
                                                   int* __restrict__ offs,
                                                   int nch, int nbk, int n, int E) {
    __shared__ int part[256];
    const int t = threadIdx.x;
    int tot = 0;
    if (t < nbk) {
        for (int c = 0; c < nch; ++c)
            tot += table[(size_t)c * (nbk + 1) + t + 1] - table[(size_t)c * (nbk + 1) + t];
    }
    part[t] = tot;
    __syncthreads();
    for (int s = 1; s < 256; s <<= 1) {
        int u = (t >= s) ? part[t - s] : 0;
        __syncthreads();
        part[t] += u;
        __syncthreads();
    }
    if (t < nbk) bbase[t] = part[t] - tot;
    if (t == 0) { bbase[nbk] = E; offs[n] = E; }
}

// Phase 2: per-bucket two-pass counting sort. Pass 1 counts degrees -> writes
// offs/invd; pass 2 places into LDS; contiguous flush. All heavy I/O coalesced
// or L2-resident.
constexpr int P2CAP = 10240;   // bucket ~8192 +- 90; 22 sigma + fallback
__global__ __launch_bounds__(1024) void fillsort_kernel(const unsigned int* __restrict__ chunkdata,
                                                        const int* __restrict__ table,
                                                        const int* __restrict__ bbase,
                                                        int* __restrict__ offs,
                                                        float* __restrict__ invd,
                                                        int* __restrict__ eidx,
                                                        int n, int nch, int nbk) {
    __shared__ int cnt[512];
    __shared__ int lcur[512];
    __shared__ int part[512];
    __shared__ int lbuf[P2CAP];
    const int b  = blockIdx.x;
    const int t  = threadIdx.x;
    const int lo = b << 9;
    const int base = bbase[b];

    for (int i = t; i < 512; i += 1024) cnt[i] = 0;
    __syncthreads();

    const int w    = t >> 6;
    const int lane = t & 63;
    // pass 1: count degrees
    for (int c = w; c < nch; c += 16) {
        int o0 = table[(size_t)c * (nbk + 1) + b];
        int o1 = table[(size_t)c * (nbk + 1) + b + 1];
        for (int i = o0 + lane; i < o1; i += 64)
            atomicAdd(&cnt[(chunkdata[(size_t)c * 8192 + i] >> 16) & 511], 1);
    }
    __syncthreads();

    // scan 512 counts (threads 0..511)
    int v = (t < 512) ? cnt[t] : 0;
    if (t < 512) part[t] = v;
    __syncthreads();
    for (int s = 1; s < 512; s <<= 1) {
        int u = (t >= s && t < 512) ? part[t - s] : 0;
        __syncthreads();
        if (t < 512) part[t] += u;
        __syncthreads();
    }
    if (t < 512) {
        int ex = part[t] - v;
        lcur[t] = ex;
        int idx = lo + t;
        if (idx < n) {
            offs[idx] = base + ex;
            invd[idx] = 1.0f / fmaxf((float)v, 1.0f);
        }
    }
    __syncthreads();

    // pass 2: place
    for (int c = w; c < nch; c += 16) {
        int o0 = table[(size_t)c * (nbk + 1) + b];
        int o1 = table[(size_t)c * (nbk + 1) + b + 1];
        for (int i = o0 + lane; i < o1; i += 64) {
            unsigned int wd = chunkdata[(size_t)c * 8192 + i];
            int s = wd & 0xffff;
            int p = atomicAdd(&lcur[(wd >> 16) & 511], 1);
            if (p < P2CAP) lbuf[p] = s;
            else           eidx[base + p] = s;   // overflow fallback
        }
    }
    __syncthreads();

    const int m = min(bbase[b + 1] - base, P2CAP);
    for (int i = t; i < m; i += 1024) eidx[base + i] = lbuf[i];
}

// ================= CSR build fallback (N > 65536) =================
__global__ void deg_kernel(const int* __restrict__ dst, int* __restrict__ degi, int E) {
    int e = blockIdx.x * 256 + threadIdx.x;
    if (e < E) atomicAdd(&degi[__builtin_nontemporal_load(dst + e)], 1);
}
__global__ __launch_bounds__(256) void blockred_kernel(const int* __restrict__ deg,
                                                       int* __restrict__ bsum, int n) {
    __shared__ int red[256];
    int base = blockIdx.x * 1024 + threadIdx.x * 4;
    int s = 0;
    if (base + 3 < n) {
        int4 v = *(const int4*)(deg + base);
        s = v.x + v.y + v.z + v.w;
    } else {
        for (int i = 0; i < 4; ++i) if (base + i < n) s += deg[base + i];
    }
    red[threadIdx.x] = s;
    __syncthreads();
    for (int st = 128; st > 0; st >>= 1) {
        if (threadIdx.x < st) red[threadIdx.x] += red[threadIdx.x + st];
        __syncthreads();
    }
    if (threadIdx.x == 0) bsum[blockIdx.x] = red[0];
}
__global__ __launch_bounds__(256) void scanb_kernel(const int* __restrict__ bsum,
                                                    int* __restrict__ bpre, int nb) {
    __shared__ int part[256];
    int t = threadIdx.x;
    int v = (t < nb) ? bsum[t] : 0;
    part[t] = v;
    __syncthreads();
    for (int s = 1; s < 256; s <<= 1) {
        int u = (t >= s) ? part[t - s] : 0;
        __syncthreads();
        part[t] += u;
        __syncthreads();
    }
    if (t < nb) bpre[t] = part[t] - v;
}
__global__ __launch_bounds__(256) void scanfill_kernel(const int* __restrict__ deg,
                                                       const int* __restrict__ bpre,
                                                       int* __restrict__ offs,
                                                       int* __restrict__ cur,
                                                       float* __restrict__ invd,
                                                       int n, int E) {
    __shared__ int part[256];
    int t = threadIdx.x;
    int base = blockIdx.x * 1024 + t * 4;
    int d[4];
    int s = 0;
    #pragma unroll
    for (int i = 0; i < 4; ++i) {
        d[i] = (base + i < n) ? deg[base + i] : 0;
        s += d[i];
    }
    part[t] = s;
    __syncthreads();
    for (int st = 1; st < 256; st <<= 1) {
        int u = (t >= st) ? part[t - st] : 0;
        __syncthreads();
        part[t] += u;
        __syncthreads();
    }
    int pre = bpre[blockIdx.x] + part[t] - s;
    #pragma unroll
    for (int i = 0; i < 4; ++i) {
        int idx = base + i;
        if (idx < n) {
            offs[idx] = pre;
            cur[idx]  = pre;
            invd[idx] = 1.0f / fmaxf((float)d[i], 1.0f);
            pre += d[i];
        }
    }
    if (blockIdx.x == 0 && t == 0) offs[n] = E;
}
constexpr int FCH = 4096;
__global__ __launch_bounds__(256) void fill_xcd_kernel(const int* __restrict__ src,
                                                       const int* __restrict__ dst,
                                                       int* __restrict__ cur,
                                                       int* __restrict__ eidx,
                                                       int E, int rsize) {
    const int p     = blockIdx.x & 7;
    const int chunk = blockIdx.x >> 3;
    const int lo = p * rsize;
    const int hi = lo + rsize;
    #pragma unroll
    for (int it = 0; it < 4; ++it) {
        int e = chunk * FCH + (it * 256 + threadIdx.x) * 4;
        if (e + 3 < E) {
            int4v d4 = __builtin_nontemporal_load((const int4v*)(dst + e));
            #pragma unroll
            for (int q = 0; q < 4; ++q) {
                int d = d4[q];
                if (d >= lo && d < hi) {
                    int pos = atomicAdd(&cur[d], 1);
                    eidx[pos] = __builtin_nontemporal_load(src + e + q);
                }
            }
        } else {
            for (int q = 0; e + q < E && q < 4; ++q) {
                int d = dst[e + q];
                if (d >= lo && d < hi) {
                    int pos = atomicAdd(&cur[d], 1);
                    eidx[pos] = src[e + q];
                }
            }
        }
    }
}

// ================= weight / feature prep =================
__global__ void prep_wt(const float* __restrict__ Wl, const float* __restrict__ Wr,
                        unsigned short* __restrict__ WTh, unsigned short* __restrict__ WTl,
                        int dout) {
    int idx = blockIdx.x * 256 + threadIdx.x;
    if (idx >= dout * 256) return;
    int c = idx >> 8;
    int k = idx & 255;
    float v = (k < 128) ? Wl[(size_t)k * dout + c] : Wr[(size_t)(k - 128) * dout + c];
    unsigned short h = f2bf(v);
    WTh[(size_t)c * 256 + k] = h;
    WTl[(size_t)c * 256 + k] = f2bf(v - bf2f(h));
}

__global__ void f2bf8_kernel(const float* __restrict__ in, unsigned short* __restrict__ outbf,
                             unsigned char* __restrict__ outf8, int total4) {
    int i = blockIdx.x * 256 + threadIdx.x;
    if (i >= total4) return;
    float4 v = *(const float4*)(in + (size_t)i * 4);
    ushort4 h;
    h.x = f2bf(v.x); h.y = f2bf(v.y); h.z = f2bf(v.z); h.w = f2bf(v.w);
    *(ushort4*)(outbf + (size_t)i * 4) = h;
    uchar4 c;
    c.x = f2fp8(v.x); c.y = f2fp8(v.y); c.z = f2fp8(v.z); c.w = f2fp8(v.w);
    *(uchar4*)(outf8 + (size_t)i * 4) = c;
}

// ================= gather mean from fp8 feats: 8 B/lane, 4 edges in flight =================
__global__ __launch_bounds__(256) void gather_f8_kernel(const unsigned char* __restrict__ featf8,
                                                        const int* __restrict__ offs,
                                                        const int* __restrict__ eidx,
                                                        const float* __restrict__ invd,
                                                        float* __restrict__ agg, int n) {
    int node = blockIdx.x * 4 + (threadIdx.x >> 6);
    if (node >= n) return;
    const int l   = threadIdx.x & 63;
    const int grp = l >> 4;
    const int li  = l & 15;
    const int c8  = li * 8;
    int beg = offs[node], end = offs[node + 1];
    float acc[8];
    #pragma unroll
    for (int q = 0; q < 8; ++q) acc[q] = 0.f;

    int j = beg + grp;
    for (; j + 4 < end; j += 8) {
        int s0 = eidx[j], s1 = eidx[j + 4];
        uint2 v0 = *(const uint2*)(featf8 + (size_t)s0 * FEAT + c8);
        uint2 v1 = *(const uint2*)(featf8 + (size_t)s1 * FEAT + c8);
        f32x2 p;
        p = __builtin_amdgcn_cvt_pk_f32_fp8(v0.x, false); acc[0] += p.x; acc[1] += p.y;
        p = __builtin_amdgcn_cvt_pk_f32_fp8(v0.x, true);  acc[2] += p.x; acc[3] += p.y;
        p = __builtin_amdgcn_cvt_pk_f32_fp8(v0.y, false); acc[4] += p.x; acc[5] += p.y;
        p = __builtin_amdgcn_cvt_pk_f32_fp8(v0.y, true);  acc[6] += p.x; acc[7] += p.y;
        p = __builtin_amdgcn_cvt_pk_f32_fp8(v1.x, false); acc[0] += p.x; acc[1] += p.y;
        p = __builtin_amdgcn_cvt_pk_f32_fp8(v1.x, true);  acc[2] += p.x; acc[3] += p.y;
        p = __builtin_amdgcn_cvt_pk_f32_fp8(v1.y, false); acc[4] += p.x; acc[5] += p.y;
        p = __builtin_amdgcn_cvt_pk_f32_fp8(v1.y, true);  acc[6] += p.x; acc[7] += p.y;
    }
    if (j < end) {
        int s0 = eidx[j];
        uint2 v0 = *(const uint2*)(featf8 + (size_t)s0 * FEAT + c8);
        f32x2 p;
        p = __builtin_amdgcn_cvt_pk_f32_fp8(v0.x, false); acc[0] += p.x; acc[1] += p.y;
        p = __builtin_amdgcn_cvt_pk_f32_fp8(v0.x, true);  acc[2] += p.x; acc[3] += p.y;
        p = __builtin_amdgcn_cvt_pk_f32_fp8(v0.y, false); acc[4] += p.x; acc[5] += p.y;
        p = __builtin_amdgcn_cvt_pk_f32_fp8(v0.y, true);  acc[6] += p.x; acc[7] += p.y;
    }

    #pragma unroll
    for (int off = 16; off < 64; off <<= 1)
        #pragma unroll
        for (int q = 0; q < 8; ++q)
            acc[q] += __shfl_xor(acc[q], off, 64);

    if (grp == 0) {
        float sc = invd[node];
        float4 r0, r1;
        r0.x = acc[0] * sc; r0.y = acc[1] * sc; r0.z = acc[2] * sc; r0.w = acc[3] * sc;
        r1.x = acc[4] * sc; r1.y = acc[5] * sc; r1.z = acc[6] * sc; r1.w = acc[7] * sc;
        float* p = agg + (size_t)node * FEAT + c8;
        *(float4*)p = r0;
        *(float4*)(p + 4) = r1;
    }
}

// ================= MFMA dense, LDS-resident B, 64 cols/block =================
// out = elu([mean|x] @ W + b); K=256. mean: bf16 hi/lo (3 MFMAs); x: bf16 (2).
// 1024 thr = 16 waves x 16 rows = 256 rows/block; blockIdx.y = 64-col tile.
// B staged once (64 KB, XOR swizzle); one barrier. WBF/WF8: bf16/fp8 copies.
// LSM: fused log_softmax (DOUT=64).
template <int DOUT, bool WBF, bool WF8, bool LSM>
__global__ __launch_bounds__(1024, 4) void dense_mfma(
    const float* __restrict__ mean, const unsigned short* __restrict__ xinbf,
    const unsigned short* __restrict__ WTh, const unsigned short* __restrict__ WTl,
    const float* __restrict__ bias,
    float* outf, unsigned short* outbf, unsigned char* outf8, int n)
{
    __shared__ unsigned short Bh[64 * 256];   // 32 KB
    __shared__ unsigned short Bl[64 * 256];   // 32 KB
    const int tid = threadIdx.x;
    const int colbase = blockIdx.y * 64;

    #pragma unroll
    for (int it = 0; it < 2; ++it) {
        int o  = (tid + it * 1024) * 8;
        int cl = o >> 8;
        int k  = o & 255;
        size_t gsrc = (size_t)(colbase + cl) * 256 + k;
        int db = (o * 2) ^ ((cl & 7) << 4);
        *(short8v*)((char*)Bh + db) = *(const short8v*)(WTh + gsrc);
        *(short8v*)((char*)Bl + db) = *(const short8v*)(WTl + gsrc);
    }
    __syncthreads();

    const int l    = tid & 63;
    const int w    = tid >> 6;
    const int l15  = l & 15;
    const int lg   = l >> 4;
    const int row0 = blockIdx.x * 256 + w * 16;
    if (row0 >= n) return;
    const int g = row0 + l15;

    f32x4 acc[4];
    #pragma unroll
    for (int ct = 0; ct < 4; ++ct) acc[ct] = (f32x4){0.f, 0.f, 0.f, 0.f};

    #pragma unroll
    for (int ch = 0; ch < 4; ++ch) {
        float4 v0 = make_float4(0.f, 0.f, 0.f, 0.f), v1 = v0;
        if (g < n) {
            const float* p = mean + (size_t)g * FEAT + ch * 32 + lg * 8;
            v0 = *(const float4*)p;
            v1 = *(const float4*)(p + 4);
        }
        short8v ah, al;
        split8(v0, v1, ah, al);
        #pragma unroll
        for (int ct = 0; ct < 4; ++ct) {
            int cl = ct * 16 + l15;
            int db = (cl * 512 + ch * 64 + lg * 16) ^ ((cl & 7) << 4);
            short8v bh = *(const short8v*)((const char*)Bh + db);
            short8v bl = *(const short8v*)((const char*)Bl + db);
            acc[ct] = __builtin_amdgcn_mfma_f32_16x16x32_bf16(ah, bh, acc[ct], 0, 0, 0);
            acc[ct] = __builtin_amdgcn_mfma_f32_16x16x32_bf16(ah, bl, acc[ct], 0, 0, 0);
            acc[ct] = __builtin_amdgcn_mfma_f32_16x16x32_bf16(al, bh, acc[ct], 0, 0, 0);
        }
    }
    #pragma unroll
    for (int ch = 4; ch < 8; ++ch) {
        short8v ah = (short8v){0,0,0,0,0,0,0,0};
        if (g < n) ah = *(const short8v*)(xinbf + (size_t)g * FEAT + (ch - 4) * 32 + lg * 8);
        #pragma unroll
        for (int ct = 0; ct < 4; ++ct) {
            int cl = ct * 16 + l15;
            int db = (cl * 512 + ch * 64 + lg * 16) ^ ((cl & 7) << 4);
            short8v bh = *(const short8v*)((const char*)Bh + db);
            short8v bl = *(const short8v*)((const char*)Bl + db);
            acc[ct] = __builtin_amdgcn_mfma_f32_16x16x32_bf16(ah, bh, acc[ct], 0, 0, 0);
            acc[ct] = __builtin_amdgcn_mfma_f32_16x16x32_bf16(ah, bl, acc[ct], 0, 0, 0);
        }
    }

    float t[4][4];
    #pragma unroll
    for (int ct = 0; ct < 4; ++ct) {
        float b = bias[colbase + ct * 16 + l15];
        #pragma unroll
        for (int q = 0; q < 4; ++q) {
            float v = acc[ct][q] + b;
            t[ct][q] = (v > 0.f) ? v : expm1f(v);
        }
    }
    if (LSM) {
        #pragma unroll
        for (int q = 0; q < 4; ++q) {
            float m = t[0][q];
            #pragma unroll
            for (int ct = 1; ct < 4; ++ct) m = fmaxf(m, t[ct][q]);
            #pragma unroll
            for (int s = 1; s < 16; s <<= 1) m = fmaxf(m, __shfl_xor(m, s, 64));
            float sum = 0.f;
            #pragma unroll
            for (int ct = 0; ct < 4; ++ct) sum += expf(t[ct][q] - m);
            #pragma unroll
            for (int s = 1; s < 16; s <<= 1) sum += __shfl_xor(sum, s, 64);
            float ls = m + logf(sum);
            #pragma unroll
            for (int ct = 0; ct < 4; ++ct) t[ct][q] -= ls;
        }
    }
    #pragma unroll
    for (int ct = 0; ct < 4; ++ct) {
        int col = colbase + ct * 16 + l15;
        #pragma unroll
        for (int q = 0; q < 4; ++q) {
            int grow = row0 + lg * 4 + q;
            if (grow < n) {
                if (WBF) outbf[(size_t)grow * DOUT + col] = f2bf(t[ct][q]);
                if (WF8) outf8[(size_t)grow * DOUT + col] = f2fp8(t[ct][q]);
                if (!WBF && !WF8) outf[(size_t)grow * DOUT + col] = t[ct][q];
            }
        }
    }
}

extern "C" void kernel_launch(void* const* d_in, const int* in_sizes, int n_in,
                              void* d_out, int out_size, void* d_ws, size_t ws_size,
                              hipStream_t stream) {
    const float* x   = (const float*)d_in[0];
    const float* W1l = (const float*)d_in[1];
    const float* W1r = (const float*)d_in[2];
    const float* b1  = (const float*)d_in[3];
    const float* W2l = (const float*)d_in[4];
    const float* W2r = (const float*)d_in[5];
    const float* b2  = (const float*)d_in[6];
    const float* W3l = (const float*)d_in[7];
    const float* W3r = (const float*)d_in[8];
    const float* b3  = (const float*)d_in[9];
    const int*   src = (const int*)d_in[10];
    const int*   dst = (const int*)d_in[11];

    const int N = in_sizes[0] / FEAT;
    const int E = in_sizes[10];

    const size_t NA = ((size_t)N + 63) & ~(size_t)63;
    const size_t EA = ((size_t)E + 63) & ~(size_t)63;
    const int nb  = (N + 1023) / 1024;      // fallback scan blocks
    const int nbk = (N + 511) >> 9;         // buckets (512 dsts)
    const int nch = (E + 8191) / 8192;      // chunks

    float* ws   = (float*)d_ws;
    float* invd = ws;                             // NA floats
    int*   offs = (int*)(ws + NA);                // NA+64 ints
    int*   eidx = offs + NA + 64;                 // EA ints
    unsigned int* chunkd = (unsigned int*)(eidx + EA);          // nch*8192
    int*   table = (int*)(chunkd + (size_t)nch * 8192 + 64);    // nch*(nbk+1)
    int*   bbase = table + (size_t)nch * (nbk + 1) + 64;        // 256+
    int*   deg   = bbase + 512;                   // NA (fallback)
    int*   cur   = deg + NA;                      // NA (fallback)
    int*   bsum  = cur + NA;                      // 256 (fallback)
    int*   bpre  = bsum + 256;                    // 256 (fallback)
    unsigned short* wtb = (unsigned short*)(bpre + 256);
    unsigned short* WTh1 = wtb;                   // 128*256
    unsigned short* WTl1 = WTh1 + 128 * 256;
    unsigned short* WTh2 = WTl1 + 128 * 256;
    unsigned short* WTl2 = WTh2 + 128 * 256;
    unsigned short* WTh3 = WTl2 + 128 * 256;      // 64*256
    unsigned short* WTl3 = WTh3 + 64 * 256;
    float* bufM = (float*)(WTl3 + 64 * 256 + 64); // NA*128 fp32
    unsigned short* bfA = (unsigned short*)(bufM + NA * FEAT);  // NA*128 bf16
    unsigned short* bfB = bfA + NA * FEAT;                      // NA*128 bf16
    unsigned char*  f8X = (unsigned char*)(bfB + NA * FEAT);    // NA*128 fp8
    float* outp = (float*)d_out;

    const int gblocks = (N + 3) / 4;
    const int dblocks = (N + 255) / 256;

    // ---- CSR build + prep ----
    if (N <= 65536) {
        bucket_kernel<<<nch, 1024, 0, stream>>>(src, dst, chunkd, table, E, nbk);
        btot_kernel<<<1, 256, 0, stream>>>(table, bbase, offs, nch, nbk, N, E);
        fillsort_kernel<<<nbk, 1024, 0, stream>>>(chunkd, table, bbase, offs, invd, eidx, N, nch, nbk);
    } else {
        hipMemsetAsync(deg, 0, (size_t)N * 4, stream);
        deg_kernel<<<(E + 255) / 256, 256, 0, stream>>>(dst, deg, E);
        blockred_kernel<<<nb, 256, 0, stream>>>(deg, bsum, N);
        scanb_kernel<<<1, 256, 0, stream>>>(bsum, bpre, nb);
        scanfill_kernel<<<nb, 256, 0, stream>>>(deg, bpre, offs, cur, invd, N, E);
        const int rsize   = (N + 7) / 8;
        const int fblocks = ((E + FCH - 1) / FCH) * 8;
        fill_xcd_kernel<<<fblocks, 256, 0, stream>>>(src, dst, cur, eidx, E, rsize);
    }
    prep_wt<<<(128 * 256 + 255) / 256, 256, 0, stream>>>(W1l, W1r, WTh1, WTl1, 128);
    prep_wt<<<(128 * 256 + 255) / 256, 256, 0, stream>>>(W2l, W2r, WTh2, WTl2, 128);
    prep_wt<<<(64 * 256 + 255) / 256, 256, 0, stream>>>(W3l, W3r, WTh3, WTl3, 64);
    f2bf8_kernel<<<(N * FEAT / 4 + 255) / 256, 256, 0, stream>>>(x, bfA, f8X, N * FEAT / 4);

    // layer 1: gather_f8(x_f8) -> M ; h1 = dense(M, x_bf) -> bfB + f8X
    gather_f8_kernel<<<gblocks, 256, 0, stream>>>(f8X, offs, eidx, invd, bufM, N);
    dense_mfma<128, true, true, false><<<dim3(dblocks, 2), 1024, 0, stream>>>(bufM, bfA, WTh1, WTl1, b1, nullptr, bfB, f8X, N);

    // layer 2: gather_f8(h1_f8) -> M ; h2 = dense(M, h1_bf) -> bfA + f8X
    gather_f8_kernel<<<gblocks, 256, 0, stream>>>(f8X, offs, eidx, invd, bufM, N);
    dense_mfma<128, true, true, false><<<dim3(dblocks, 2), 1024, 0, stream>>>(bufM, bfB, WTh2, WTl2, b2, nullptr, bfA, f8X, N);

    // layer 3: gather_f8(h2_f8) -> M ; out = log_softmax(elu(dense(M, h2_bf))) -> d_out
    gather_f8_kernel<<<gblocks, 256, 0, stream>>>(f8X, offs, eidx, invd, bufM, N);
    dense_mfma<64, false, false, true><<<dim3(dblocks, 1), 1024, 0, stream>>>(bufM, bfA, WTh3, WTl3, b3, outp, nullptr, nullptr, N);
}

// Round 15
// 161.124 us; speedup vs baseline: 2.2100x; 1.2853x over previous
//
#include <hip/hip_runtime.h>
#include <math.h>

constexpr int FEAT = 128;   // DIN == DH == 128

typedef __attribute__((ext_vector_type(8))) short short8v;   // 8 bf16 raw / 16 B
typedef __attribute__((ext_vector_type(4))) float f32x4;
typedef __attribute__((ext_vector_type(2))) float f32x2;
typedef __attribute__((ext_vector_type(4))) int   int4v;

// ---- fp32 -> bf16 (RNE) / fp8 helpers ----
__device__ inline unsigned short f2bf(float f) {
    unsigned int u = __float_as_uint(f);
    u += 0x7fffu + ((u >> 16) & 1u);
    return (unsigned short)(u >> 16);
}
__device__ inline float bf2f(unsigned short h) {
    return __uint_as_float(((unsigned int)h) << 16);
}
__device__ inline unsigned char f2fp8(float f) {
    int r = __builtin_amdgcn_cvt_pk_fp8_f32(f, 0.f, 0, false);
    return (unsigned char)(r & 0xff);
}

// ================= CSR build (N <= 65536 fast path) =================
// Phase 1: per-chunk LDS bucket sort. Chunk = 8192 edges/block; bucket = dst>>9.
// Packed word: src(16b) | (dst&511)<<16. Output written LINEARLY (coalesced).
__global__ __launch_bounds__(1024) void bucket_kernel(const int* __restrict__ src,
                                                      const int* __restrict__ dst,
                                                      unsigned int* __restrict__ chunkdata,
                                                      int* __restrict__ table,
                                                      int E, int nb) {
    __shared__ int cnt[128];
    __shared__ int part[128];
    __shared__ int sbase[128];
    __shared__ unsigned int sbuf[8192];
    const int t = threadIdx.x;
    const int c = blockIdx.x;
    const int e0 = c * 8192;

    if (t < 128) cnt[t] = 0;
    __syncthreads();

    unsigned int word[8];
    int bkt[8], rnk[8];
    #pragma unroll
    for (int it = 0; it < 2; ++it) {
        int e = e0 + it * 4096 + t * 4;
        int4 d4 = make_int4(0, 0, 0, 0), s4 = d4;
        if (e + 3 < E) {
            d4 = *(const int4*)(dst + e);
            s4 = *(const int4*)(src + e);
        } else {
            if (e + 0 < E) { d4.x = dst[e + 0]; s4.x = src[e + 0]; } else d4.x = -1;
            if (e + 1 < E) { d4.y = dst[e + 1]; s4.y = src[e + 1]; } else d4.y = -1;
            if (e + 2 < E) { d4.z = dst[e + 2]; s4.z = src[e + 2]; } else d4.z = -1;
            if (e + 3 < E) { d4.w = dst[e + 3]; s4.w = src[e + 3]; } else d4.w = -1;
        }
        int dd[4] = {d4.x, d4.y, d4.z, d4.w};
        int ss[4] = {s4.x, s4.y, s4.z, s4.w};
        #pragma unroll
        for (int q = 0; q < 4; ++q) {
            int i = it * 4 + q;
            int d = dd[q];
            if (d >= 0) {
                bkt[i]  = d >> 9;
                rnk[i]  = atomicAdd(&cnt[bkt[i]], 1);
                word[i] = (unsigned int)ss[q] | ((unsigned int)(d & 511) << 16);
            } else bkt[i] = -1;
        }
    }
    __syncthreads();

    if (t < 128) part[t] = cnt[t];
    __syncthreads();
    for (int s = 1; s < 128; s <<= 1) {
        int v = (t >= s && t < 128) ? part[t - s] : 0;
        __syncthreads();
        if (t < 128) part[t] += v;
        __syncthreads();
    }
    if (t < 128) sbase[t] = part[t] - cnt[t];
    __syncthreads();

    if (t <= nb) table[(size_t)c * (nb + 1) + t] = sbase[t];

    #pragma unroll
    for (int i = 0; i < 8; ++i)
        if (bkt[i] >= 0) sbuf[sbase[bkt[i]] + rnk[i]] = word[i];
    __syncthreads();

    const int total = part[127];
    for (int i = t; i < total; i += 1024)
        chunkdata[(size_t)c * 8192 + i] = sbuf[i];
}

// Phase 2: per-bucket two-pass counting sort. Computes its own base
// (base = sum_c table[c][b], since table[c][0]==0), counts degrees ->
// writes offs/invd, places into LDS, contiguous flush.
constexpr int P2CAP = 10240;   // bucket ~8192 +- 90; 22 sigma + fallback
__global__ __launch_bounds__(1024) void fillsort_kernel(const unsigned int* __restrict__ chunkdata,
                                                        const int* __restrict__ table,
                                                        int* __restrict__ offs,
                                                        float* __restrict__ invd,
                                                        int* __restrict__ eidx,
                                                        int n, int nch, int nbk, int E) {
    __shared__ int cnt[512];
    __shared__ int lcur[512];
    __shared__ int part[512];
    __shared__ int redb[16];
    __shared__ int lbuf[P2CAP];
    const int b  = blockIdx.x;
    const int t  = threadIdx.x;
    const int lo = b << 9;

    // base = sum over chunks of this bucket's exclusive offset
    int partial = 0;
    for (int c = t; c < nch; c += 1024) partial += table[(size_t)c * (nbk + 1) + b];
    #pragma unroll
    for (int off = 32; off > 0; off >>= 1) partial += __shfl_down(partial, off, 64);
    if ((t & 63) == 0) redb[t >> 6] = partial;
    for (int i = t; i < 512; i += 1024) cnt[i] = 0;
    __syncthreads();
    int base = 0;
    #pragma unroll
    for (int i = 0; i < 16; ++i) base += redb[i];

    const int w    = t >> 6;
    const int lane = t & 63;
    // pass 1: count degrees
    for (int c = w; c < nch; c += 16) {
        int o0 = table[(size_t)c * (nbk + 1) + b];
        int o1 = table[(size_t)c * (nbk + 1) + b + 1];
        for (int i = o0 + lane; i < o1; i += 64)
            atomicAdd(&cnt[(chunkdata[(size_t)c * 8192 + i] >> 16) & 511], 1);
    }
    __syncthreads();

    // scan 512 counts
    int v = (t < 512) ? cnt[t] : 0;
    if (t < 512) part[t] = v;
    __syncthreads();
    for (int s = 1; s < 512; s <<= 1) {
        int u = (t >= s && t < 512) ? part[t - s] : 0;
        __syncthreads();
        if (t < 512) part[t] += u;
        __syncthreads();
    }
    const int total = part[511];
    if (t < 512) {
        int ex = part[t] - v;
        lcur[t] = ex;
        int idx = lo + t;
        if (idx < n) {
            offs[idx] = base + ex;
            invd[idx] = 1.0f / fmaxf((float)v, 1.0f);
        }
    }
    if (b == nbk - 1 && t == 0) offs[n] = E;
    __syncthreads();

    // pass 2: place
    for (int c = w; c < nch; c += 16) {
        int o0 = table[(size_t)c * (nbk + 1) + b];
        int o1 = table[(size_t)c * (nbk + 1) + b + 1];
        for (int i = o0 + lane; i < o1; i += 64) {
            unsigned int wd = chunkdata[(size_t)c * 8192 + i];
            int s = wd & 0xffff;
            int p = atomicAdd(&lcur[(wd >> 16) & 511], 1);
            if (p < P2CAP) lbuf[p] = s;
            else           eidx[base + p] = s;   // overflow fallback
        }
    }
    __syncthreads();

    const int m = min(total, P2CAP);
    for (int i = t; i < m; i += 1024) eidx[base + i] = lbuf[i];
}

// ================= CSR build fallback (N > 65536) =================
__global__ void deg_kernel(const int* __restrict__ dst, int* __restrict__ degi, int E) {
    int e = blockIdx.x * 256 + threadIdx.x;
    if (e < E) atomicAdd(&degi[__builtin_nontemporal_load(dst + e)], 1);
}
__global__ __launch_bounds__(256) void blockred_kernel(const int* __restrict__ deg,
                                                       int* __restrict__ bsum, int n) {
    __shared__ int red[256];
    int base = blockIdx.x * 1024 + threadIdx.x * 4;
    int s = 0;
    if (base + 3 < n) {
        int4 v = *(const int4*)(deg + base);
        s = v.x + v.y + v.z + v.w;
    } else {
        for (int i = 0; i < 4; ++i) if (base + i < n) s += deg[base + i];
    }
    red[threadIdx.x] = s;
    __syncthreads();
    for (int st = 128; st > 0; st >>= 1) {
        if (threadIdx.x < st) red[threadIdx.x] += red[threadIdx.x + st];
        __syncthreads();
    }
    if (threadIdx.x == 0) bsum[blockIdx.x] = red[0];
}
__global__ __launch_bounds__(256) void scanb_kernel(const int* __restrict__ bsum,
                                                    int* __restrict__ bpre, int nb) {
    __shared__ int part[256];
    int t = threadIdx.x;
    int v = (t < nb) ? bsum[t] : 0;
    part[t] = v;
    __syncthreads();
    for (int s = 1; s < 256; s <<= 1) {
        int u = (t >= s) ? part[t - s] : 0;
        __syncthreads();
        part[t] += u;
        __syncthreads();
    }
    if (t < nb) bpre[t] = part[t] - v;
}
__global__ __launch_bounds__(256) void scanfill_kernel(const int* __restrict__ deg,
                                                       const int* __restrict__ bpre,
                                                       int* __restrict__ offs,
                                                       int* __restrict__ cur,
                                                       float* __restrict__ invd,
                                                       int n, int E) {
    __shared__ int part[256];
    int t = threadIdx.x;
    int base = blockIdx.x * 1024 + t * 4;
    int d[4];
    int s = 0;
    #pragma unroll
    for (int i = 0; i < 4; ++i) {
        d[i] = (base + i < n) ? deg[base + i] : 0;
        s += d[i];
    }
    part[t] = s;
    __syncthreads();
    for (int st = 1; st < 256; st <<= 1) {
        int u = (t >= st) ? part[t - st] : 0;
        __syncthreads();
        part[t] += u;
        __syncthreads();
    }
    int pre = bpre[blockIdx.x] + part[t] - s;
    #pragma unroll
    for (int i = 0; i < 4; ++i) {
        int idx = base + i;
        if (idx < n) {
            offs[idx] = pre;
            cur[idx]  = pre;
            invd[idx] = 1.0f / fmaxf((float)d[i], 1.0f);
            pre += d[i];
        }
    }
    if (blockIdx.x == 0 && t == 0) offs[n] = E;
}
constexpr int FCH = 4096;
__global__ __launch_bounds__(256) void fill_xcd_kernel(const int* __restrict__ src,
                                                       const int* __restrict__ dst,
                                                       int* __restrict__ cur,
                                                       int* __restrict__ eidx,
                                                       int E, int rsize) {
    const int p     = blockIdx.x & 7;
    const int chunk = blockIdx.x >> 3;
    const int lo = p * rsize;
    const int hi = lo + rsize;
    #pragma unroll
    for (int it = 0; it < 4; ++it) {
        int e = chunk * FCH + (it * 256 + threadIdx.x) * 4;
        if (e + 3 < E) {
            int4v d4 = __builtin_nontemporal_load((const int4v*)(dst + e));
            #pragma unroll
            for (int q = 0; q < 4; ++q) {
                int d = d4[q];
                if (d >= lo && d < hi) {
                    int pos = atomicAdd(&cur[d], 1);
                    eidx[pos] = __builtin_nontemporal_load(src + e + q);
                }
            }
        } else {
            for (int q = 0; e + q < E && q < 4; ++q) {
                int d = dst[e + q];
                if (d >= lo && d < hi) {
                    int pos = atomicAdd(&cur[d], 1);
                    eidx[pos] = src[e + q];
                }
            }
        }
    }
}

// ================= merged prep: 3x weight split-transpose + x -> (bf16, fp8) =================
// blocks [0,128): W1, [128,256): W2, [256,320): W3, [320, ...): x convert.
__global__ __launch_bounds__(256) void prep_kernel(
    const float* __restrict__ W1l, const float* __restrict__ W1r,
    const float* __restrict__ W2l, const float* __restrict__ W2r,
    const float* __restrict__ W3l, const float* __restrict__ W3r,
    unsigned short* __restrict__ WTh1, unsigned short* __restrict__ WTl1,
    unsigned short* __restrict__ WTh2, unsigned short* __restrict__ WTl2,
    unsigned short* __restrict__ WTh3, unsigned short* __restrict__ WTl3,
    const float* __restrict__ x, unsigned short* __restrict__ xbf,
    unsigned char* __restrict__ xf8, int total4)
{
    const int b = blockIdx.x;
    if (b < 320) {
        const float *Wl, *Wr;
        unsigned short *WTh, *WTl;
        int dout, idx;
        if (b < 128)      { Wl = W1l; Wr = W1r; WTh = WTh1; WTl = WTl1; dout = 128; idx = b * 256 + threadIdx.x; }
        else if (b < 256) { Wl = W2l; Wr = W2r; WTh = WTh2; WTl = WTl2; dout = 128; idx = (b - 128) * 256 + threadIdx.x; }
        else              { Wl = W3l; Wr = W3r; WTh = WTh3; WTl = WTl3; dout = 64;  idx = (b - 256) * 256 + threadIdx.x; }
        if (idx < dout * 256) {
            int c = idx >> 8;
            int k = idx & 255;
            float v = (k < 128) ? Wl[(size_t)k * dout + c] : Wr[(size_t)(k - 128) * dout + c];
            unsigned short h = f2bf(v);
            WTh[(size_t)c * 256 + k] = h;
            WTl[(size_t)c * 256 + k] = f2bf(v - bf2f(h));
        }
    } else {
        int i = (b - 320) * 256 + threadIdx.x;
        if (i < total4) {
            float4 v = *(const float4*)(x + (size_t)i * 4);
            ushort4 h;
            h.x = f2bf(v.x); h.y = f2bf(v.y); h.z = f2bf(v.z); h.w = f2bf(v.w);
            *(ushort4*)(xbf + (size_t)i * 4) = h;
            uchar4 c;
            c.x = f2fp8(v.x); c.y = f2fp8(v.y); c.z = f2fp8(v.z); c.w = f2fp8(v.w);
            *(uchar4*)(xf8 + (size_t)i * 4) = c;
        }
    }
}

// ================= gather mean from fp8 feats -> bf16 mean, 8 B/lane =================
__global__ __launch_bounds__(256) void gather_f8_kernel(const unsigned char* __restrict__ featf8,
                                                        const int* __restrict__ offs,
                                                        const int* __restrict__ eidx,
                                                        const float* __restrict__ invd,
                                                        unsigned short* __restrict__ aggbf, int n) {
    int node = blockIdx.x * 4 + (threadIdx.x >> 6);
    if (node >= n) return;
    const int l   = threadIdx.x & 63;
    const int grp = l >> 4;
    const int li  = l & 15;
    const int c8  = li * 8;
    int beg = offs[node], end = offs[node + 1];
    float acc[8];
    #pragma unroll
    for (int q = 0; q < 8; ++q) acc[q] = 0.f;

    int j = beg + grp;
    for (; j + 4 < end; j += 8) {
        int s0 = eidx[j], s1 = eidx[j + 4];
        uint2 v0 = *(const uint2*)(featf8 + (size_t)s0 * FEAT + c8);
        uint2 v1 = *(const uint2*)(featf8 + (size_t)s1 * FEAT + c8);
        f32x2 p;
        p = __builtin_amdgcn_cvt_pk_f32_fp8(v0.x, false); acc[0] += p.x; acc[1] += p.y;
        p = __builtin_amdgcn_cvt_pk_f32_fp8(v0.x, true);  acc[2] += p.x; acc[3] += p.y;
        p = __builtin_amdgcn_cvt_pk_f32_fp8(v0.y, false); acc[4] += p.x; acc[5] += p.y;
        p = __builtin_amdgcn_cvt_pk_f32_fp8(v0.y, true);  acc[6] += p.x; acc[7] += p.y;
        p = __builtin_amdgcn_cvt_pk_f32_fp8(v1.x, false); acc[0] += p.x; acc[1] += p.y;
        p = __builtin_amdgcn_cvt_pk_f32_fp8(v1.x, true);  acc[2] += p.x; acc[3] += p.y;
        p = __builtin_amdgcn_cvt_pk_f32_fp8(v1.y, false); acc[4] += p.x; acc[5] += p.y;
        p = __builtin_amdgcn_cvt_pk_f32_fp8(v1.y, true);  acc[6] += p.x; acc[7] += p.y;
    }
    if (j < end) {
        int s0 = eidx[j];
        uint2 v0 = *(const uint2*)(featf8 + (size_t)s0 * FEAT + c8);
        f32x2 p;
        p = __builtin_amdgcn_cvt_pk_f32_fp8(v0.x, false); acc[0] += p.x; acc[1] += p.y;
        p = __builtin_amdgcn_cvt_pk_f32_fp8(v0.x, true);  acc[2] += p.x; acc[3] += p.y;
        p = __builtin_amdgcn_cvt_pk_f32_fp8(v0.y, false); acc[4] += p.x; acc[5] += p.y;
        p = __builtin_amdgcn_cvt_pk_f32_fp8(v0.y, true);  acc[6] += p.x; acc[7] += p.y;
    }

    #pragma unroll
    for (int off = 16; off < 64; off <<= 1)
        #pragma unroll
        for (int q = 0; q < 8; ++q)
            acc[q] += __shfl_xor(acc[q], off, 64);

    if (grp == 0) {
        float sc = invd[node];
        unsigned short o[8];
        #pragma unroll
        for (int q = 0; q < 8; ++q) o[q] = f2bf(acc[q] * sc);
        *(short8v*)(aggbf + (size_t)node * FEAT + c8) = *(short8v*)o;
    }
}

// ================= MFMA dense, LDS-resident B, 64 cols/block =================
// out = elu([mean|x] @ W + b); K=256. mean AND x are bf16 (2 MFMAs per
// chunk-ct against W hi/lo). 1024 thr = 16 waves x 16 rows = 256 rows/block;
// blockIdx.y = 64-col tile. B staged once (64 KB, XOR swizzle); one barrier.
// WBF/WF8: bf16/fp8 activation copies. LSM: fused log_softmax (DOUT=64).
template <int DOUT, bool WBF, bool WF8, bool LSM>
__global__ __launch_bounds__(1024, 4) void dense_mfma(
    const unsigned short* __restrict__ meanbf, const unsigned short* __restrict__ xinbf,
    const unsigned short* __restrict__ WTh, const unsigned short* __restrict__ WTl,
    const float* __restrict__ bias,
    float* outf, unsigned short* outbf, unsigned char* outf8, int n)
{
    __shared__ unsigned short Bh[64 * 256];   // 32 KB
    __shared__ unsigned short Bl[64 * 256];   // 32 KB
    const int tid = threadIdx.x;
    const int colbase = blockIdx.y * 64;

    #pragma unroll
    for (int it = 0; it < 2; ++it) {
        int o  = (tid + it * 1024) * 8;
        int cl = o >> 8;
        int k  = o & 255;
        size_t gsrc = (size_t)(colbase + cl) * 256 + k;
        int db = (o * 2) ^ ((cl & 7) << 4);
        *(short8v*)((char*)Bh + db) = *(const short8v*)(WTh + gsrc);
        *(short8v*)((char*)Bl + db) = *(const short8v*)(WTl + gsrc);
    }
    __syncthreads();

    const int l    = tid & 63;
    const int w    = tid >> 6;
    const int l15  = l & 15;
    const int lg   = l >> 4;
    const int row0 = blockIdx.x * 256 + w * 16;
    if (row0 >= n) return;
    const int g = row0 + l15;

    f32x4 acc[4];
    #pragma unroll
    for (int ct = 0; ct < 4; ++ct) acc[ct] = (f32x4){0.f, 0.f, 0.f, 0.f};

    #pragma unroll
    for (int ch = 0; ch < 8; ++ch) {
        const unsigned short* As = (ch < 4) ? meanbf : xinbf;
        const int kb = (ch & 3) * 32 + lg * 8;
        short8v ah = (short8v){0, 0, 0, 0, 0, 0, 0, 0};
        if (g < n) ah = *(const short8v*)(As + (size_t)g * FEAT + kb);
        #pragma unroll
        for (int ct = 0; ct < 4; ++ct) {
            int cl = ct * 16 + l15;
            int db = (cl * 512 + ch * 64 + lg * 16) ^ ((cl & 7) << 4);
            short8v bh = *(const short8v*)((const char*)Bh + db);
            short8v bl = *(const short8v*)((const char*)Bl + db);
            acc[ct] = __builtin_amdgcn_mfma_f32_16x16x32_bf16(ah, bh, acc[ct], 0, 0, 0);
            acc[ct] = __builtin_amdgcn_mfma_f32_16x16x32_bf16(ah, bl, acc[ct], 0, 0, 0);
        }
    }

    float t[4][4];
    #pragma unroll
    for (int ct = 0; ct < 4; ++ct) {
        float b = bias[colbase + ct * 16 + l15];
        #pragma unroll
        for (int q = 0; q < 4; ++q) {
            float v = acc[ct][q] + b;
            t[ct][q] = (v > 0.f) ? v : expm1f(v);
        }
    }
    if (LSM) {
        #pragma unroll
        for (int q = 0; q < 4; ++q) {
            float m = t[0][q];
            #pragma unroll
            for (int ct = 1; ct < 4; ++ct) m = fmaxf(m, t[ct][q]);
            #pragma unroll
            for (int s = 1; s < 16; s <<= 1) m = fmaxf(m, __shfl_xor(m, s, 64));
            float sum = 0.f;
            #pragma unroll
            for (int ct = 0; ct < 4; ++ct) sum += expf(t[ct][q] - m);
            #pragma unroll
            for (int s = 1; s < 16; s <<= 1) sum += __shfl_xor(sum, s, 64);
            float ls = m + logf(sum);
            #pragma unroll
            for (int ct = 0; ct < 4; ++ct) t[ct][q] -= ls;
        }
    }
    #pragma unroll
    for (int ct = 0; ct < 4; ++ct) {
        int col = colbase + ct * 16 + l15;
        #pragma unroll
        for (int q = 0; q < 4; ++q) {
            int grow = row0 + lg * 4 + q;
            if (grow < n) {
                if (WBF) outbf[(size_t)grow * DOUT + col] = f2bf(t[ct][q]);
                if (WF8) outf8[(size_t)grow * DOUT + col] = f2fp8(t[ct][q]);
                if (!WBF && !WF8) outf[(size_t)grow * DOUT + col] = t[ct][q];
            }
        }
    }
}

extern "C" void kernel_launch(void* const* d_in, const int* in_sizes, int n_in,
                              void* d_out, int out_size, void* d_ws, size_t ws_size,
                              hipStream_t stream) {
    const float* x   = (const float*)d_in[0];
    const float* W1l = (const float*)d_in[1];
    const float* W1r = (const float*)d_in[2];
    const float* b1  = (const float*)d_in[3];
    const float* W2l = (const float*)d_in[4];
    const float* W2r = (const float*)d_in[5];
    const float* b2  = (const float*)d_in[6];
    const float* W3l = (const float*)d_in[7];
    const float* W3r = (const float*)d_in[8];
    const float* b3  = (const float*)d_in[9];
    const int*   src = (const int*)d_in[10];
    const int*   dst = (const int*)d_in[11];

    const int N = in_sizes[0] / FEAT;
    const int E = in_sizes[10];

    const size_t NA = ((size_t)N + 63) & ~(size_t)63;
    const size_t EA = ((size_t)E + 63) & ~(size_t)63;
    const int nb  = (N + 1023) / 1024;      // fallback scan blocks
    const int nbk = (N + 511) >> 9;         // buckets (512 dsts)
    const int nch = (E + 8191) / 8192;      // chunks

    auto alignup = [](char* p) { return (char*)(((uintptr_t)p + 255) & ~(uintptr_t)255); };
    char* p = (char*)d_ws;
    float* invd = (float*)p;                 p += NA * 4;
    int*   offs = (int*)p;                   p += (NA + 64) * 4;
    int*   eidx = (int*)p;                   p += EA * 4;
    unsigned int* chunkd = (unsigned int*)p; p += (size_t)nch * 8192 * 4;
    int*   table = (int*)p;                  p += (size_t)nch * (nbk + 1) * 4;
    p = alignup(p);
    int*   deg  = (int*)p;                   p += NA * 4;     // fallback
    int*   cur  = (int*)p;                   p += NA * 4;     // fallback
    int*   bsum = (int*)p;                   p += 256 * 4;    // fallback
    int*   bpre = (int*)p;                   p += 256 * 4;    // fallback
    p = alignup(p);
    unsigned short* WTh1 = (unsigned short*)p; p += 128 * 256 * 2;
    unsigned short* WTl1 = (unsigned short*)p; p += 128 * 256 * 2;
    unsigned short* WTh2 = (unsigned short*)p; p += 128 * 256 * 2;
    unsigned short* WTl2 = (unsigned short*)p; p += 128 * 256 * 2;
    unsigned short* WTh3 = (unsigned short*)p; p += 64 * 256 * 2;
    unsigned short* WTl3 = (unsigned short*)p; p += 64 * 256 * 2;
    p = alignup(p);
    unsigned short* mbf = (unsigned short*)p;  p += NA * FEAT * 2;   // bf16 mean
    unsigned short* bfA = (unsigned short*)p;  p += NA * FEAT * 2;   // bf16 act
    unsigned short* bfB = (unsigned short*)p;  p += NA * FEAT * 2;   // bf16 act
    unsigned char*  f8X = (unsigned char*)p;   p += NA * FEAT;       // fp8 act
    float* outp = (float*)d_out;

    const int gblocks = (N + 3) / 4;
    const int dblocks = (N + 255) / 256;
    const int total4  = N * FEAT / 4;

    // ---- CSR build ----
    if (N <= 65536) {
        bucket_kernel<<<nch, 1024, 0, stream>>>(src, dst, chunkd, table, E, nbk);
        fillsort_kernel<<<nbk, 1024, 0, stream>>>(chunkd, table, offs, invd, eidx, N, nch, nbk, E);
    } else {
        hipMemsetAsync(deg, 0, (size_t)N * 4, stream);
        deg_kernel<<<(E + 255) / 256, 256, 0, stream>>>(dst, deg, E);
        blockred_kernel<<<nb, 256, 0, stream>>>(deg, bsum, N);
        scanb_kernel<<<1, 256, 0, stream>>>(bsum, bpre, nb);
        scanfill_kernel<<<nb, 256, 0, stream>>>(deg, bpre, offs, cur, invd, N, E);
        const int rsize   = (N + 7) / 8;
        const int fblocks = ((E + FCH - 1) / FCH) * 8;
        fill_xcd_kernel<<<fblocks, 256, 0, stream>>>(src, dst, cur, eidx, E, rsize);
    }
    // ---- merged prep (weights + x conversions) ----
    prep_kernel<<<320 + (total4 + 255) / 256, 256, 0, stream>>>(
        W1l, W1r, W2l, W2r, W3l, W3r, WTh1, WTl1, WTh2, WTl2, WTh3, WTl3,
        x, bfA, f8X, total4);

    // layer 1: gather_f8(x_f8) -> mbf ; h1 = dense(mbf, x_bf) -> bfB + f8X
    gather_f8_kernel<<<gblocks, 256, 0, stream>>>(f8X, offs, eidx, invd, mbf, N);
    dense_mfma<128, true, true, false><<<dim3(dblocks, 2), 1024, 0, stream>>>(mbf, bfA, WTh1, WTl1, b1, nullptr, bfB, f8X, N);

    // layer 2: gather_f8(h1_f8) -> mbf ; h2 = dense(mbf, h1_bf) -> bfA + f8X
    gather_f8_kernel<<<gblocks, 256, 0, stream>>>(f8X, offs, eidx, invd, mbf, N);
    dense_mfma<128, true, true, false><<<dim3(dblocks, 2), 1024, 0, stream>>>(mbf, bfB, WTh2, WTl2, b2, nullptr, bfA, f8X, N);

    // layer 3: gather_f8(h2_f8) -> mbf ; out = log_softmax(elu(dense(mbf, h2_bf))) -> d_out
    gather_f8_kernel<<<gblocks, 256, 0, stream>>>(f8X, offs, eidx, invd, mbf, N);
    dense_mfma<64, false, false, true><<<dim3(dblocks, 1), 1024, 0, stream>>>(mbf, bfA, WTh3, WTl3, b3, outp, nullptr, nullptr, N);
}

// Round 16
// 159.568 us; speedup vs baseline: 2.2316x; 1.0098x over previous
//
#include <hip/hip_runtime.h>
#include <math.h>

constexpr int FEAT = 128;   // DIN == DH == 128

typedef __attribute__((ext_vector_type(8))) short short8v;   // 8 bf16 raw / 16 B
typedef __attribute__((ext_vector_type(4))) float f32x4;
typedef __attribute__((ext_vector_type(2))) float f32x2;
typedef __attribute__((ext_vector_type(4))) int   int4v;

// ---- fp32 -> bf16 (RNE) / fp8 helpers ----
__device__ inline unsigned short f2bf(float f) {
    unsigned int u = __float_as_uint(f);
    u += 0x7fffu + ((u >> 16) & 1u);
    return (unsigned short)(u >> 16);
}
__device__ inline float bf2f(unsigned short h) {
    return __uint_as_float(((unsigned int)h) << 16);
}
__device__ inline unsigned char f2fp8(float f) {
    int r = __builtin_amdgcn_cvt_pk_fp8_f32(f, 0.f, 0, false);
    return (unsigned char)(r & 0xff);
}

// ================= fused CSR bucket phase 1 + weight/x prep =================
// blocks [0,nch): per-chunk LDS bucket sort (chunk = 8192 edges, bucket =
// dst>>9, packed word src(16b)|(dst&511)<<16, coalesced linear dump).
// blocks [nch,nch+80): weight split-transpose. blocks [nch+80,...): x->bf16/fp8.
__global__ __launch_bounds__(1024) void bucket_prep_kernel(
    const int* __restrict__ src, const int* __restrict__ dst,
    unsigned int* __restrict__ chunkdata, int* __restrict__ table,
    int E, int nbk, int nch,
    const float* __restrict__ W1l, const float* __restrict__ W1r,
    const float* __restrict__ W2l, const float* __restrict__ W2r,
    const float* __restrict__ W3l, const float* __restrict__ W3r,
    unsigned short* __restrict__ WTh1, unsigned short* __restrict__ WTl1,
    unsigned short* __restrict__ WTh2, unsigned short* __restrict__ WTl2,
    unsigned short* __restrict__ WTh3, unsigned short* __restrict__ WTl3,
    const float* __restrict__ x, unsigned short* __restrict__ xbf,
    unsigned char* __restrict__ xf8, int total4)
{
    __shared__ int cnt[128];
    __shared__ int part[128];
    __shared__ int sbase[128];
    __shared__ unsigned int sbuf[8192];
    const int t = threadIdx.x;
    const int blk = blockIdx.x;

    if (blk >= nch) {
        // ---- prep path ----
        int b = blk - nch;
        if (b < 80) {
            const float *Wl, *Wr;
            unsigned short *WTh, *WTl;
            int dout, idx;
            if (b < 32)      { Wl = W1l; Wr = W1r; WTh = WTh1; WTl = WTl1; dout = 128; idx = b * 1024 + t; }
            else if (b < 64) { Wl = W2l; Wr = W2r; WTh = WTh2; WTl = WTl2; dout = 128; idx = (b - 32) * 1024 + t; }
            else             { Wl = W3l; Wr = W3r; WTh = WTh3; WTl = WTl3; dout = 64;  idx = (b - 64) * 1024 + t; }
            if (idx < dout * 256) {
                int c = idx >> 8;
                int k = idx & 255;
                float v = (k < 128) ? Wl[(size_t)k * dout + c] : Wr[(size_t)(k - 128) * dout + c];
                unsigned short h = f2bf(v);
                WTh[(size_t)c * 256 + k] = h;
                WTl[(size_t)c * 256 + k] = f2bf(v - bf2f(h));
            }
        } else {
            int i = (b - 80) * 1024 + t;
            if (i < total4) {
                float4 v = *(const float4*)(x + (size_t)i * 4);
                ushort4 h;
                h.x = f2bf(v.x); h.y = f2bf(v.y); h.z = f2bf(v.z); h.w = f2bf(v.w);
                *(ushort4*)(xbf + (size_t)i * 4) = h;
                uchar4 c;
                c.x = f2fp8(v.x); c.y = f2fp8(v.y); c.z = f2fp8(v.z); c.w = f2fp8(v.w);
                *(uchar4*)(xf8 + (size_t)i * 4) = c;
            }
        }
        return;
    }

    // ---- bucket path ----
    const int c = blk;
    const int e0 = c * 8192;

    if (t < 128) cnt[t] = 0;
    __syncthreads();

    unsigned int word[8];
    int bkt[8], rnk[8];
    #pragma unroll
    for (int it = 0; it < 2; ++it) {
        int e = e0 + it * 4096 + t * 4;
        int4 d4 = make_int4(0, 0, 0, 0), s4 = d4;
        if (e + 3 < E) {
            d4 = *(const int4*)(dst + e);
            s4 = *(const int4*)(src + e);
        } else {
            if (e + 0 < E) { d4.x = dst[e + 0]; s4.x = src[e + 0]; } else d4.x = -1;
            if (e + 1 < E) { d4.y = dst[e + 1]; s4.y = src[e + 1]; } else d4.y = -1;
            if (e + 2 < E) { d4.z = dst[e + 2]; s4.z = src[e + 2]; } else d4.z = -1;
            if (e + 3 < E) { d4.w = dst[e + 3]; s4.w = src[e + 3]; } else d4.w = -1;
        }
        int dd[4] = {d4.x, d4.y, d4.z, d4.w};
        int ss[4] = {s4.x, s4.y, s4.z, s4.w};
        #pragma unroll
        for (int q = 0; q < 4; ++q) {
            int i = it * 4 + q;
            int d = dd[q];
            if (d >= 0) {
                bkt[i]  = d >> 9;
                rnk[i]  = atomicAdd(&cnt[bkt[i]], 1);
                word[i] = (unsigned int)ss[q] | ((unsigned int)(d & 511) << 16);
            } else bkt[i] = -1;
        }
    }
    __syncthreads();

    if (t < 128) part[t] = cnt[t];
    __syncthreads();
    for (int s = 1; s < 128; s <<= 1) {
        int v = (t >= s && t < 128) ? part[t - s] : 0;
        __syncthreads();
        if (t < 128) part[t] += v;
        __syncthreads();
    }
    if (t < 128) sbase[t] = part[t] - cnt[t];
    __syncthreads();

    if (t <= nbk) table[(size_t)c * (nbk + 1) + t] = sbase[t];

    #pragma unroll
    for (int i = 0; i < 8; ++i)
        if (bkt[i] >= 0) sbuf[sbase[bkt[i]] + rnk[i]] = word[i];
    __syncthreads();

    const int total = part[127];
    for (int i = t; i < total; i += 1024)
        chunkdata[(size_t)c * 8192 + i] = sbuf[i];
}

// Phase 2: per-bucket two-pass counting sort. Computes its own base
// (base = sum_c table[c][b]), counts degrees -> offs/invd, places into LDS,
// contiguous ushort flush (src < 65536 in fast path).
constexpr int P2CAP = 10240;   // bucket ~8192 +- 90; 22 sigma + fallback
__global__ __launch_bounds__(1024) void fillsort_kernel(const unsigned int* __restrict__ chunkdata,
                                                        const int* __restrict__ table,
                                                        int* __restrict__ offs,
                                                        float* __restrict__ invd,
                                                        unsigned short* __restrict__ eidx,
                                                        int n, int nch, int nbk, int E) {
    __shared__ int cnt[512];
    __shared__ int lcur[512];
    __shared__ int part[512];
    __shared__ int redb[16];
    __shared__ int lbuf[P2CAP];
    const int b  = blockIdx.x;
    const int t  = threadIdx.x;
    const int lo = b << 9;

    int partial = 0;
    for (int c = t; c < nch; c += 1024) partial += table[(size_t)c * (nbk + 1) + b];
    #pragma unroll
    for (int off = 32; off > 0; off >>= 1) partial += __shfl_down(partial, off, 64);
    if ((t & 63) == 0) redb[t >> 6] = partial;
    for (int i = t; i < 512; i += 1024) cnt[i] = 0;
    __syncthreads();
    int base = 0;
    #pragma unroll
    for (int i = 0; i < 16; ++i) base += redb[i];

    const int w    = t >> 6;
    const int lane = t & 63;
    for (int c = w; c < nch; c += 16) {
        int o0 = table[(size_t)c * (nbk + 1) + b];
        int o1 = table[(size_t)c * (nbk + 1) + b + 1];
        for (int i = o0 + lane; i < o1; i += 64)
            atomicAdd(&cnt[(chunkdata[(size_t)c * 8192 + i] >> 16) & 511], 1);
    }
    __syncthreads();

    int v = (t < 512) ? cnt[t] : 0;
    if (t < 512) part[t] = v;
    __syncthreads();
    for (int s = 1; s < 512; s <<= 1) {
        int u = (t >= s && t < 512) ? part[t - s] : 0;
        __syncthreads();
        if (t < 512) part[t] += u;
        __syncthreads();
    }
    const int total = part[511];
    if (t < 512) {
        int ex = part[t] - v;
        lcur[t] = ex;
        int idx = lo + t;
        if (idx < n) {
            offs[idx] = base + ex;
            invd[idx] = 1.0f / fmaxf((float)v, 1.0f);
        }
    }
    if (b == nbk - 1 && t == 0) offs[n] = E;
    __syncthreads();

    for (int c = w; c < nch; c += 16) {
        int o0 = table[(size_t)c * (nbk + 1) + b];
        int o1 = table[(size_t)c * (nbk + 1) + b + 1];
        for (int i = o0 + lane; i < o1; i += 64) {
            unsigned int wd = chunkdata[(size_t)c * 8192 + i];
            int s = wd & 0xffff;
            int p = atomicAdd(&lcur[(wd >> 16) & 511], 1);
            if (p < P2CAP) lbuf[p] = s;
            else           eidx[base + p] = (unsigned short)s;   // overflow fallback
        }
    }
    __syncthreads();

    const int m = min(total, P2CAP);
    for (int i = t; i < m; i += 1024) eidx[base + i] = (unsigned short)lbuf[i];
}

// ================= CSR build fallback (N > 65536) =================
__global__ void deg_kernel(const int* __restrict__ dst, int* __restrict__ degi, int E) {
    int e = blockIdx.x * 256 + threadIdx.x;
    if (e < E) atomicAdd(&degi[__builtin_nontemporal_load(dst + e)], 1);
}
__global__ __launch_bounds__(256) void blockred_kernel(const int* __restrict__ deg,
                                                       int* __restrict__ bsum, int n) {
    __shared__ int red[256];
    int base = blockIdx.x * 1024 + threadIdx.x * 4;
    int s = 0;
    if (base + 3 < n) {
        int4 v = *(const int4*)(deg + base);
        s = v.x + v.y + v.z + v.w;
    } else {
        for (int i = 0; i < 4; ++i) if (base + i < n) s += deg[base + i];
    }
    red[threadIdx.x] = s;
    __syncthreads();
    for (int st = 128; st > 0; st >>= 1) {
        if (threadIdx.x < st) red[threadIdx.x] += red[threadIdx.x + st];
        __syncthreads();
    }
    if (threadIdx.x == 0) bsum[blockIdx.x] = red[0];
}
__global__ __launch_bounds__(256) void scanb_kernel(const int* __restrict__ bsum,
                                                    int* __restrict__ bpre, int nb) {
    __shared__ int part[256];
    int t = threadIdx.x;
    int v = (t < nb) ? bsum[t] : 0;
    part[t] = v;
    __syncthreads();
    for (int s = 1; s < 256; s <<= 1) {
        int u = (t >= s) ? part[t - s] : 0;
        __syncthreads();
        part[t] += u;
        __syncthreads();
    }
    if (t < nb) bpre[t] = part[t] - v;
}
__global__ __launch_bounds__(256) void scanfill_kernel(const int* __restrict__ deg,
                                                       const int* __restrict__ bpre,
                                                       int* __restrict__ offs,
                                                       int* __restrict__ cur,
                                                       float* __restrict__ invd,
                                                       int n, int E) {
    __shared__ int part[256];
    int t = threadIdx.x;
    int base = blockIdx.x * 1024 + t * 4;
    int d[4];
    int s = 0;
    #pragma unroll
    for (int i = 0; i < 4; ++i) {
        d[i] = (base + i < n) ? deg[base + i] : 0;
        s += d[i];
    }
    part[t] = s;
    __syncthreads();
    for (int st = 1; st < 256; st <<= 1) {
        int u = (t >= st) ? part[t - st] : 0;
        __syncthreads();
        part[t] += u;
        __syncthreads();
    }
    int pre = bpre[blockIdx.x] + part[t] - s;
    #pragma unroll
    for (int i = 0; i < 4; ++i) {
        int idx = base + i;
        if (idx < n) {
            offs[idx] = pre;
            cur[idx]  = pre;
            invd[idx] = 1.0f / fmaxf((float)d[i], 1.0f);
            pre += d[i];
        }
    }
    if (blockIdx.x == 0 && t == 0) offs[n] = E;
}
constexpr int FCH = 4096;
__global__ __launch_bounds__(256) void fill_xcd_kernel(const int* __restrict__ src,
                                                       const int* __restrict__ dst,
                                                       int* __restrict__ cur,
                                                       int* __restrict__ eidx,
                                                       int E, int rsize) {
    const int p     = blockIdx.x & 7;
    const int chunk = blockIdx.x >> 3;
    const int lo = p * rsize;
    const int hi = lo + rsize;
    #pragma unroll
    for (int it = 0; it < 4; ++it) {
        int e = chunk * FCH + (it * 256 + threadIdx.x) * 4;
        if (e + 3 < E) {
            int4v d4 = __builtin_nontemporal_load((const int4v*)(dst + e));
            #pragma unroll
            for (int q = 0; q < 4; ++q) {
                int d = d4[q];
                if (d >= lo && d < hi) {
                    int pos = atomicAdd(&cur[d], 1);
                    eidx[pos] = __builtin_nontemporal_load(src + e + q);
                }
            }
        } else {
            for (int q = 0; e + q < E && q < 4; ++q) {
                int d = dst[e + q];
                if (d >= lo && d < hi) {
                    int pos = atomicAdd(&cur[d], 1);
                    eidx[pos] = src[e + q];
                }
            }
        }
    }
}
// standalone prep (fallback path only)
__global__ __launch_bounds__(256) void prep_kernel(
    const float* __restrict__ W1l, const float* __restrict__ W1r,
    const float* __restrict__ W2l, const float* __restrict__ W2r,
    const float* __restrict__ W3l, const float* __restrict__ W3r,
    unsigned short* __restrict__ WTh1, unsigned short* __restrict__ WTl1,
    unsigned short* __restrict__ WTh2, unsigned short* __restrict__ WTl2,
    unsigned short* __restrict__ WTh3, unsigned short* __restrict__ WTl3,
    const float* __restrict__ x, unsigned short* __restrict__ xbf,
    unsigned char* __restrict__ xf8, int total4)
{
    const int b = blockIdx.x;
    if (b < 320) {
        const float *Wl, *Wr;
        unsigned short *WTh, *WTl;
        int dout, idx;
        if (b < 128)      { Wl = W1l; Wr = W1r; WTh = WTh1; WTl = WTl1; dout = 128; idx = b * 256 + threadIdx.x; }
        else if (b < 256) { Wl = W2l; Wr = W2r; WTh = WTh2; WTl = WTl2; dout = 128; idx = (b - 128) * 256 + threadIdx.x; }
        else              { Wl = W3l; Wr = W3r; WTh = WTh3; WTl = WTl3; dout = 64;  idx = (b - 256) * 256 + threadIdx.x; }
        if (idx < dout * 256) {
            int c = idx >> 8;
            int k = idx & 255;
            float v = (k < 128) ? Wl[(size_t)k * dout + c] : Wr[(size_t)(k - 128) * dout + c];
            unsigned short h = f2bf(v);
            WTh[(size_t)c * 256 + k] = h;
            WTl[(size_t)c * 256 + k] = f2bf(v - bf2f(h));
        }
    } else {
        int i = (b - 320) * 256 + threadIdx.x;
        if (i < total4) {
            float4 v = *(const float4*)(x + (size_t)i * 4);
            ushort4 h;
            h.x = f2bf(v.x); h.y = f2bf(v.y); h.z = f2bf(v.z); h.w = f2bf(v.w);
            *(ushort4*)(xbf + (size_t)i * 4) = h;
            uchar4 c;
            c.x = f2fp8(v.x); c.y = f2fp8(v.y); c.z = f2fp8(v.z); c.w = f2fp8(v.w);
            *(uchar4*)(xf8 + (size_t)i * 4) = c;
        }
    }
}

// ================= gather mean from fp8 feats -> bf16 mean, 8 B/lane =================
template <typename IT>
__global__ __launch_bounds__(256) void gather_f8_kernel(const unsigned char* __restrict__ featf8,
                                                        const int* __restrict__ offs,
                                                        const IT* __restrict__ eidx,
                                                        const float* __restrict__ invd,
                                                        unsigned short* __restrict__ aggbf, int n) {
    int node = blockIdx.x * 4 + (threadIdx.x >> 6);
    if (node >= n) return;
    const int l   = threadIdx.x & 63;
    const int grp = l >> 4;
    const int li  = l & 15;
    const int c8  = li * 8;
    int beg = offs[node], end = offs[node + 1];
    float acc[8];
    #pragma unroll
    for (int q = 0; q < 8; ++q) acc[q] = 0.f;

    int j = beg + grp;
    for (; j + 4 < end; j += 8) {
        int s0 = eidx[j], s1 = eidx[j + 4];
        uint2 v0 = *(const uint2*)(featf8 + (size_t)s0 * FEAT + c8);
        uint2 v1 = *(const uint2*)(featf8 + (size_t)s1 * FEAT + c8);
        f32x2 p;
        p = __builtin_amdgcn_cvt_pk_f32_fp8(v0.x, false); acc[0] += p.x; acc[1] += p.y;
        p = __builtin_amdgcn_cvt_pk_f32_fp8(v0.x, true);  acc[2] += p.x; acc[3] += p.y;
        p = __builtin_amdgcn_cvt_pk_f32_fp8(v0.y, false); acc[4] += p.x; acc[5] += p.y;
        p = __builtin_amdgcn_cvt_pk_f32_fp8(v0.y, true);  acc[6] += p.x; acc[7] += p.y;
        p = __builtin_amdgcn_cvt_pk_f32_fp8(v1.x, false); acc[0] += p.x; acc[1] += p.y;
        p = __builtin_amdgcn_cvt_pk_f32_fp8(v1.x, true);  acc[2] += p.x; acc[3] += p.y;
        p = __builtin_amdgcn_cvt_pk_f32_fp8(v1.y, false); acc[4] += p.x; acc[5] += p.y;
        p = __builtin_amdgcn_cvt_pk_f32_fp8(v1.y, true);  acc[6] += p.x; acc[7] += p.y;
    }
    if (j < end) {
        int s0 = eidx[j];
        uint2 v0 = *(const uint2*)(featf8 + (size_t)s0 * FEAT + c8);
        f32x2 p;
        p = __builtin_amdgcn_cvt_pk_f32_fp8(v0.x, false); acc[0] += p.x; acc[1] += p.y;
        p = __builtin_amdgcn_cvt_pk_f32_fp8(v0.x, true);  acc[2] += p.x; acc[3] += p.y;
        p = __builtin_amdgcn_cvt_pk_f32_fp8(v0.y, false); acc[4] += p.x; acc[5] += p.y;
        p = __builtin_amdgcn_cvt_pk_f32_fp8(v0.y, true);  acc[6] += p.x; acc[7] += p.y;
    }

    #pragma unroll
    for (int off = 16; off < 64; off <<= 1)
        #pragma unroll
        for (int q = 0; q < 8; ++q)
            acc[q] += __shfl_xor(acc[q], off, 64);

    if (grp == 0) {
        float sc = invd[node];
        unsigned short o[8];
        #pragma unroll
        for (int q = 0; q < 8; ++q) o[q] = f2bf(acc[q] * sc);
        *(short8v*)(aggbf + (size_t)node * FEAT + c8) = *(short8v*)o;
    }
}

// ================= MFMA dense, LDS-resident B (ALL DOUT cols), 1 block row-tile =================
// out = elu([mean|x] @ W + b); K=256, mean AND x bf16 (2 MFMAs per chunk-ct).
// 1024 thr = 16 waves x 16 rows = 256 rows/block. B staged once: DOUT*256
// ushorts hi + lo (128 KB for DOUT=128 -> 1 block/CU; A then read ONCE).
// XOR swizzle byte^=((cl&7)<<4); one barrier. WBF/WF8: bf16/fp8 copies.
// LSM: fused log_softmax (DOUT=64).
template <int DOUT, bool WBF, bool WF8, bool LSM>
__global__ __launch_bounds__(1024, 4) void dense_mfma(
    const unsigned short* __restrict__ meanbf, const unsigned short* __restrict__ xinbf,
    const unsigned short* __restrict__ WTh, const unsigned short* __restrict__ WTl,
    const float* __restrict__ bias,
    float* outf, unsigned short* outbf, unsigned char* outf8, int n)
{
    constexpr int NCT = DOUT / 16;
    __shared__ unsigned short Bh[DOUT * 256];
    __shared__ unsigned short Bl[DOUT * 256];
    const int tid = threadIdx.x;

    #pragma unroll
    for (int it = 0; it < DOUT / 32; ++it) {
        int o  = (tid + it * 1024) * 8;
        int cl = o >> 8;
        int k  = o & 255;
        size_t gsrc = (size_t)cl * 256 + k;
        int db = (o * 2) ^ ((cl & 7) << 4);
        *(short8v*)((char*)Bh + db) = *(const short8v*)(WTh + gsrc);
        *(short8v*)((char*)Bl + db) = *(const short8v*)(WTl + gsrc);
    }
    __syncthreads();

    const int l    = tid & 63;
    const int w    = tid >> 6;
    const int l15  = l & 15;
    const int lg   = l >> 4;
    const int row0 = blockIdx.x * 256 + w * 16;
    if (row0 >= n) return;
    const int g = row0 + l15;

    f32x4 acc[NCT];
    #pragma unroll
    for (int ct = 0; ct < NCT; ++ct) acc[ct] = (f32x4){0.f, 0.f, 0.f, 0.f};

    #pragma unroll
    for (int ch = 0; ch < 8; ++ch) {
        const unsigned short* As = (ch < 4) ? meanbf : xinbf;
        const int kb = (ch & 3) * 32 + lg * 8;
        short8v ah = (short8v){0, 0, 0, 0, 0, 0, 0, 0};
        if (g < n) ah = *(const short8v*)(As + (size_t)g * FEAT + kb);
        #pragma unroll
        for (int ct = 0; ct < NCT; ++ct) {
            int cl = ct * 16 + l15;
            int db = (cl * 512 + ch * 64 + lg * 16) ^ ((cl & 7) << 4);
            short8v bh = *(const short8v*)((const char*)Bh + db);
            short8v bl = *(const short8v*)((const char*)Bl + db);
            acc[ct] = __builtin_amdgcn_mfma_f32_16x16x32_bf16(ah, bh, acc[ct], 0, 0, 0);
            acc[ct] = __builtin_amdgcn_mfma_f32_16x16x32_bf16(ah, bl, acc[ct], 0, 0, 0);
        }
    }

    float t[NCT][4];
    #pragma unroll
    for (int ct = 0; ct < NCT; ++ct) {
        float b = bias[ct * 16 + l15];
        #pragma unroll
        for (int q = 0; q < 4; ++q) {
            float v = acc[ct][q] + b;
            t[ct][q] = (v > 0.f) ? v : expm1f(v);
        }
    }
    if (LSM) {
        #pragma unroll
        for (int q = 0; q < 4; ++q) {
            float m = t[0][q];
            #pragma unroll
            for (int ct = 1; ct < NCT; ++ct) m = fmaxf(m, t[ct][q]);
            #pragma unroll
            for (int s = 1; s < 16; s <<= 1) m = fmaxf(m, __shfl_xor(m, s, 64));
            float sum = 0.f;
            #pragma unroll
            for (int ct = 0; ct < NCT; ++ct) sum += expf(t[ct][q] - m);
            #pragma unroll
            for (int s = 1; s < 16; s <<= 1) sum += __shfl_xor(sum, s, 64);
            float ls = m + logf(sum);
            #pragma unroll
            for (int ct = 0; ct < NCT; ++ct) t[ct][q] -= ls;
        }
    }
    #pragma unroll
    for (int ct = 0; ct < NCT; ++ct) {
        int col = ct * 16 + l15;
        #pragma unroll
        for (int q = 0; q < 4; ++q) {
            int grow = row0 + lg * 4 + q;
            if (grow < n) {
                if (WBF) outbf[(size_t)grow * DOUT + col] = f2bf(t[ct][q]);
                if (WF8) outf8[(size_t)grow * DOUT + col] = f2fp8(t[ct][q]);
                if (!WBF && !WF8) outf[(size_t)grow * DOUT + col] = t[ct][q];
            }
        }
    }
}

extern "C" void kernel_launch(void* const* d_in, const int* in_sizes, int n_in,
                              void* d_out, int out_size, void* d_ws, size_t ws_size,
                              hipStream_t stream) {
    const float* x   = (const float*)d_in[0];
    const float* W1l = (const float*)d_in[1];
    const float* W1r = (const float*)d_in[2];
    const float* b1  = (const float*)d_in[3];
    const float* W2l = (const float*)d_in[4];
    const float* W2r = (const float*)d_in[5];
    const float* b2  = (const float*)d_in[6];
    const float* W3l = (const float*)d_in[7];
    const float* W3r = (const float*)d_in[8];
    const float* b3  = (const float*)d_in[9];
    const int*   src = (const int*)d_in[10];
    const int*   dst = (const int*)d_in[11];

    const int N = in_sizes[0] / FEAT;
    const int E = in_sizes[10];

    const size_t NA = ((size_t)N + 63) & ~(size_t)63;
    const size_t EA = ((size_t)E + 63) & ~(size_t)63;
    const int nb  = (N + 1023) / 1024;      // fallback scan blocks
    const int nbk = (N + 511) >> 9;         // buckets (512 dsts)
    const int nch = (E + 8191) / 8192;      // chunks

    auto alignup = [](char* p) { return (char*)(((uintptr_t)p + 255) & ~(uintptr_t)255); };
    char* p = (char*)d_ws;
    float* invd = (float*)p;                 p += NA * 4;
    int*   offs = (int*)p;                   p += (NA + 64) * 4;
    int*   eidxi = (int*)p;                  p += EA * 4;      // int (fallback) / ushort (fast)
    unsigned short* eidx16 = (unsigned short*)eidxi;
    unsigned int* chunkd = (unsigned int*)p; p += (size_t)nch * 8192 * 4;
    int*   table = (int*)p;                  p += (size_t)nch * (nbk + 1) * 4;
    p = alignup(p);
    int*   deg  = (int*)p;                   p += NA * 4;     // fallback
    int*   cur  = (int*)p;                   p += NA * 4;     // fallback
    int*   bsum = (int*)p;                   p += 256 * 4;    // fallback
    int*   bpre = (int*)p;                   p += 256 * 4;    // fallback
    p = alignup(p);
    unsigned short* WTh1 = (unsigned short*)p; p += 128 * 256 * 2;
    unsigned short* WTl1 = (unsigned short*)p; p += 128 * 256 * 2;
    unsigned short* WTh2 = (unsigned short*)p; p += 128 * 256 * 2;
    unsigned short* WTl2 = (unsigned short*)p; p += 128 * 256 * 2;
    unsigned short* WTh3 = (unsigned short*)p; p += 64 * 256 * 2;
    unsigned short* WTl3 = (unsigned short*)p; p += 64 * 256 * 2;
    p = alignup(p);
    unsigned short* mbf = (unsigned short*)p;  p += NA * FEAT * 2;   // bf16 mean
    unsigned short* bfA = (unsigned short*)p;  p += NA * FEAT * 2;   // bf16 act
    unsigned short* bfB = (unsigned short*)p;  p += NA * FEAT * 2;   // bf16 act
    unsigned char*  f8X = (unsigned char*)p;   p += NA * FEAT;       // fp8 act
    float* outp = (float*)d_out;

    const int gblocks = (N + 3) / 4;
    const int dblocks = (N + 255) / 256;
    const int total4  = N * FEAT / 4;

    if (N <= 65536) {
        // ---- fused CSR phase-1 + prep, then phase-2 ----
        const int pblocks = 80 + (total4 + 1023) / 1024;
        bucket_prep_kernel<<<nch + pblocks, 1024, 0, stream>>>(
            src, dst, chunkd, table, E, nbk, nch,
            W1l, W1r, W2l, W2r, W3l, W3r,
            WTh1, WTl1, WTh2, WTl2, WTh3, WTl3,
            x, bfA, f8X, total4);
        fillsort_kernel<<<nbk, 1024, 0, stream>>>(chunkd, table, offs, invd, eidx16, N, nch, nbk, E);

        gather_f8_kernel<unsigned short><<<gblocks, 256, 0, stream>>>(f8X, offs, eidx16, invd, mbf, N);
        dense_mfma<128, true, true, false><<<dblocks, 1024, 0, stream>>>(mbf, bfA, WTh1, WTl1, b1, nullptr, bfB, f8X, N);

        gather_f8_kernel<unsigned short><<<gblocks, 256, 0, stream>>>(f8X, offs, eidx16, invd, mbf, N);
        dense_mfma<128, true, true, false><<<dblocks, 1024, 0, stream>>>(mbf, bfB, WTh2, WTl2, b2, nullptr, bfA, f8X, N);

        gather_f8_kernel<unsigned short><<<gblocks, 256, 0, stream>>>(f8X, offs, eidx16, invd, mbf, N);
        dense_mfma<64, false, false, true><<<dblocks, 1024, 0, stream>>>(mbf, bfA, WTh3, WTl3, b3, outp, nullptr, nullptr, N);
    } else {
        // ---- fallback: atomic fill CSR (int eidx) + standalone prep ----
        hipMemsetAsync(deg, 0, (size_t)N * 4, stream);
        deg_kernel<<<(E + 255) / 256, 256, 0, stream>>>(dst, deg, E);
        blockred_kernel<<<nb, 256, 0, stream>>>(deg, bsum, N);
        scanb_kernel<<<1, 256, 0, stream>>>(bsum, bpre, nb);
        scanfill_kernel<<<nb, 256, 0, stream>>>(deg, bpre, offs, cur, invd, N, E);
        const int rsize   = (N + 7) / 8;
        const int fblocks = ((E + FCH - 1) / FCH) * 8;
        fill_xcd_kernel<<<fblocks, 256, 0, stream>>>(src, dst, cur, eidxi, E, rsize);
        prep_kernel<<<320 + (total4 + 255) / 256, 256, 0, stream>>>(
            W1l, W1r, W2l, W2r, W3l, W3r, WTh1, WTl1, WTh2, WTl2, WTh3, WTl3,
            x, bfA, f8X, total4);

        gather_f8_kernel<int><<<gblocks, 256, 0, stream>>>(f8X, offs, eidxi, invd, mbf, N);
        dense_mfma<128, true, true, false><<<dblocks, 1024, 0, stream>>>(mbf, bfA, WTh1, WTl1, b1, nullptr, bfB, f8X, N);

        gather_f8_kernel<int><<<gblocks, 256, 0, stream>>>(f8X, offs, eidxi, invd, mbf, N);
        dense_mfma<128, true, true, false><<<dblocks, 1024, 0, stream>>>(mbf, bfB, WTh2, WTl2, b2, nullptr, bfA, f8X, N);

        gather_f8_kernel<int><<<gblocks, 256, 0, stream>>>(f8X, offs, eidxi, invd, mbf, N);
        dense_mfma<64, false, false, true><<<dblocks, 1024, 0, stream>>>(mbf, bfA, WTh3, WTl3, b3, outp, nullptr, nullptr, N);
    }
}

// Round 18
// 152.868 us; speedup vs baseline: 2.3294x; 1.0438x over previous
//
#include <hip/hip_runtime.h>
#include <math.h>

constexpr int FEAT = 128;   // DIN == DH == 128

typedef __attribute__((ext_vector_type(8))) short short8v;   // 8 bf16 raw / 16 B
typedef __attribute__((ext_vector_type(4))) float f32x4;
typedef __attribute__((ext_vector_type(2))) float f32x2;
typedef __attribute__((ext_vector_type(4))) int   int4v;

// ---- fp32 -> bf16 (RNE) / fp8 helpers ----
__device__ inline unsigned short f2bf(float f) {
    unsigned int u = __float_as_uint(f);
    u += 0x7fffu + ((u >> 16) & 1u);
    return (unsigned short)(u >> 16);
}
__device__ inline float bf2f(unsigned short h) {
    return __uint_as_float(((unsigned int)h) << 16);
}
__device__ inline unsigned char f2fp8(float f) {
    int r = __builtin_amdgcn_cvt_pk_fp8_f32(f, 0.f, 0, false);
    return (unsigned char)(r & 0xff);
}

// ================= fused CSR bucket phase 1 + weight/x prep =================
__global__ __launch_bounds__(1024) void bucket_prep_kernel(
    const int* __restrict__ src, const int* __restrict__ dst,
    unsigned int* __restrict__ chunkdata, int* __restrict__ table,
    int E, int nbk, int nch,
    const float* __restrict__ W1l, const float* __restrict__ W1r,
    const float* __restrict__ W2l, const float* __restrict__ W2r,
    const float* __restrict__ W3l, const float* __restrict__ W3r,
    unsigned short* __restrict__ WTh1, unsigned short* __restrict__ WTl1,
    unsigned short* __restrict__ WTh2, unsigned short* __restrict__ WTl2,
    unsigned short* __restrict__ WTh3, unsigned short* __restrict__ WTl3,
    const float* __restrict__ x, unsigned short* __restrict__ xbf,
    unsigned char* __restrict__ xf8, int total4)
{
    __shared__ int cnt[128];
    __shared__ int part[128];
    __shared__ int sbase[128];
    __shared__ unsigned int sbuf[8192];
    const int t = threadIdx.x;
    const int blk = blockIdx.x;

    if (blk >= nch) {
        int b = blk - nch;
        if (b < 80) {
            const float *Wl, *Wr;
            unsigned short *WTh, *WTl;
            int dout, idx;
            if (b < 32)      { Wl = W1l; Wr = W1r; WTh = WTh1; WTl = WTl1; dout = 128; idx = b * 1024 + t; }
            else if (b < 64) { Wl = W2l; Wr = W2r; WTh = WTh2; WTl = WTl2; dout = 128; idx = (b - 32) * 1024 + t; }
            else             { Wl = W3l; Wr = W3r; WTh = WTh3; WTl = WTl3; dout = 64;  idx = (b - 64) * 1024 + t; }
            if (idx < dout * 256) {
                int c = idx >> 8;
                int k = idx & 255;
                float v = (k < 128) ? Wl[(size_t)k * dout + c] : Wr[(size_t)(k - 128) * dout + c];
                unsigned short h = f2bf(v);
                WTh[(size_t)c * 256 + k] = h;
                WTl[(size_t)c * 256 + k] = f2bf(v - bf2f(h));
            }
        } else {
            int i = (b - 80) * 1024 + t;
            if (i < total4) {
                float4 v = *(const float4*)(x + (size_t)i * 4);
                ushort4 h;
                h.x = f2bf(v.x); h.y = f2bf(v.y); h.z = f2bf(v.z); h.w = f2bf(v.w);
                *(ushort4*)(xbf + (size_t)i * 4) = h;
                uchar4 c;
                c.x = f2fp8(v.x); c.y = f2fp8(v.y); c.z = f2fp8(v.z); c.w = f2fp8(v.w);
                *(uchar4*)(xf8 + (size_t)i * 4) = c;
            }
        }
        return;
    }

    const int c = blk;
    const int e0 = c * 8192;

    if (t < 128) cnt[t] = 0;
    __syncthreads();

    unsigned int word[8];
    int bkt[8], rnk[8];
    #pragma unroll
    for (int it = 0; it < 2; ++it) {
        int e = e0 + it * 4096 + t * 4;
        int4 d4 = make_int4(0, 0, 0, 0), s4 = d4;
        if (e + 3 < E) {
            d4 = *(const int4*)(dst + e);
            s4 = *(const int4*)(src + e);
        } else {
            if (e + 0 < E) { d4.x = dst[e + 0]; s4.x = src[e + 0]; } else d4.x = -1;
            if (e + 1 < E) { d4.y = dst[e + 1]; s4.y = src[e + 1]; } else d4.y = -1;
            if (e + 2 < E) { d4.z = dst[e + 2]; s4.z = src[e + 2]; } else d4.z = -1;
            if (e + 3 < E) { d4.w = dst[e + 3]; s4.w = src[e + 3]; } else d4.w = -1;
        }
        int dd[4] = {d4.x, d4.y, d4.z, d4.w};
        int ss[4] = {s4.x, s4.y, s4.z, s4.w};
        #pragma unroll
        for (int q = 0; q < 4; ++q) {
            int i = it * 4 + q;
            int d = dd[q];
            if (d >= 0) {
                bkt[i]  = d >> 9;
                rnk[i]  = atomicAdd(&cnt[bkt[i]], 1);
                word[i] = (unsigned int)ss[q] | ((unsigned int)(d & 511) << 16);
            } else bkt[i] = -1;
        }
    }
    __syncthreads();

    if (t < 128) part[t] = cnt[t];
    __syncthreads();
    for (int s = 1; s < 128; s <<= 1) {
        int v = (t >= s && t < 128) ? part[t - s] : 0;
        __syncthreads();
        if (t < 128) part[t] += v;
        __syncthreads();
    }
    if (t < 128) sbase[t] = part[t] - cnt[t];
    __syncthreads();

    if (t <= nbk) table[(size_t)c * (nbk + 1) + t] = sbase[t];

    #pragma unroll
    for (int i = 0; i < 8; ++i)
        if (bkt[i] >= 0) sbuf[sbase[bkt[i]] + rnk[i]] = word[i];
    __syncthreads();

    const int total = part[127];
    for (int i = t; i < total; i += 1024)
        chunkdata[(size_t)c * 8192 + i] = sbuf[i];
}

// Phase 2: per-bucket two-pass counting sort -> offs/invd + ushort eidx flush.
constexpr int P2CAP = 10240;
__global__ __launch_bounds__(1024) void fillsort_kernel(const unsigned int* __restrict__ chunkdata,
                                                        const int* __restrict__ table,
                                                        int* __restrict__ offs,
                                                        float* __restrict__ invd,
                                                        unsigned short* __restrict__ eidx,
                                                        int n, int nch, int nbk, int E) {
    __shared__ int cnt[512];
    __shared__ int lcur[512];
    __shared__ int part[512];
    __shared__ int redb[16];
    __shared__ int lbuf[P2CAP];
    const int b  = blockIdx.x;
    const int t  = threadIdx.x;
    const int lo = b << 9;

    int partial = 0;
    for (int c = t; c < nch; c += 1024) partial += table[(size_t)c * (nbk + 1) + b];
    #pragma unroll
    for (int off = 32; off > 0; off >>= 1) partial += __shfl_down(partial, off, 64);
    if ((t & 63) == 0) redb[t >> 6] = partial;
    for (int i = t; i < 512; i += 1024) cnt[i] = 0;
    __syncthreads();
    int base = 0;
    #pragma unroll
    for (int i = 0; i < 16; ++i) base += redb[i];

    const int w    = t >> 6;
    const int lane = t & 63;
    for (int c = w; c < nch; c += 16) {
        int o0 = table[(size_t)c * (nbk + 1) + b];
        int o1 = table[(size_t)c * (nbk + 1) + b + 1];
        for (int i = o0 + lane; i < o1; i += 64)
            atomicAdd(&cnt[(chunkdata[(size_t)c * 8192 + i] >> 16) & 511], 1);
    }
    __syncthreads();

    int v = (t < 512) ? cnt[t] : 0;
    if (t < 512) part[t] = v;
    __syncthreads();
    for (int s = 1; s < 512; s <<= 1) {
        int u = (t >= s && t < 512) ? part[t - s] : 0;
        __syncthreads();
        if (t < 512) part[t] += u;
        __syncthreads();
    }
    const int total = part[511];
    if (t < 512) {
        int ex = part[t] - v;
        lcur[t] = ex;
        int idx = lo + t;
        if (idx < n) {
            offs[idx] = base + ex;
            invd[idx] = 1.0f / fmaxf((float)v, 1.0f);
        }
    }
    if (b == nbk - 1 && t == 0) offs[n] = E;
    __syncthreads();

    for (int c = w; c < nch; c += 16) {
        int o0 = table[(size_t)c * (nbk + 1) + b];
        int o1 = table[(size_t)c * (nbk + 1) + b + 1];
        for (int i = o0 + lane; i < o1; i += 64) {
            unsigned int wd = chunkdata[(size_t)c * 8192 + i];
            int s = wd & 0xffff;
            int p = atomicAdd(&lcur[(wd >> 16) & 511], 1);
            if (p < P2CAP) lbuf[p] = s;
            else           eidx[base + p] = (unsigned short)s;
        }
    }
    __syncthreads();

    const int m = min(total, P2CAP);
    for (int i = t; i < m; i += 1024) eidx[base + i] = (unsigned short)lbuf[i];
}

// ================= CSR build fallback (N > 65536) =================
__global__ void deg_kernel(const int* __restrict__ dst, int* __restrict__ degi, int E) {
    int e = blockIdx.x * 256 + threadIdx.x;
    if (e < E) atomicAdd(&degi[__builtin_nontemporal_load(dst + e)], 1);
}
__global__ __launch_bounds__(256) void blockred_kernel(const int* __restrict__ deg,
                                                       int* __restrict__ bsum, int n) {
    __shared__ int red[256];
    int base = blockIdx.x * 1024 + threadIdx.x * 4;
    int s = 0;
    if (base + 3 < n) {
        int4 v = *(const int4*)(deg + base);
        s = v.x + v.y + v.z + v.w;
    } else {
        for (int i = 0; i < 4; ++i) if (base + i < n) s += deg[base + i];
    }
    red[threadIdx.x] = s;
    __syncthreads();
    for (int st = 128; st > 0; st >>= 1) {
        if (threadIdx.x < st) red[threadIdx.x] += red[threadIdx.x + st];
        __syncthreads();
    }
    if (threadIdx.x == 0) bsum[blockIdx.x] = red[0];
}
__global__ __launch_bounds__(256) void scanb_kernel(const int* __restrict__ bsum,
                                                    int* __restrict__ bpre, int nb) {
    __shared__ int part[256];
    int t = threadIdx.x;
    int v = (t < nb) ? bsum[t] : 0;
    part[t] = v;
    __syncthreads();
    for (int s = 1; s < 256; s <<= 1) {
        int u = (t >= s) ? part[t - s] : 0;
        __syncthreads();
        part[t] += u;
        __syncthreads();
    }
    if (t < nb) bpre[t] = part[t] - v;
}
__global__ __launch_bounds__(256) void scanfill_kernel(const int* __restrict__ deg,
                                                       const int* __restrict__ bpre,
                                                       int* __restrict__ offs,
                                                       int* __restrict__ cur,
                                                       float* __restrict__ invd,
                                                       int n, int E) {
    __shared__ int part[256];
    int t = threadIdx.x;
    int base = blockIdx.x * 1024 + t * 4;
    int d[4];
    int s = 0;
    #pragma unroll
    for (int i = 0; i < 4; ++i) {
        d[i] = (base + i < n) ? deg[base + i] : 0;
        s += d[i];
    }
    part[t] = s;
    __syncthreads();
    for (int st = 1; st < 256; st <<= 1) {
        int u = (t >= st) ? part[t - st] : 0;
        __syncthreads();
        part[t] += u;
        __syncthreads();
    }
    int pre = bpre[blockIdx.x] + part[t] - s;
    #pragma unroll
    for (int i = 0; i < 4; ++i) {
        int idx = base + i;
        if (idx < n) {
            offs[idx] = pre;
            cur[idx]  = pre;
            invd[idx] = 1.0f / fmaxf((float)d[i], 1.0f);
            pre += d[i];
        }
    }
    if (blockIdx.x == 0 && t == 0) offs[n] = E;
}
constexpr int FCH = 4096;
__global__ __launch_bounds__(256) void fill_xcd_kernel(const int* __restrict__ src,
                                                       const int* __restrict__ dst,
                                                       int* __restrict__ cur,
                                                       int* __restrict__ eidx,
                                                       int E, int rsize) {
    const int p     = blockIdx.x & 7;
    const int chunk = blockIdx.x >> 3;
    const int lo = p * rsize;
    const int hi = lo + rsize;
    #pragma unroll
    for (int it = 0; it < 4; ++it) {
        int e = chunk * FCH + (it * 256 + threadIdx.x) * 4;
        if (e + 3 < E) {
            int4v d4 = __builtin_nontemporal_load((const int4v*)(dst + e));
            #pragma unroll
            for (int q = 0; q < 4; ++q) {
                int d = d4[q];
                if (d >= lo && d < hi) {
                    int pos = atomicAdd(&cur[d], 1);
                    eidx[pos] = __builtin_nontemporal_load(src + e + q);
                }
            }
        } else {
            for (int q = 0; e + q < E && q < 4; ++q) {
                int d = dst[e + q];
                if (d >= lo && d < hi) {
                    int pos = atomicAdd(&cur[d], 1);
                    eidx[pos] = src[e + q];
                }
            }
        }
    }
}
__global__ __launch_bounds__(256) void prep_kernel(
    const float* __restrict__ W1l, const float* __restrict__ W1r,
    const float* __restrict__ W2l, const float* __restrict__ W2r,
    const float* __restrict__ W3l, const float* __restrict__ W3r,
    unsigned short* __restrict__ WTh1, unsigned short* __restrict__ WTl1,
    unsigned short* __restrict__ WTh2, unsigned short* __restrict__ WTl2,
    unsigned short* __restrict__ WTh3, unsigned short* __restrict__ WTl3,
    const float* __restrict__ x, unsigned short* __restrict__ xbf,
    unsigned char* __restrict__ xf8, int total4)
{
    const int b = blockIdx.x;
    if (b < 320) {
        const float *Wl, *Wr;
        unsigned short *WTh, *WTl;
        int dout, idx;
        if (b < 128)      { Wl = W1l; Wr = W1r; WTh = WTh1; WTl = WTl1; dout = 128; idx = b * 256 + threadIdx.x; }
        else if (b < 256) { Wl = W2l; Wr = W2r; WTh = WTh2; WTl = WTl2; dout = 128; idx = (b - 128) * 256 + threadIdx.x; }
        else              { Wl = W3l; Wr = W3r; WTh = WTh3; WTl = WTl3; dout = 64;  idx = (b - 256) * 256 + threadIdx.x; }
        if (idx < dout * 256) {
            int c = idx >> 8;
            int k = idx & 255;
            float v = (k < 128) ? Wl[(size_t)k * dout + c] : Wr[(size_t)(k - 128) * dout + c];
            unsigned short h = f2bf(v);
            WTh[(size_t)c * 256 + k] = h;
            WTl[(size_t)c * 256 + k] = f2bf(v - bf2f(h));
        }
    } else {
        int i = (b - 320) * 256 + threadIdx.x;
        if (i < total4) {
            float4 v = *(const float4*)(x + (size_t)i * 4);
            ushort4 h;
            h.x = f2bf(v.x); h.y = f2bf(v.y); h.z = f2bf(v.z); h.w = f2bf(v.w);
            *(ushort4*)(xbf + (size_t)i * 4) = h;
            uchar4 c;
            c.x = f2fp8(v.x); c.y = f2fp8(v.y); c.z = f2fp8(v.z); c.w = f2fp8(v.w);
            *(uchar4*)(xf8 + (size_t)i * 4) = c;
        }
    }
}

// ================= gather mean from fp8 feats -> bf16 mean =================
// Latency-optimized, exec-mask-safe: each wave prefetches <=64 indices with ONE
// coalesced read and stages them in its private LDS slice (no cross-wave use,
// no barrier). Compute loops read indices via ds_read (immune to group
// divergence, unlike shfl). Up to 16 feature rows in flight per wave.
template <typename IT>
__global__ __launch_bounds__(256) void gather_f8_kernel(const unsigned char* __restrict__ featf8,
                                                        const int* __restrict__ offs,
                                                        const IT* __restrict__ eidx,
                                                        const float* __restrict__ invd,
                                                        unsigned short* __restrict__ aggbf, int n) {
    __shared__ int sidx[4][64];
    const int widx = threadIdx.x >> 6;
    int node = blockIdx.x * 4 + widx;
    if (node >= n) return;
    const int l   = threadIdx.x & 63;
    const int grp = l >> 4;
    const int li  = l & 15;
    const int c8  = li * 8;
    const int beg = offs[node], end = offs[node + 1];
    const int deg = end - beg;

    // one coalesced index prefetch into this wave's private LDS slice
    if (l < deg) sidx[widx][l] = (int)eidx[beg + l];

    float acc[8];
    #pragma unroll
    for (int q = 0; q < 8; ++q) acc[q] = 0.f;

    const int m = min(deg, 64);
    int k = grp;
    // main loop: 4 rows deep per group -> 16 feature loads in flight per wave
    for (; k + 12 < m; k += 16) {
        int s0 = sidx[widx][k];
        int s1 = sidx[widx][k + 4];
        int s2 = sidx[widx][k + 8];
        int s3 = sidx[widx][k + 12];
        uint2 v0 = *(const uint2*)(featf8 + (size_t)s0 * FEAT + c8);
        uint2 v1 = *(const uint2*)(featf8 + (size_t)s1 * FEAT + c8);
        uint2 v2 = *(const uint2*)(featf8 + (size_t)s2 * FEAT + c8);
        uint2 v3 = *(const uint2*)(featf8 + (size_t)s3 * FEAT + c8);
        f32x2 p;
        p = __builtin_amdgcn_cvt_pk_f32_fp8(v0.x, false); acc[0] += p.x; acc[1] += p.y;
        p = __builtin_amdgcn_cvt_pk_f32_fp8(v0.x, true);  acc[2] += p.x; acc[3] += p.y;
        p = __builtin_amdgcn_cvt_pk_f32_fp8(v0.y, false); acc[4] += p.x; acc[5] += p.y;
        p = __builtin_amdgcn_cvt_pk_f32_fp8(v0.y, true);  acc[6] += p.x; acc[7] += p.y;
        p = __builtin_amdgcn_cvt_pk_f32_fp8(v1.x, false); acc[0] += p.x; acc[1] += p.y;
        p = __builtin_amdgcn_cvt_pk_f32_fp8(v1.x, true);  acc[2] += p.x; acc[3] += p.y;
        p = __builtin_amdgcn_cvt_pk_f32_fp8(v1.y, false); acc[4] += p.x; acc[5] += p.y;
        p = __builtin_amdgcn_cvt_pk_f32_fp8(v1.y, true);  acc[6] += p.x; acc[7] += p.y;
        p = __builtin_amdgcn_cvt_pk_f32_fp8(v2.x, false); acc[0] += p.x; acc[1] += p.y;
        p = __builtin_amdgcn_cvt_pk_f32_fp8(v2.x, true);  acc[2] += p.x; acc[3] += p.y;
        p = __builtin_amdgcn_cvt_pk_f32_fp8(v2.y, false); acc[4] += p.x; acc[5] += p.y;
        p = __builtin_amdgcn_cvt_pk_f32_fp8(v2.y, true);  acc[6] += p.x; acc[7] += p.y;
        p = __builtin_amdgcn_cvt_pk_f32_fp8(v3.x, false); acc[0] += p.x; acc[1] += p.y;
        p = __builtin_amdgcn_cvt_pk_f32_fp8(v3.x, true);  acc[2] += p.x; acc[3] += p.y;
        p = __builtin_amdgcn_cvt_pk_f32_fp8(v3.y, false); acc[4] += p.x; acc[5] += p.y;
        p = __builtin_amdgcn_cvt_pk_f32_fp8(v3.y, true);  acc[6] += p.x; acc[7] += p.y;
    }
    for (; k < m; k += 4) {
        int s0 = sidx[widx][k];
        uint2 v0 = *(const uint2*)(featf8 + (size_t)s0 * FEAT + c8);
        f32x2 p;
        p = __builtin_amdgcn_cvt_pk_f32_fp8(v0.x, false); acc[0] += p.x; acc[1] += p.y;
        p = __builtin_amdgcn_cvt_pk_f32_fp8(v0.x, true);  acc[2] += p.x; acc[3] += p.y;
        p = __builtin_amdgcn_cvt_pk_f32_fp8(v0.y, false); acc[4] += p.x; acc[5] += p.y;
        p = __builtin_amdgcn_cvt_pk_f32_fp8(v0.y, true);  acc[6] += p.x; acc[7] += p.y;
    }
    // rare tail: deg > 64 (direct loads, still correct)
    for (int j = beg + 64 + grp; j < end; j += 4) {
        int s0 = (int)eidx[j];
        uint2 v0 = *(const uint2*)(featf8 + (size_t)s0 * FEAT + c8);
        f32x2 p;
        p = __builtin_amdgcn_cvt_pk_f32_fp8(v0.x, false); acc[0] += p.x; acc[1] += p.y;
        p = __builtin_amdgcn_cvt_pk_f32_fp8(v0.x, true);  acc[2] += p.x; acc[3] += p.y;
        p = __builtin_amdgcn_cvt_pk_f32_fp8(v0.y, false); acc[4] += p.x; acc[5] += p.y;
        p = __builtin_amdgcn_cvt_pk_f32_fp8(v0.y, true);  acc[6] += p.x; acc[7] += p.y;
    }

    // reduce across the 4 groups (wave-convergent point)
    #pragma unroll
    for (int off = 16; off < 64; off <<= 1)
        #pragma unroll
        for (int q = 0; q < 8; ++q)
            acc[q] += __shfl_xor(acc[q], off, 64);

    if (grp == 0) {
        float sc = invd[node];
        unsigned short o[8];
        #pragma unroll
        for (int q = 0; q < 8; ++q) o[q] = f2bf(acc[q] * sc);
        *(short8v*)(aggbf + (size_t)node * FEAT + c8) = *(short8v*)o;
    }
}

// ================= MFMA dense, LDS-resident B (ALL DOUT cols) =================
template <int DOUT, bool WBF, bool WF8, bool LSM>
__global__ __launch_bounds__(1024, 4) void dense_mfma(
    const unsigned short* __restrict__ meanbf, const unsigned short* __restrict__ xinbf,
    const unsigned short* __restrict__ WTh, const unsigned short* __restrict__ WTl,
    const float* __restrict__ bias,
    float* outf, unsigned short* outbf, unsigned char* outf8, int n)
{
    constexpr int NCT = DOUT / 16;
    __shared__ unsigned short Bh[DOUT * 256];
    __shared__ unsigned short Bl[DOUT * 256];
    const int tid = threadIdx.x;

    #pragma unroll
    for (int it = 0; it < DOUT / 32; ++it) {
        int o  = (tid + it * 1024) * 8;
        int cl = o >> 8;
        int k  = o & 255;
        size_t gsrc = (size_t)cl * 256 + k;
        int db = (o * 2) ^ ((cl & 7) << 4);
        *(short8v*)((char*)Bh + db) = *(const short8v*)(WTh + gsrc);
        *(short8v*)((char*)Bl + db) = *(const short8v*)(WTl + gsrc);
    }
    __syncthreads();

    const int l    = tid & 63;
    const int w    = tid >> 6;
    const int l15  = l & 15;
    const int lg   = l >> 4;
    const int row0 = blockIdx.x * 256 + w * 16;
    if (row0 >= n) return;
    const int g = row0 + l15;

    f32x4 acc[NCT];
    #pragma unroll
    for (int ct = 0; ct < NCT; ++ct) acc[ct] = (f32x4){0.f, 0.f, 0.f, 0.f};

    #pragma unroll
    for (int ch = 0; ch < 8; ++ch) {
        const unsigned short* As = (ch < 4) ? meanbf : xinbf;
        const int kb = (ch & 3) * 32 + lg * 8;
        short8v ah = (short8v){0, 0, 0, 0, 0, 0, 0, 0};
        if (g < n) ah = *(const short8v*)(As + (size_t)g * FEAT + kb);
        #pragma unroll
        for (int ct = 0; ct < NCT; ++ct) {
            int cl = ct * 16 + l15;
            int db = (cl * 512 + ch * 64 + lg * 16) ^ ((cl & 7) << 4);
            short8v bh = *(const short8v*)((const char*)Bh + db);
            short8v bl = *(const short8v*)((const char*)Bl + db);
            acc[ct] = __builtin_amdgcn_mfma_f32_16x16x32_bf16(ah, bh, acc[ct], 0, 0, 0);
            acc[ct] = __builtin_amdgcn_mfma_f32_16x16x32_bf16(ah, bl, acc[ct], 0, 0, 0);
        }
    }

    float t[NCT][4];
    #pragma unroll
    for (int ct = 0; ct < NCT; ++ct) {
        float b = bias[ct * 16 + l15];
        #pragma unroll
        for (int q = 0; q < 4; ++q) {
            float v = acc[ct][q] + b;
            t[ct][q] = (v > 0.f) ? v : expm1f(v);
        }
    }
    if (LSM) {
        #pragma unroll
        for (int q = 0; q < 4; ++q) {
            float m = t[0][q];
            #pragma unroll
            for (int ct = 1; ct < NCT; ++ct) m = fmaxf(m, t[ct][q]);
            #pragma unroll
            for (int s = 1; s < 16; s <<= 1) m = fmaxf(m, __shfl_xor(m, s, 64));
            float sum = 0.f;
            #pragma unroll
            for (int ct = 0; ct < NCT; ++ct) sum += expf(t[ct][q] - m);
            #pragma unroll
            for (int s = 1; s < 16; s <<= 1) sum += __shfl_xor(sum, s, 64);
            float ls = m + logf(sum);
            #pragma unroll
            for (int ct = 0; ct < NCT; ++ct) t[ct][q] -= ls;
        }
    }
    #pragma unroll
    for (int ct = 0; ct < NCT; ++ct) {
        int col = ct * 16 + l15;
        #pragma unroll
        for (int q = 0; q < 4; ++q) {
            int grow = row0 + lg * 4 + q;
            if (grow < n) {
                if (WBF) outbf[(size_t)grow * DOUT + col] = f2bf(t[ct][q]);
                if (WF8) outf8[(size_t)grow * DOUT + col] = f2fp8(t[ct][q]);
                if (!WBF && !WF8) outf[(size_t)grow * DOUT + col] = t[ct][q];
            }
        }
    }
}

extern "C" void kernel_launch(void* const* d_in, const int* in_sizes, int n_in,
                              void* d_out, int out_size, void* d_ws, size_t ws_size,
                              hipStream_t stream) {
    const float* x   = (const float*)d_in[0];
    const float* W1l = (const float*)d_in[1];
    const float* W1r = (const float*)d_in[2];
    const float* b1  = (const float*)d_in[3];
    const float* W2l = (const float*)d_in[4];
    const float* W2r = (const float*)d_in[5];
    const float* b2  = (const float*)d_in[6];
    const float* W3l = (const float*)d_in[7];
    const float* W3r = (const float*)d_in[8];
    const float* b3  = (const float*)d_in[9];
    const int*   src = (const int*)d_in[10];
    const int*   dst = (const int*)d_in[11];

    const int N = in_sizes[0] / FEAT;
    const int E = in_sizes[10];

    const size_t NA = ((size_t)N + 63) & ~(size_t)63;
    const size_t EA = ((size_t)E + 63) & ~(size_t)63;
    const int nb  = (N + 1023) / 1024;
    const int nbk = (N + 511) >> 9;
    const int nch = (E + 8191) / 8192;

    auto alignup = [](char* p) { return (char*)(((uintptr_t)p + 255) & ~(uintptr_t)255); };
    char* p = (char*)d_ws;
    float* invd = (float*)p;                 p += NA * 4;
    int*   offs = (int*)p;                   p += (NA + 64) * 4;
    int*   eidxi = (int*)p;                  p += EA * 4;
    unsigned short* eidx16 = (unsigned short*)eidxi;
    unsigned int* chunkd = (unsigned int*)p; p += (size_t)nch * 8192 * 4;
    int*   table = (int*)p;                  p += (size_t)nch * (nbk + 1) * 4;
    p = alignup(p);
    int*   deg  = (int*)p;                   p += NA * 4;
    int*   cur  = (int*)p;                   p += NA * 4;
    int*   bsum = (int*)p;                   p += 256 * 4;
    int*   bpre = (int*)p;                   p += 256 * 4;
    p = alignup(p);
    unsigned short* WTh1 = (unsigned short*)p; p += 128 * 256 * 2;
    unsigned short* WTl1 = (unsigned short*)p; p += 128 * 256 * 2;
    unsigned short* WTh2 = (unsigned short*)p; p += 128 * 256 * 2;
    unsigned short* WTl2 = (unsigned short*)p; p += 128 * 256 * 2;
    unsigned short* WTh3 = (unsigned short*)p; p += 64 * 256 * 2;
    unsigned short* WTl3 = (unsigned short*)p; p += 64 * 256 * 2;
    p = alignup(p);
    unsigned short* mbf = (unsigned short*)p;  p += NA * FEAT * 2;
    unsigned short* bfA = (unsigned short*)p;  p += NA * FEAT * 2;
    unsigned short* bfB = (unsigned short*)p;  p += NA * FEAT * 2;
    unsigned char*  f8X = (unsigned char*)p;   p += NA * FEAT;
    float* outp = (float*)d_out;

    const int gblocks = (N + 3) / 4;
    const int dblocks = (N + 255) / 256;
    const int total4  = N * FEAT / 4;

    if (N <= 65536) {
        const int pblocks = 80 + (total4 + 1023) / 1024;
        bucket_prep_kernel<<<nch + pblocks, 1024, 0, stream>>>(
            src, dst, chunkd, table, E, nbk, nch,
            W1l, W1r, W2l, W2r, W3l, W3r,
            WTh1, WTl1, WTh2, WTl2, WTh3, WTl3,
            x, bfA, f8X, total4);
        fillsort_kernel<<<nbk, 1024, 0, stream>>>(chunkd, table, offs, invd, eidx16, N, nch, nbk, E);

        gather_f8_kernel<unsigned short><<<gblocks, 256, 0, stream>>>(f8X, offs, eidx16, invd, mbf, N);
        dense_mfma<128, true, true, false><<<dblocks, 1024, 0, stream>>>(mbf, bfA, WTh1, WTl1, b1, nullptr, bfB, f8X, N);

        gather_f8_kernel<unsigned short><<<gblocks, 256, 0, stream>>>(f8X, offs, eidx16, invd, mbf, N);
        dense_mfma<128, true, true, false><<<dblocks, 1024, 0, stream>>>(mbf, bfB, WTh2, WTl2, b2, nullptr, bfA, f8X, N);

        gather_f8_kernel<unsigned short><<<gblocks, 256, 0, stream>>>(f8X, offs, eidx16, invd, mbf, N);
        dense_mfma<64, false, false, true><<<dblocks, 1024, 0, stream>>>(mbf, bfA, WTh3, WTl3, b3, outp, nullptr, nullptr, N);
    } else {
        hipMemsetAsync(deg, 0, (size_t)N * 4, stream);
        deg_kernel<<<(E + 255) / 256, 256, 0, stream>>>(dst, deg, E);
        blockred_kernel<<<nb, 256, 0, stream>>>(deg, bsum, N);
        scanb_kernel<<<1, 256, 0, stream>>>(bsum, bpre, nb);
        scanfill_kernel<<<nb, 256, 0, stream>>>(deg, bpre, offs, cur, invd, N, E);
        const int rsize   = (N + 7) / 8;
        const int fblocks = ((E + FCH - 1) / FCH) * 8;
        fill_xcd_kernel<<<fblocks, 256, 0, stream>>>(src, dst, cur, eidxi, E, rsize);
        prep_kernel<<<320 + (total4 + 255) / 256, 256, 0, stream>>>(
            W1l, W1r, W2l, W2r, W3l, W3r, WTh1, WTl1, WTh2, WTl2, WTh3, WTl3,
            x, bfA, f8X, total4);

        gather_f8_kernel<int><<<gblocks, 256, 0, stream>>>(f8X, offs, eidxi, invd, mbf, N);
        dense_mfma<128, true, true, false><<<dblocks, 1024, 0, stream>>>(mbf, bfA, WTh1, WTl1, b1, nullptr, bfB, f8X, N);

        gather_f8_kernel<int><<<gblocks, 256, 0, stream>>>(f8X, offs, eidxi, invd, mbf, N);
        dense_mfma<128, true, true, false><<<dblocks, 1024, 0, stream>>>(mbf, bfB, WTh2, WTl2, b2, nullptr, bfA, f8X, N);

        gather_f8_kernel<int><<<gblocks, 256, 0, stream>>>(f8X, offs, eidxi, invd, mbf, N);
        dense_mfma<64, false, false, true><<<dblocks, 1024, 0, stream>>>(mbf, bfA, WTh3, WTl3, b3, outp, nullptr, nullptr, N);
    }
}